// Round 5
// baseline (983.157 us; speedup 1.0000x reference)
//
#include <hip/hip_runtime.h>
#include <math.h>

#define NN 16384
#define EE 262144
#define FF 32
#define HH 128
#define BB 16
#define DI 256
#define DS 16
#define DC 4
#define DTR 8
#define OUTW 1552
#define NCH 256
#define CHLEN 64    // NCH*CHLEN == NN

// ---------------------------------------------------------------- utilities
__device__ __forceinline__ float siluf(float v) { return v / (1.f + __expf(-v)); }
__device__ __forceinline__ float softplusf(float v) {
    return fmaxf(v, 0.f) + log1pf(expf(-fabsf(v)));
}

// ---------------------------------------------------------------- CSR build
__global__ void deg_kernel(const int* __restrict__ dst, int* __restrict__ cnt) {
    int e = blockIdx.x * blockDim.x + threadIdx.x;
    if (e < EE) atomicAdd(&cnt[dst[e]], 1);
}

__global__ __launch_bounds__(1024) void prefix_kernel(const int* __restrict__ cnt,
                                                      int* __restrict__ rowptr,
                                                      int* __restrict__ cursor,
                                                      float* __restrict__ dinv) {
    __shared__ int part[1024];
    int tid = threadIdx.x;
    int4 c4[4];
#pragma unroll
    for (int j = 0; j < 4; j++) c4[j] = ((const int4*)cnt)[tid * 4 + j];
    int v[16] = {c4[0].x, c4[0].y, c4[0].z, c4[0].w, c4[1].x, c4[1].y, c4[1].z, c4[1].w,
                 c4[2].x, c4[2].y, c4[2].z, c4[2].w, c4[3].x, c4[3].y, c4[3].z, c4[3].w};
    int s = 0;
#pragma unroll
    for (int j = 0; j < 16; j++) s += v[j];
    part[tid] = s;
    __syncthreads();
    for (int off = 1; off < 1024; off <<= 1) {
        int t = (tid >= off) ? part[tid - off] : 0;
        __syncthreads();
        part[tid] += t;
        __syncthreads();
    }
    int running = part[tid] - s;
    int rp[16];
    float dv[16];
#pragma unroll
    for (int j = 0; j < 16; j++) {
        rp[j] = running;
        running += v[j];
        dv[j] = rsqrtf((float)(v[j] + 1));  // +1 self loop
    }
#pragma unroll
    for (int j = 0; j < 4; j++) {
        int4 r4; r4.x = rp[j*4]; r4.y = rp[j*4+1]; r4.z = rp[j*4+2]; r4.w = rp[j*4+3];
        ((int4*)rowptr)[tid * 4 + j] = r4;
        ((int4*)cursor)[tid * 4 + j] = r4;
        float4 d4; d4.x = dv[j*4]; d4.y = dv[j*4+1]; d4.z = dv[j*4+2]; d4.w = dv[j*4+3];
        ((float4*)dinv)[tid * 4 + j] = d4;
    }
    if (tid == 1023) rowptr[NN] = part[1023];
}

__global__ void scatter_kernel(const int* __restrict__ src, const int* __restrict__ dst,
                               int* __restrict__ cursor, int* __restrict__ col) {
    int e = blockIdx.x * blockDim.x + threadIdx.x;
    if (e < EE) {
        int d = dst[e];
        int pos = atomicAdd(&cursor[d], 1);
        col[pos] = src[e];
    }
}

// ---------------------------------------------------------------- GEMM (fp32, 64x64 tile)
__global__ __launch_bounds__(256) void gemm_k(const float* __restrict__ A,
                                              const float* __restrict__ B,
                                              const float* __restrict__ bias,
                                              float* __restrict__ C,
                                              int M, int Nn, int K, int act) {
    __shared__ float As[16][68];
    __shared__ float Bs[16][68];
    int tid = threadIdx.x;
    int m0 = blockIdx.y * 64;
    int n0 = blockIdx.x * 64;
    int ty = tid >> 4, tx = tid & 15;
    float acc[4][4] = {{0.f}};
    for (int k0 = 0; k0 < K; k0 += 16) {
#pragma unroll
        for (int l = 0; l < 4; l++) {
            int idx = tid + l * 256;
            int i = idx >> 4, j = idx & 15;
            As[j][i] = A[(size_t)(m0 + i) * K + k0 + j];
        }
#pragma unroll
        for (int l = 0; l < 4; l++) {
            int idx = tid + l * 256;
            int i = idx >> 6, j = idx & 63;
            int n = n0 + j;
            Bs[i][j] = (n < Nn) ? B[(size_t)(k0 + i) * Nn + n] : 0.f;
        }
        __syncthreads();
#pragma unroll
        for (int kk = 0; kk < 16; kk++) {
            float4 a4 = *(const float4*)&As[kk][ty * 4];
            float4 b4 = *(const float4*)&Bs[kk][tx * 4];
            float av[4] = {a4.x, a4.y, a4.z, a4.w};
            float bv[4] = {b4.x, b4.y, b4.z, b4.w};
#pragma unroll
            for (int r = 0; r < 4; r++)
#pragma unroll
                for (int c = 0; c < 4; c++) acc[r][c] = fmaf(av[r], bv[c], acc[r][c]);
        }
        __syncthreads();
    }
    int nb = n0 + tx * 4;
    if (nb < Nn) {
        float4 bi4 = {0.f, 0.f, 0.f, 0.f};
        if (bias) bi4 = *(const float4*)&bias[nb];
#pragma unroll
        for (int r = 0; r < 4; r++) {
            int m = m0 + ty * 4 + r;
            float4 v;
            v.x = acc[r][0] + bi4.x; v.y = acc[r][1] + bi4.y;
            v.z = acc[r][2] + bi4.z; v.w = acc[r][3] + bi4.w;
            if (act == 1) {
                v.x = fmaxf(v.x, 0.f); v.y = fmaxf(v.y, 0.f);
                v.z = fmaxf(v.z, 0.f); v.w = fmaxf(v.w, 0.f);
            }
            *(float4*)&C[(size_t)m * Nn + nb] = v;
        }
    }
}

// ---------------------------------------------------------------- GEMM with A^T input (A stored [K][M])
__global__ __launch_bounds__(256) void gemm_at(const float* __restrict__ AT,
                                               const float* __restrict__ B,
                                               float* __restrict__ C,
                                               int M, int Nn, int K) {
    __shared__ float As[16][68];
    __shared__ float Bs[16][68];
    int tid = threadIdx.x;
    int m0 = blockIdx.y * 64;
    int n0 = blockIdx.x * 64;
    int ty = tid >> 4, tx = tid & 15;
    float acc[4][4] = {{0.f}};
    for (int k0 = 0; k0 < K; k0 += 16) {
#pragma unroll
        for (int l = 0; l < 4; l++) {
            int idx = tid + l * 256;
            int kk = idx >> 6, i = idx & 63;
            As[kk][i] = AT[(size_t)(k0 + kk) * M + m0 + i];
        }
#pragma unroll
        for (int l = 0; l < 4; l++) {
            int idx = tid + l * 256;
            int i = idx >> 6, j = idx & 63;
            int n = n0 + j;
            Bs[i][j] = (n < Nn) ? B[(size_t)(k0 + i) * Nn + n] : 0.f;
        }
        __syncthreads();
#pragma unroll
        for (int kk = 0; kk < 16; kk++) {
            float4 a4 = *(const float4*)&As[kk][ty * 4];
            float4 b4 = *(const float4*)&Bs[kk][tx * 4];
            float av[4] = {a4.x, a4.y, a4.z, a4.w};
            float bv[4] = {b4.x, b4.y, b4.z, b4.w};
#pragma unroll
            for (int r = 0; r < 4; r++)
#pragma unroll
                for (int c = 0; c < 4; c++) acc[r][c] = fmaf(av[r], bv[c], acc[r][c]);
        }
        __syncthreads();
    }
    int nb = n0 + tx * 4;
    if (nb < Nn) {
#pragma unroll
        for (int r = 0; r < 4; r++) {
            int m = m0 + ty * 4 + r;
            float4 v;
            v.x = acc[r][0]; v.y = acc[r][1]; v.z = acc[r][2]; v.w = acc[r][3];
            *(float4*)&C[(size_t)m * Nn + nb] = v;
        }
    }
}

// ---------------------------------------------------------------- GCN gather (CSR by dest), 4-deep edge unroll
__global__ void gcn_gather(const float* __restrict__ xw, const int* __restrict__ rowptr,
                           const int* __restrict__ col, const float* __restrict__ dinv,
                           const float* __restrict__ b, float* __restrict__ out) {
    int n = blockIdx.x;
    int f = threadIdx.x;  // 128
    float dn = dinv[n];
    float acc = xw[(size_t)n * HH + f] * dn * dn;  // self loop
    int beg = rowptr[n], end = rowptr[n + 1];
    int e = beg;
    for (; e + 4 <= end; e += 4) {
        int s0 = col[e], s1 = col[e + 1], s2 = col[e + 2], s3 = col[e + 3];
        float w0 = dinv[s0] * dn, w1 = dinv[s1] * dn, w2 = dinv[s2] * dn, w3 = dinv[s3] * dn;
        float v0 = xw[(size_t)s0 * HH + f];
        float v1 = xw[(size_t)s1 * HH + f];
        float v2 = xw[(size_t)s2 * HH + f];
        float v3 = xw[(size_t)s3 * HH + f];
        acc = fmaf(v0, w0, acc);
        acc = fmaf(v1, w1, acc);
        acc = fmaf(v2, w2, acc);
        acc = fmaf(v3, w3, acc);
    }
    for (; e < end; e++) {
        int s0 = col[e];
        acc = fmaf(xw[(size_t)s0 * HH + f], dinv[s0] * dn, acc);
    }
    acc += b[f];
    out[(size_t)n * HH + f] = fmaxf(acc, 0.f);
}

// ---------------------------------------------------------------- conv + silu, transposed outputs
__global__ __launch_bounds__(256) void conv_silu_t(const float* __restrict__ xz,
                                                   const float* __restrict__ cw,
                                                   const float* __restrict__ cb,
                                                   float* __restrict__ xst,
                                                   float* __restrict__ szt) {
    __shared__ float tile[67][65];
    int tid = threadIdx.x;
    int t0 = blockIdx.x * 64;
    int c0 = blockIdx.y * 64;
#pragma unroll
    for (int l = 0; l < 17; l++) {
        int idx = tid + l * 256;
        if (idx < 67 * 64) {
            int r = idx >> 6, c = idx & 63;
            int gt = t0 - 3 + r;
            tile[r][c] = (gt >= 0) ? xz[(size_t)gt * 512 + c0 + c] : 0.f;
        }
    }
    __syncthreads();
    int tl = tid & 63;
    int d0 = tid >> 6;
    if (c0 < 256) {
#pragma unroll
        for (int l = 0; l < 16; l++) {
            int dl = d0 + l * 4;
            int dg = c0 + dl;
            float acc = cb[dg];
#pragma unroll
            for (int k = 0; k < DC; k++)
                acc = fmaf(tile[tl + k][dl], cw[dg * DC + k], acc);
            xst[dg * NN + t0 + tl] = siluf(acc);
        }
    } else {
#pragma unroll
        for (int l = 0; l < 16; l++) {
            int dl = d0 + l * 4;
            int dg = c0 - 256 + dl;
            szt[dg * NN + t0 + tl] = siluf(tile[tl + 3][dl]);
        }
    }
}

// ---------------------------------------------------------------- transpose dbl [NN][40] -> [40][NN]
__global__ __launch_bounds__(256) void transpose_dbl(const float* __restrict__ dbl,
                                                     float* __restrict__ dblt) {
    __shared__ float tile[64][41];
    int tid = threadIdx.x;
    int t0 = blockIdx.x * 64;
#pragma unroll
    for (int l = 0; l < 10; l++) {
        int idx = tid + l * 256;
        int r = idx / 40, c = idx - r * 40;
        tile[r][c] = dbl[(size_t)(t0 + r) * 40 + c];
    }
    __syncthreads();
#pragma unroll
    for (int l = 0; l < 10; l++) {
        int idx = tid + l * 256;
        int c = idx >> 6, t = idx & 63;
        dblt[c * NN + t0 + t] = tile[t][c];
    }
}

// ---------------------------------------------------------------- dt (transposed): DT_T[d][t]
__global__ __launch_bounds__(256) void dt_t_kernel(const float* __restrict__ dblt,
                                                   const float* __restrict__ W_dt,
                                                   const float* __restrict__ b_dt,
                                                   float* __restrict__ dtt) {
    int t = blockIdx.x * 256 + threadIdx.x;
    int d = blockIdx.y;
    float acc = b_dt[d];
#pragma unroll
    for (int j = 0; j < DTR; j++)
        acc = fmaf(dblt[j * NN + t], W_dt[j * DI + d], acc);
    dtt[d * NN + t] = softplusf(acc);
}

// ---------------------------------------------------------------- fused single-pass Mamba scan
// Decoupled lookback (rocPRIM pattern; AMD CP dispatches workgroups in order, so a
// block only ever waits on lower-index predecessors -> no deadlock).
// Lane layout: sg = lane&7 (states 2sg, 2sg+1), dl = lane>>3; block covers 32 d.
// B/C staged in LDS (stride 68: 16B-aligned rows, 2-way conflicts only = free).
// y accumulated in LDS, stored as full 256B lines. Cross-block data via agent-scope atomics.
__global__ __launch_bounds__(256, 8) void scan_fused(const float* __restrict__ dtt,
                                                     const float* __restrict__ xst,
                                                     const float* __restrict__ dblt,
                                                     const float* __restrict__ A_log,
                                                     const float* __restrict__ D_p,
                                                     const float* __restrict__ szt,
                                                     float* __restrict__ yt,
                                                     float* __restrict__ aggP,
                                                     float* __restrict__ aggH,
                                                     float* __restrict__ pre,
                                                     int* __restrict__ flags) {
    __shared__ float Bs[16][68];
    __shared__ float Cs[16][68];
    __shared__ float Ys[4][8][68];
    __shared__ int sflag;
    int tid = threadIdx.x;
    int wave = tid >> 6, lane = tid & 63;
    int sg = lane & 7, dl = lane >> 3;
    int dblk = blockIdx.x, chunk = blockIdx.y;
    int d_local = wave * 8 + dl;
    int d = dblk * 32 + d_local;
    int t0 = chunk * CHLEN;
    int s0 = 2 * sg;
    {   // stage B (rows 8..23) and C (rows 24..39) tiles
        int s = tid >> 4, t4 = (tid & 15) * 4;
        *(float4*)&Bs[s][t4] = *(const float4*)&dblt[(8 + s) * NN + t0 + t4];
        *(float4*)&Cs[s][t4] = *(const float4*)&dblt[(24 + s) * NN + t0 + t4];
    }
    float A0 = -expf(A_log[d * DS + s0]);
    float A1 = -expf(A_log[d * DS + s0 + 1]);
    float Dd = D_p[d];
    const float* dtp = dtt + d * NN + t0;
    const float* xsp = xst + d * NN + t0;
    const float* szp = szt + d * NN + t0;
    __syncthreads();

    // ---- local chunk scan (aggregate only)
    float h0 = 0.f, h1 = 0.f, P0 = 1.f, P1 = 1.f;
    {
        float4 dA = *(const float4*)dtp;
        float4 xA = *(const float4*)xsp;
        float4 dB = *(const float4*)(dtp + 4);
        float4 xB = *(const float4*)(xsp + 4);
        for (int i = 0; i < CHLEN; i += 4) {
            float4 dC, xC;
            if (i + 8 < CHLEN) {
                dC = *(const float4*)(dtp + i + 8);
                xC = *(const float4*)(xsp + i + 8);
            }
            float4 b04 = *(const float4*)&Bs[s0][i];
            float4 b14 = *(const float4*)&Bs[s0 + 1][i];
#define P1S(U) { float dtv = dA.U; float a0 = __expf(dtv * A0); float a1 = __expf(dtv * A1); \
        float dx = dtv * xA.U; h0 = fmaf(a0, h0, dx * b04.U); h1 = fmaf(a1, h1, dx * b14.U); \
        P0 *= a0; P1 *= a1; }
            P1S(x) P1S(y) P1S(z) P1S(w)
#undef P1S
            dA = dB; xA = xB; dB = dC; xB = xC;
        }
    }

    int slab = (dblk * NCH + chunk) * 512;
    int e0 = d_local * 16 + s0;
    float sb0 = 0.f, sb1 = 0.f;
    if (chunk == 0) {
        __hip_atomic_store(&pre[slab + e0], h0, __ATOMIC_RELAXED, __HIP_MEMORY_SCOPE_AGENT);
        __hip_atomic_store(&pre[slab + e0 + 1], h1, __ATOMIC_RELAXED, __HIP_MEMORY_SCOPE_AGENT);
        __syncthreads();
        if (tid == 0)
            __hip_atomic_store(&flags[dblk * NCH], 2, __ATOMIC_RELEASE, __HIP_MEMORY_SCOPE_AGENT);
    } else {
        __hip_atomic_store(&aggP[slab + e0], P0, __ATOMIC_RELAXED, __HIP_MEMORY_SCOPE_AGENT);
        __hip_atomic_store(&aggH[slab + e0], h0, __ATOMIC_RELAXED, __HIP_MEMORY_SCOPE_AGENT);
        __hip_atomic_store(&aggP[slab + e0 + 1], P1, __ATOMIC_RELAXED, __HIP_MEMORY_SCOPE_AGENT);
        __hip_atomic_store(&aggH[slab + e0 + 1], h1, __ATOMIC_RELAXED, __HIP_MEMORY_SCOPE_AGENT);
        __syncthreads();
        if (tid == 0)
            __hip_atomic_store(&flags[dblk * NCH + chunk], 1, __ATOMIC_RELEASE, __HIP_MEMORY_SCOPE_AGENT);
        // lookback
        float aP0 = 1.f, aH0 = 0.f, aP1 = 1.f, aH1 = 0.f;
        int j = chunk - 1;
        for (;;) {
            if (tid == 0) {
                int f;
                do {
                    f = __hip_atomic_load(&flags[dblk * NCH + j], __ATOMIC_ACQUIRE,
                                          __HIP_MEMORY_SCOPE_AGENT);
                    if (f == 0) __builtin_amdgcn_s_sleep(2);
                } while (f == 0);
                sflag = f;
            }
            __syncthreads();
            int f = sflag;
            __syncthreads();
            int js = (dblk * NCH + j) * 512;
            if (f == 2) {
                float q0 = __hip_atomic_load(&pre[js + e0], __ATOMIC_RELAXED, __HIP_MEMORY_SCOPE_AGENT);
                float q1 = __hip_atomic_load(&pre[js + e0 + 1], __ATOMIC_RELAXED, __HIP_MEMORY_SCOPE_AGENT);
                sb0 = fmaf(aP0, q0, aH0);
                sb1 = fmaf(aP1, q1, aH1);
                break;
            } else {
                float gp0 = __hip_atomic_load(&aggP[js + e0], __ATOMIC_RELAXED, __HIP_MEMORY_SCOPE_AGENT);
                float gh0 = __hip_atomic_load(&aggH[js + e0], __ATOMIC_RELAXED, __HIP_MEMORY_SCOPE_AGENT);
                float gp1 = __hip_atomic_load(&aggP[js + e0 + 1], __ATOMIC_RELAXED, __HIP_MEMORY_SCOPE_AGENT);
                float gh1 = __hip_atomic_load(&aggH[js + e0 + 1], __ATOMIC_RELAXED, __HIP_MEMORY_SCOPE_AGENT);
                aH0 = fmaf(aP0, gh0, aH0); aP0 *= gp0;
                aH1 = fmaf(aP1, gh1, aH1); aP1 *= gp1;
                j--;
            }
        }
        // publish own inclusive prefix (unblocks successors before replay)
        __hip_atomic_store(&pre[slab + e0], fmaf(P0, sb0, h0), __ATOMIC_RELAXED, __HIP_MEMORY_SCOPE_AGENT);
        __hip_atomic_store(&pre[slab + e0 + 1], fmaf(P1, sb1, h1), __ATOMIC_RELAXED, __HIP_MEMORY_SCOPE_AGENT);
        __syncthreads();
        if (tid == 0)
            __hip_atomic_store(&flags[dblk * NCH + chunk], 2, __ATOMIC_RELEASE, __HIP_MEMORY_SCOPE_AGENT);
    }

    // ---- replay with correct initial state; y -> LDS -> full-line stores
    h0 = sb0; h1 = sb1;
    {
        float4 dA = *(const float4*)dtp;
        float4 xA = *(const float4*)xsp;
        float4 zA = *(const float4*)szp;
        float4 dB = *(const float4*)(dtp + 4);
        float4 xB = *(const float4*)(xsp + 4);
        float4 zB = *(const float4*)(szp + 4);
        for (int i = 0; i < CHLEN; i += 4) {
            float4 dC, xC, zC;
            if (i + 8 < CHLEN) {
                dC = *(const float4*)(dtp + i + 8);
                xC = *(const float4*)(xsp + i + 8);
                zC = *(const float4*)(szp + i + 8);
            }
            float4 b04 = *(const float4*)&Bs[s0][i];
            float4 b14 = *(const float4*)&Bs[s0 + 1][i];
            float4 c04 = *(const float4*)&Cs[s0][i];
            float4 c14 = *(const float4*)&Cs[s0 + 1][i];
            float4 yv;
#define P3S(U) { float dtv = dA.U; float a0 = __expf(dtv * A0); float a1 = __expf(dtv * A1); \
        float dx = dtv * xA.U; h0 = fmaf(a0, h0, dx * b04.U); h1 = fmaf(a1, h1, dx * b14.U); \
        float c = fmaf(h1, c14.U, h0 * c04.U); \
        c += __shfl_xor(c, 1); c += __shfl_xor(c, 2); c += __shfl_xor(c, 4); \
        yv.U = (c + Dd * xA.U) * zA.U; }
            P3S(x) P3S(y) P3S(z) P3S(w)
#undef P3S
            if (sg == 0) *(float4*)&Ys[wave][dl][i] = yv;
            dA = dB; xA = xB; zA = zB; dB = dC; xB = xC; zB = zC;
        }
    }
#pragma unroll
    for (int r = 0; r < 8; r++)
        yt[(size_t)(dblk * 32 + wave * 8 + r) * NN + t0 + lane] = Ys[wave][r][lane];
}

// ---------------------------------------------------------------- add + LayerNorm (wave per row)
__global__ void add_ln(const float* __restrict__ hg, const float* __restrict__ hm,
                       const float* __restrict__ gamma, const float* __restrict__ beta,
                       float* __restrict__ out) {
    int row = blockIdx.x * 4 + (threadIdx.x >> 6);
    int lane = threadIdx.x & 63;
    size_t base = (size_t)row * HH;
    float v0 = hg[base + lane] + hm[base + lane];
    float v1 = hg[base + 64 + lane] + hm[base + 64 + lane];
    float sum = v0 + v1;
#pragma unroll
    for (int m = 32; m >= 1; m >>= 1) sum += __shfl_xor(sum, m);
    float mu = sum * (1.f / 128.f);
    float d0 = v0 - mu, d1 = v1 - mu;
    float vs = d0 * d0 + d1 * d1;
#pragma unroll
    for (int m = 32; m >= 1; m >>= 1) vs += __shfl_xor(vs, m);
    float inv = rsqrtf(vs * (1.f / 128.f) + 1e-5f);
    out[base + lane] = d0 * inv * gamma[lane] + beta[lane];
    out[base + 64 + lane] = d1 * inv * gamma[64 + lane] + beta[64 + lane];
}

// ---------------------------------------------------------------- pooling (batch sorted), 4-row unroll
__global__ void pool_kernel(const float* __restrict__ hf, const int* __restrict__ batch,
                            float* __restrict__ ge, int* __restrict__ counts) {
    int f = threadIdx.x;  // 128
    int r0 = blockIdx.x * 128;
    int gcur = batch[r0];
    float acc = 0.f;
    int cnt = 0;
    for (int i = 0; i < 128; i += 4) {
        int r = r0 + i;
        int g0 = batch[r], g3 = batch[r + 3];
        float v0 = hf[(size_t)r * HH + f];
        float v1 = hf[(size_t)(r + 1) * HH + f];
        float v2 = hf[(size_t)(r + 2) * HH + f];
        float v3 = hf[(size_t)(r + 3) * HH + f];
        if (g0 == gcur && g3 == gcur) {
            acc += (v0 + v1) + (v2 + v3);
            cnt += 4;
        } else {
            int gs[4] = {g0, batch[r + 1], batch[r + 2], g3};
            float vs[4] = {v0, v1, v2, v3};
#pragma unroll
            for (int k = 0; k < 4; k++) {
                if (gs[k] != gcur) {
                    atomicAdd(&ge[gcur * HH + f], acc);
                    if (f == 0) atomicAdd(&counts[gcur], cnt);
                    acc = 0.f; cnt = 0; gcur = gs[k];
                }
                acc += vs[k];
                cnt++;
            }
        }
    }
    atomicAdd(&ge[gcur * HH + f], acc);
    if (f == 0) atomicAdd(&counts[gcur], cnt);
}

__global__ void ge_norm(float* __restrict__ ge, const int* __restrict__ counts) {
    int idx = blockIdx.x * blockDim.x + threadIdx.x;
    if (idx < BB * HH) {
        int b = idx >> 7;
        ge[idx] /= fmaxf((float)counts[b], 1.f);
    }
}

// ---------------------------------------------------------------- output heads
__global__ void heads_kernel(const float* __restrict__ ge,
                             const float* Wc, const float* bc, const float* Wh, const float* bh,
                             const float* Wt, const float* bt, const float* Wp1, const float* bp1,
                             const float* Wp2, const float* bp2, const float* Wd, const float* bd,
                             const float* Ws, const float* bs, float* __restrict__ out) {
    int col = blockIdx.x * blockDim.x + threadIdx.x;
    int b = blockIdx.y;
    if (col >= OUTW) return;
    const float* W; const float* bi; int lc, w;
    if (col < 1)         { W = Wc;  bi = bc;  lc = col;        w = 1; }
    else if (col < 5)    { W = Wh;  bi = bh;  lc = col - 1;    w = 4; }
    else if (col < 8)    { W = Wt;  bi = bt;  lc = col - 5;    w = 3; }
    else if (col < 520)  { W = Wp1; bi = bp1; lc = col - 8;    w = 512; }
    else if (col < 1032) { W = Wp2; bi = bp2; lc = col - 520;  w = 512; }
    else if (col < 1544) { W = Wd;  bi = bd;  lc = col - 1032; w = 512; }
    else                 { W = Ws;  bi = bs;  lc = col - 1544; w = 8; }
    float acc = bi[lc];
#pragma unroll 8
    for (int f = 0; f < HH; f++) acc = fmaf(ge[b * HH + f], W[f * w + lc], acc);
    out[(size_t)b * OUTW + col] = acc;
}

// ---------------------------------------------------------------- launch
extern "C" void kernel_launch(void* const* d_in, const int* in_sizes, int n_in,
                              void* d_out, int out_size, void* d_ws, size_t ws_size,
                              hipStream_t stream) {
    const float* nf      = (const float*)d_in[0];
    const int*   ei      = (const int*)d_in[1];
    const int*   batch   = (const int*)d_in[2];
    const float* W_in    = (const float*)d_in[3];
    const float* b_in    = (const float*)d_in[4];
    const float* W_g1    = (const float*)d_in[5];
    const float* b_g1    = (const float*)d_in[6];
    const float* W_g2    = (const float*)d_in[7];
    const float* b_g2    = (const float*)d_in[8];
    const float* W_inproj= (const float*)d_in[9];
    const float* conv_w  = (const float*)d_in[10];
    const float* conv_b  = (const float*)d_in[11];
    const float* W_xproj = (const float*)d_in[12];
    const float* W_dt    = (const float*)d_in[13];
    const float* b_dt    = (const float*)d_in[14];
    const float* A_log   = (const float*)d_in[15];
    const float* D_p     = (const float*)d_in[16];
    const float* W_out   = (const float*)d_in[17];
    const float* gamma   = (const float*)d_in[18];
    const float* beta    = (const float*)d_in[19];
    const float* Wc = (const float*)d_in[20]; const float* bc = (const float*)d_in[21];
    const float* Wh = (const float*)d_in[22]; const float* bh = (const float*)d_in[23];
    const float* Wt = (const float*)d_in[24]; const float* bt = (const float*)d_in[25];
    const float* Wp1= (const float*)d_in[26]; const float* bp1= (const float*)d_in[27];
    const float* Wp2= (const float*)d_in[28]; const float* bp2= (const float*)d_in[29];
    const float* Wd = (const float*)d_in[30]; const float* bd = (const float*)d_in[31];
    const float* Ws = (const float*)d_in[32]; const float* bs = (const float*)d_in[33];

    const int* e_src = ei;
    const int* e_dst = ei + EE;

    // workspace layout (floats, then ints)
    float* w = (float*)d_ws;
    size_t o = 0;
    float* F0   = w + o; o += (size_t)NN * HH;   // dead during scan -> AGGP/AGGH
    float* F1   = w + o; o += (size_t)NN * HH;   // dead during scan -> PRE/FLAGS
    float* F2   = w + o; o += (size_t)NN * HH;
    float* XZ   = w + o; o += (size_t)NN * 512;  // dead after conv_silu_t; reused:
    float* DTT  = XZ;                             //   DT_T [DI][NN]
    float* YT   = XZ + (size_t)NN * DI;           //   y^T  [DI][NN]
    float* XST  = w + o; o += (size_t)NN * DI;   // x (conv+silu), transposed [DI][NN]
    float* SZT  = w + o; o += (size_t)NN * DI;   // silu(z), transposed [DI][NN]
    float* DBL  = w + o; o += (size_t)NN * 40;
    float* DBLT = w + o; o += (size_t)NN * 40;   // [40][NN]; rows 8..23 = B^T, 24..39 = C^T
    float* GE   = w + o; o += BB * HH;
    float* DINV = w + o; o += NN;
    int* ip = (int*)(w + o);
    int* CNT    = ip; ip += NN;
    int* ROWPTR = ip; ip += NN + 1;
    int* CURSOR = ip; ip += NN;
    int* COL    = ip; ip += EE;
    int* COUNTS = ip; ip += BB;

    // scan-time overlays (F0/F1 dead during scan)
    float* AGGP  = F0;                        // 8*NCH*512 = 1M floats
    float* AGGH  = F0 + (size_t)8 * NCH * 512;
    float* PRE   = F1;                        // 1M floats
    int*   FLAGS = (int*)(F1 + (size_t)8 * NCH * 512);  // 8*NCH ints

    hipMemsetAsync(CNT, 0, NN * sizeof(int), stream);
    hipMemsetAsync(GE, 0, BB * HH * sizeof(float), stream);
    hipMemsetAsync(COUNTS, 0, BB * sizeof(int), stream);

    // CSR build
    deg_kernel<<<EE / 256, 256, 0, stream>>>(e_dst, CNT);
    prefix_kernel<<<1, 1024, 0, stream>>>(CNT, ROWPTR, CURSOR, DINV);
    scatter_kernel<<<EE / 256, 256, 0, stream>>>(e_src, e_dst, CURSOR, COL);

    // h0 = relu(nf @ W_in + b_in)
    gemm_k<<<dim3(2, NN / 64), 256, 0, stream>>>(nf, W_in, b_in, F0, NN, HH, FF, 1);
    // GCN layer 1
    gemm_k<<<dim3(2, NN / 64), 256, 0, stream>>>(F0, W_g1, nullptr, F1, NN, HH, HH, 0);
    gcn_gather<<<NN, HH, 0, stream>>>(F1, ROWPTR, COL, DINV, b_g1, F0);
    // GCN layer 2
    gemm_k<<<dim3(2, NN / 64), 256, 0, stream>>>(F0, W_g2, nullptr, F1, NN, HH, HH, 0);
    gcn_gather<<<NN, HH, 0, stream>>>(F1, ROWPTR, COL, DINV, b_g2, F2);  // F2 = h_gnn

    // xz = h_gnn @ W_inproj
    gemm_k<<<dim3(8, NN / 64), 256, 0, stream>>>(F2, W_inproj, nullptr, XZ, NN, 512, HH, 0);
    // conv + silu -> XST; silu(z) -> SZT (both transposed)
    conv_silu_t<<<dim3(NN / 64, 8), 256, 0, stream>>>(XZ, conv_w, conv_b, XST, SZT);
    // dbl = xs @ W_xproj (A^T layout)
    gemm_at<<<dim3(1, NN / 64), 256, 0, stream>>>(XST, W_xproj, DBL, NN, 40, DI);
    // transpose dbl -> DBLT
    transpose_dbl<<<NN / 64, 256, 0, stream>>>(DBL, DBLT);
    // dt (transposed) — overwrites XZ region (dead)
    dt_t_kernel<<<dim3(NN / 256, DI), 256, 0, stream>>>(DBLT, W_dt, b_dt, DTT);

    // fused single-pass Mamba scan (F0/F1 now dead -> overlays live)
    hipMemsetAsync(FLAGS, 0, 8 * NCH * sizeof(int), stream);
    scan_fused<<<dim3(8, NCH), 256, 0, stream>>>(DTT, XST, DBLT, A_log, D_p, SZT, YT,
                                                 AGGP, AGGH, PRE, FLAGS);

    // h_mamba = y @ W_out -> F1 (y stored transposed)
    gemm_at<<<dim3(2, NN / 64), 256, 0, stream>>>(YT, W_out, F1, NN, HH, DI);
    // hh = h_gnn + h_mamba; LayerNorm -> F0
    add_ln<<<NN / 4, 256, 0, stream>>>(F2, F1, gamma, beta, F0);

    // pooling
    pool_kernel<<<NN / 128, HH, 0, stream>>>(F0, batch, GE, COUNTS);
    ge_norm<<<(BB * HH + 255) / 256, 256, 0, stream>>>(GE, COUNTS);

    // heads
    heads_kernel<<<dim3((OUTW + 127) / 128, BB), 128, 0, stream>>>(
        GE, Wc, bc, Wh, bh, Wt, bt, Wp1, bp1, Wp2, bp2, Wd, bd, Ws, bs, (float*)d_out);
}

// Round 6
// 750.662 us; speedup vs baseline: 1.3097x; 1.3097x over previous
//
#include <hip/hip_runtime.h>
#include <math.h>

#define NN 16384
#define EE 262144
#define FF 32
#define HH 128
#define BB 16
#define DI 256
#define DS 16
#define DC 4
#define DTR 8
#define OUTW 1552
#define NCH 256
#define CHLEN 64    // NCH*CHLEN == NN
#define NG 8        // phase2 groups
#define GL 32       // chunks per group; NG*GL == NCH

// ---------------------------------------------------------------- utilities
__device__ __forceinline__ float siluf(float v) { return v / (1.f + __expf(-v)); }
__device__ __forceinline__ float softplusf(float v) {
    return fmaxf(v, 0.f) + log1pf(expf(-fabsf(v)));
}

// ---------------------------------------------------------------- CSR build
__global__ void deg_kernel(const int* __restrict__ dst, int* __restrict__ cnt) {
    int e = blockIdx.x * blockDim.x + threadIdx.x;
    if (e < EE) atomicAdd(&cnt[dst[e]], 1);
}

__global__ __launch_bounds__(1024) void prefix_kernel(const int* __restrict__ cnt,
                                                      int* __restrict__ rowptr,
                                                      int* __restrict__ cursor,
                                                      float* __restrict__ dinv) {
    __shared__ int part[1024];
    int tid = threadIdx.x;
    int4 c4[4];
#pragma unroll
    for (int j = 0; j < 4; j++) c4[j] = ((const int4*)cnt)[tid * 4 + j];
    int v[16] = {c4[0].x, c4[0].y, c4[0].z, c4[0].w, c4[1].x, c4[1].y, c4[1].z, c4[1].w,
                 c4[2].x, c4[2].y, c4[2].z, c4[2].w, c4[3].x, c4[3].y, c4[3].z, c4[3].w};
    int s = 0;
#pragma unroll
    for (int j = 0; j < 16; j++) s += v[j];
    part[tid] = s;
    __syncthreads();
    for (int off = 1; off < 1024; off <<= 1) {
        int t = (tid >= off) ? part[tid - off] : 0;
        __syncthreads();
        part[tid] += t;
        __syncthreads();
    }
    int running = part[tid] - s;
    int rp[16];
    float dv[16];
#pragma unroll
    for (int j = 0; j < 16; j++) {
        rp[j] = running;
        running += v[j];
        dv[j] = rsqrtf((float)(v[j] + 1));  // +1 self loop
    }
#pragma unroll
    for (int j = 0; j < 4; j++) {
        int4 r4; r4.x = rp[j*4]; r4.y = rp[j*4+1]; r4.z = rp[j*4+2]; r4.w = rp[j*4+3];
        ((int4*)rowptr)[tid * 4 + j] = r4;
        ((int4*)cursor)[tid * 4 + j] = r4;
        float4 d4; d4.x = dv[j*4]; d4.y = dv[j*4+1]; d4.z = dv[j*4+2]; d4.w = dv[j*4+3];
        ((float4*)dinv)[tid * 4 + j] = d4;
    }
    if (tid == 1023) rowptr[NN] = part[1023];
}

__global__ void scatter_kernel(const int* __restrict__ src, const int* __restrict__ dst,
                               int* __restrict__ cursor, int* __restrict__ col) {
    int e = blockIdx.x * blockDim.x + threadIdx.x;
    if (e < EE) {
        int d = dst[e];
        int pos = atomicAdd(&cursor[d], 1);
        col[pos] = src[e];
    }
}

// ---------------------------------------------------------------- GEMM (fp32, 64x64 tile)
__global__ __launch_bounds__(256) void gemm_k(const float* __restrict__ A,
                                              const float* __restrict__ B,
                                              const float* __restrict__ bias,
                                              float* __restrict__ C,
                                              int M, int Nn, int K, int act) {
    __shared__ float As[16][68];
    __shared__ float Bs[16][68];
    int tid = threadIdx.x;
    int m0 = blockIdx.y * 64;
    int n0 = blockIdx.x * 64;
    int ty = tid >> 4, tx = tid & 15;
    float acc[4][4] = {{0.f}};
    for (int k0 = 0; k0 < K; k0 += 16) {
#pragma unroll
        for (int l = 0; l < 4; l++) {
            int idx = tid + l * 256;
            int i = idx >> 4, j = idx & 15;
            As[j][i] = A[(size_t)(m0 + i) * K + k0 + j];
        }
#pragma unroll
        for (int l = 0; l < 4; l++) {
            int idx = tid + l * 256;
            int i = idx >> 6, j = idx & 63;
            int n = n0 + j;
            Bs[i][j] = (n < Nn) ? B[(size_t)(k0 + i) * Nn + n] : 0.f;
        }
        __syncthreads();
#pragma unroll
        for (int kk = 0; kk < 16; kk++) {
            float4 a4 = *(const float4*)&As[kk][ty * 4];
            float4 b4 = *(const float4*)&Bs[kk][tx * 4];
            float av[4] = {a4.x, a4.y, a4.z, a4.w};
            float bv[4] = {b4.x, b4.y, b4.z, b4.w};
#pragma unroll
            for (int r = 0; r < 4; r++)
#pragma unroll
                for (int c = 0; c < 4; c++) acc[r][c] = fmaf(av[r], bv[c], acc[r][c]);
        }
        __syncthreads();
    }
    int nb = n0 + tx * 4;
    if (nb < Nn) {
        float4 bi4 = {0.f, 0.f, 0.f, 0.f};
        if (bias) bi4 = *(const float4*)&bias[nb];
#pragma unroll
        for (int r = 0; r < 4; r++) {
            int m = m0 + ty * 4 + r;
            float4 v;
            v.x = acc[r][0] + bi4.x; v.y = acc[r][1] + bi4.y;
            v.z = acc[r][2] + bi4.z; v.w = acc[r][3] + bi4.w;
            if (act == 1) {
                v.x = fmaxf(v.x, 0.f); v.y = fmaxf(v.y, 0.f);
                v.z = fmaxf(v.z, 0.f); v.w = fmaxf(v.w, 0.f);
            }
            *(float4*)&C[(size_t)m * Nn + nb] = v;
        }
    }
}

// ---------------------------------------------------------------- GEMM with A^T input (A stored [K][M])
__global__ __launch_bounds__(256) void gemm_at(const float* __restrict__ AT,
                                               const float* __restrict__ B,
                                               float* __restrict__ C,
                                               int M, int Nn, int K) {
    __shared__ float As[16][68];
    __shared__ float Bs[16][68];
    int tid = threadIdx.x;
    int m0 = blockIdx.y * 64;
    int n0 = blockIdx.x * 64;
    int ty = tid >> 4, tx = tid & 15;
    float acc[4][4] = {{0.f}};
    for (int k0 = 0; k0 < K; k0 += 16) {
#pragma unroll
        for (int l = 0; l < 4; l++) {
            int idx = tid + l * 256;
            int kk = idx >> 6, i = idx & 63;
            As[kk][i] = AT[(size_t)(k0 + kk) * M + m0 + i];
        }
#pragma unroll
        for (int l = 0; l < 4; l++) {
            int idx = tid + l * 256;
            int i = idx >> 6, j = idx & 63;
            int n = n0 + j;
            Bs[i][j] = (n < Nn) ? B[(size_t)(k0 + i) * Nn + n] : 0.f;
        }
        __syncthreads();
#pragma unroll
        for (int kk = 0; kk < 16; kk++) {
            float4 a4 = *(const float4*)&As[kk][ty * 4];
            float4 b4 = *(const float4*)&Bs[kk][tx * 4];
            float av[4] = {a4.x, a4.y, a4.z, a4.w};
            float bv[4] = {b4.x, b4.y, b4.z, b4.w};
#pragma unroll
            for (int r = 0; r < 4; r++)
#pragma unroll
                for (int c = 0; c < 4; c++) acc[r][c] = fmaf(av[r], bv[c], acc[r][c]);
        }
        __syncthreads();
    }
    int nb = n0 + tx * 4;
    if (nb < Nn) {
#pragma unroll
        for (int r = 0; r < 4; r++) {
            int m = m0 + ty * 4 + r;
            float4 v;
            v.x = acc[r][0]; v.y = acc[r][1]; v.z = acc[r][2]; v.w = acc[r][3];
            *(float4*)&C[(size_t)m * Nn + nb] = v;
        }
    }
}

// ---------------------------------------------------------------- GCN gather (CSR by dest), 4-deep edge unroll
__global__ void gcn_gather(const float* __restrict__ xw, const int* __restrict__ rowptr,
                           const int* __restrict__ col, const float* __restrict__ dinv,
                           const float* __restrict__ b, float* __restrict__ out) {
    int n = blockIdx.x;
    int f = threadIdx.x;  // 128
    float dn = dinv[n];
    float acc = xw[(size_t)n * HH + f] * dn * dn;  // self loop
    int beg = rowptr[n], end = rowptr[n + 1];
    int e = beg;
    for (; e + 4 <= end; e += 4) {
        int s0 = col[e], s1 = col[e + 1], s2 = col[e + 2], s3 = col[e + 3];
        float w0 = dinv[s0] * dn, w1 = dinv[s1] * dn, w2 = dinv[s2] * dn, w3 = dinv[s3] * dn;
        float v0 = xw[(size_t)s0 * HH + f];
        float v1 = xw[(size_t)s1 * HH + f];
        float v2 = xw[(size_t)s2 * HH + f];
        float v3 = xw[(size_t)s3 * HH + f];
        acc = fmaf(v0, w0, acc);
        acc = fmaf(v1, w1, acc);
        acc = fmaf(v2, w2, acc);
        acc = fmaf(v3, w3, acc);
    }
    for (; e < end; e++) {
        int s0 = col[e];
        acc = fmaf(xw[(size_t)s0 * HH + f], dinv[s0] * dn, acc);
    }
    acc += b[f];
    out[(size_t)n * HH + f] = fmaxf(acc, 0.f);
}

// ---------------------------------------------------------------- conv + silu, transposed outputs
__global__ __launch_bounds__(256) void conv_silu_t(const float* __restrict__ xz,
                                                   const float* __restrict__ cw,
                                                   const float* __restrict__ cb,
                                                   float* __restrict__ xst,
                                                   float* __restrict__ szt) {
    __shared__ float tile[67][65];
    int tid = threadIdx.x;
    int t0 = blockIdx.x * 64;
    int c0 = blockIdx.y * 64;
#pragma unroll
    for (int l = 0; l < 17; l++) {
        int idx = tid + l * 256;
        if (idx < 67 * 64) {
            int r = idx >> 6, c = idx & 63;
            int gt = t0 - 3 + r;
            tile[r][c] = (gt >= 0) ? xz[(size_t)gt * 512 + c0 + c] : 0.f;
        }
    }
    __syncthreads();
    int tl = tid & 63;
    int d0 = tid >> 6;
    if (c0 < 256) {
#pragma unroll
        for (int l = 0; l < 16; l++) {
            int dl = d0 + l * 4;
            int dg = c0 + dl;
            float acc = cb[dg];
#pragma unroll
            for (int k = 0; k < DC; k++)
                acc = fmaf(tile[tl + k][dl], cw[dg * DC + k], acc);
            xst[dg * NN + t0 + tl] = siluf(acc);
        }
    } else {
#pragma unroll
        for (int l = 0; l < 16; l++) {
            int dl = d0 + l * 4;
            int dg = c0 - 256 + dl;
            szt[dg * NN + t0 + tl] = siluf(tile[tl + 3][dl]);
        }
    }
}

// ---------------------------------------------------------------- transpose dbl [NN][40] -> [40][NN]
__global__ __launch_bounds__(256) void transpose_dbl(const float* __restrict__ dbl,
                                                     float* __restrict__ dblt) {
    __shared__ float tile[64][41];
    int tid = threadIdx.x;
    int t0 = blockIdx.x * 64;
#pragma unroll
    for (int l = 0; l < 10; l++) {
        int idx = tid + l * 256;
        int r = idx / 40, c = idx - r * 40;
        tile[r][c] = dbl[(size_t)(t0 + r) * 40 + c];
    }
    __syncthreads();
#pragma unroll
    for (int l = 0; l < 10; l++) {
        int idx = tid + l * 256;
        int c = idx >> 6, t = idx & 63;
        dblt[c * NN + t0 + t] = tile[t][c];
    }
}

// ---------------------------------------------------------------- dt (transposed): DT_T[d][t]
__global__ __launch_bounds__(256) void dt_t_kernel(const float* __restrict__ dblt,
                                                   const float* __restrict__ W_dt,
                                                   const float* __restrict__ b_dt,
                                                   float* __restrict__ dtt) {
    int t = blockIdx.x * 256 + threadIdx.x;
    int d = blockIdx.y;
    float acc = b_dt[d];
#pragma unroll
    for (int j = 0; j < DTR; j++)
        acc = fmaf(dblt[j * NN + t], W_dt[j * DI + d], acc);
    dtt[d * NN + t] = softplusf(acc);
}

// ---------------------------------------------------------------- Mamba scan (3-phase, R4 structure)
// G=2: sg = lane&7 (states 2sg, 2sg+1), dl = lane>>3. Block covers 32 d; grid (8, NCH).
// B (and C in phase3) staged in LDS; y staged in LDS and stored as full 256B lines.
__global__ __launch_bounds__(256, 8) void scan_phase1(const float* __restrict__ dtt,
                                                      const float* __restrict__ xst,
                                                      const float* __restrict__ dblt,
                                                      const float* __restrict__ A_log,
                                                      float* __restrict__ chkP,
                                                      float* __restrict__ chkH) {
    __shared__ float Bs[16][68];
    int tid = threadIdx.x;
    int wave = tid >> 6, lane = tid & 63;
    int sg = lane & 7, dl = lane >> 3;
    int d = blockIdx.x * 32 + wave * 8 + dl;
    int chunk = blockIdx.y;
    int t0 = chunk * CHLEN;
    int s0 = 2 * sg;
    {   // stage B rows 8..23 (16 s x 64 t), one float4 per thread
        int s = tid >> 4, t4 = (tid & 15) * 4;
        *(float4*)&Bs[s][t4] = *(const float4*)&dblt[(8 + s) * NN + t0 + t4];
    }
    float A0 = -expf(A_log[d * DS + s0]);
    float A1 = -expf(A_log[d * DS + s0 + 1]);
    const float* dtp = dtt + d * NN + t0;
    const float* xsp = xst + d * NN + t0;
    __syncthreads();
    float h0 = 0.f, h1 = 0.f, P0 = 1.f, P1 = 1.f;
    float4 dA = *(const float4*)dtp;
    float4 xA = *(const float4*)xsp;
    float4 dB = *(const float4*)(dtp + 4);
    float4 xB = *(const float4*)(xsp + 4);
    for (int i = 0; i < CHLEN; i += 4) {
        float4 dC, xC;
        if (i + 8 < CHLEN) {
            dC = *(const float4*)(dtp + i + 8);
            xC = *(const float4*)(xsp + i + 8);
        }
        float4 b04 = *(const float4*)&Bs[s0][i];
        float4 b14 = *(const float4*)&Bs[s0 + 1][i];
#define P1S(U) { float dtv = dA.U; float a0 = __expf(dtv * A0); float a1 = __expf(dtv * A1); \
        float dx = dtv * xA.U; h0 = fmaf(a0, h0, dx * b04.U); h1 = fmaf(a1, h1, dx * b14.U); \
        P0 *= a0; P1 *= a1; }
        P1S(x) P1S(y) P1S(z) P1S(w)
#undef P1S
        dA = dB; xA = xB; dB = dC; xB = xC;
    }
    int idx = chunk * 4096 + d * DS + s0;
    float2 vP; vP.x = P0; vP.y = P1;
    float2 vH; vH.x = h0; vH.y = h1;
    *(float2*)(chkP + idx) = vP;
    *(float2*)(chkH + idx) = vH;
}

// phase2a: compose chunks within each group of GL -> (GP, GH) per (group, idx)
__global__ void scan_phase2a(const float* __restrict__ chkP, const float* __restrict__ chkH,
                             float* __restrict__ gp, float* __restrict__ gh) {
    int g = blockIdx.x * blockDim.x + threadIdx.x;  // 4096*NG
    int idx = g & 4095;
    int grp = g >> 12;
    int c0 = grp * GL;
    float P = 1.f, H = 0.f;
    for (int j = 0; j < GL; j += 4) {
        float p[4], q[4];
#pragma unroll
        for (int jj = 0; jj < 4; jj++) {
            p[jj] = chkP[(c0 + j + jj) * 4096 + idx];
            q[jj] = chkH[(c0 + j + jj) * 4096 + idx];
        }
#pragma unroll
        for (int jj = 0; jj < 4; jj++) {
            H = fmaf(p[jj], H, q[jj]);
            P *= p[jj];
        }
    }
    gp[grp * 4096 + idx] = P;
    gh[grp * 4096 + idx] = H;
}

// phase2b: scan across the NG groups -> group-initial states
__global__ void scan_phase2b(const float* __restrict__ gp, const float* __restrict__ gh,
                             float* __restrict__ gini) {
    int idx = blockIdx.x * blockDim.x + threadIdx.x;  // 4096
    float h = 0.f;
#pragma unroll
    for (int g = 0; g < NG; g++) {
        gini[g * 4096 + idx] = h;
        h = fmaf(gp[g * 4096 + idx], h, gh[g * 4096 + idx]);
    }
}

// phase2c: replay within group, writing per-chunk initial states
__global__ void scan_phase2c(const float* __restrict__ chkP, const float* __restrict__ chkH,
                             const float* __restrict__ gini, float* __restrict__ init) {
    int g = blockIdx.x * blockDim.x + threadIdx.x;
    int idx = g & 4095;
    int grp = g >> 12;
    int c0 = grp * GL;
    float h = gini[grp * 4096 + idx];
    for (int j = 0; j < GL; j += 4) {
        float p[4], q[4];
#pragma unroll
        for (int jj = 0; jj < 4; jj++) {
            p[jj] = chkP[(c0 + j + jj) * 4096 + idx];
            q[jj] = chkH[(c0 + j + jj) * 4096 + idx];
        }
#pragma unroll
        for (int jj = 0; jj < 4; jj++) {
            init[(c0 + j + jj) * 4096 + idx] = h;
            h = fmaf(p[jj], h, q[jj]);
        }
    }
}

__global__ __launch_bounds__(256, 8) void scan_phase3(const float* __restrict__ dtt,
                                                      const float* __restrict__ xst,
                                                      const float* __restrict__ dblt,
                                                      const float* __restrict__ A_log,
                                                      const float* __restrict__ init,
                                                      const float* __restrict__ D_p,
                                                      const float* __restrict__ szt,
                                                      float* __restrict__ yt) {
    __shared__ float Bs[16][68];
    __shared__ float Cs[16][68];
    __shared__ float Ys[4][8][68];
    int tid = threadIdx.x;
    int wave = tid >> 6, lane = tid & 63;
    int sg = lane & 7, dl = lane >> 3;
    int d = blockIdx.x * 32 + wave * 8 + dl;
    int chunk = blockIdx.y;
    int t0 = chunk * CHLEN;
    int s0 = 2 * sg;
    {   // stage B (rows 8..23) and C (rows 24..39)
        int s = tid >> 4, t4 = (tid & 15) * 4;
        *(float4*)&Bs[s][t4] = *(const float4*)&dblt[(8 + s) * NN + t0 + t4];
        *(float4*)&Cs[s][t4] = *(const float4*)&dblt[(24 + s) * NN + t0 + t4];
    }
    float A0 = -expf(A_log[d * DS + s0]);
    float A1 = -expf(A_log[d * DS + s0 + 1]);
    float Dd = D_p[d];
    const float* dtp = dtt + d * NN + t0;
    const float* xsp = xst + d * NN + t0;
    const float* szp = szt + d * NN + t0;
    float2 ini = *(const float2*)(init + chunk * 4096 + d * DS + s0);
    float h0 = ini.x, h1 = ini.y;
    __syncthreads();
    float4 dA = *(const float4*)dtp;
    float4 xA = *(const float4*)xsp;
    float4 zA = *(const float4*)szp;
    float4 dB = *(const float4*)(dtp + 4);
    float4 xB = *(const float4*)(xsp + 4);
    float4 zB = *(const float4*)(szp + 4);
    for (int i = 0; i < CHLEN; i += 4) {
        float4 dC, xC, zC;
        if (i + 8 < CHLEN) {
            dC = *(const float4*)(dtp + i + 8);
            xC = *(const float4*)(xsp + i + 8);
            zC = *(const float4*)(szp + i + 8);
        }
        float4 b04 = *(const float4*)&Bs[s0][i];
        float4 b14 = *(const float4*)&Bs[s0 + 1][i];
        float4 c04 = *(const float4*)&Cs[s0][i];
        float4 c14 = *(const float4*)&Cs[s0 + 1][i];
        float4 yv;
#define P3S(U) { float dtv = dA.U; float a0 = __expf(dtv * A0); float a1 = __expf(dtv * A1); \
        float dx = dtv * xA.U; h0 = fmaf(a0, h0, dx * b04.U); h1 = fmaf(a1, h1, dx * b14.U); \
        float c = fmaf(h1, c14.U, h0 * c04.U); \
        c += __shfl_xor(c, 1); c += __shfl_xor(c, 2); c += __shfl_xor(c, 4); \
        yv.U = (c + Dd * xA.U) * zA.U; }
        P3S(x) P3S(y) P3S(z) P3S(w)
#undef P3S
        if (sg == 0) *(float4*)&Ys[wave][dl][i] = yv;
        dA = dB; xA = xB; zA = zB; dB = dC; xB = xC; zB = zC;
    }
    __syncthreads();
#pragma unroll
    for (int r = 0; r < 8; r++)
        yt[(size_t)(blockIdx.x * 32 + wave * 8 + r) * NN + t0 + lane] = Ys[wave][r][lane];
}

// ---------------------------------------------------------------- add + LayerNorm (wave per row)
__global__ void add_ln(const float* __restrict__ hg, const float* __restrict__ hm,
                       const float* __restrict__ gamma, const float* __restrict__ beta,
                       float* __restrict__ out) {
    int row = blockIdx.x * 4 + (threadIdx.x >> 6);
    int lane = threadIdx.x & 63;
    size_t base = (size_t)row * HH;
    float v0 = hg[base + lane] + hm[base + lane];
    float v1 = hg[base + 64 + lane] + hm[base + 64 + lane];
    float sum = v0 + v1;
#pragma unroll
    for (int m = 32; m >= 1; m >>= 1) sum += __shfl_xor(sum, m);
    float mu = sum * (1.f / 128.f);
    float d0 = v0 - mu, d1 = v1 - mu;
    float vs = d0 * d0 + d1 * d1;
#pragma unroll
    for (int m = 32; m >= 1; m >>= 1) vs += __shfl_xor(vs, m);
    float inv = rsqrtf(vs * (1.f / 128.f) + 1e-5f);
    out[base + lane] = d0 * inv * gamma[lane] + beta[lane];
    out[base + 64 + lane] = d1 * inv * gamma[64 + lane] + beta[64 + lane];
}

// ---------------------------------------------------------------- pooling (batch sorted), 4-row unroll
__global__ void pool_kernel(const float* __restrict__ hf, const int* __restrict__ batch,
                            float* __restrict__ ge, int* __restrict__ counts) {
    int f = threadIdx.x;  // 128
    int r0 = blockIdx.x * 128;
    int gcur = batch[r0];
    float acc = 0.f;
    int cnt = 0;
    for (int i = 0; i < 128; i += 4) {
        int r = r0 + i;
        int g0 = batch[r], g3 = batch[r + 3];
        float v0 = hf[(size_t)r * HH + f];
        float v1 = hf[(size_t)(r + 1) * HH + f];
        float v2 = hf[(size_t)(r + 2) * HH + f];
        float v3 = hf[(size_t)(r + 3) * HH + f];
        if (g0 == gcur && g3 == gcur) {
            acc += (v0 + v1) + (v2 + v3);
            cnt += 4;
        } else {
            int gs[4] = {g0, batch[r + 1], batch[r + 2], g3};
            float vs[4] = {v0, v1, v2, v3};
#pragma unroll
            for (int k = 0; k < 4; k++) {
                if (gs[k] != gcur) {
                    atomicAdd(&ge[gcur * HH + f], acc);
                    if (f == 0) atomicAdd(&counts[gcur], cnt);
                    acc = 0.f; cnt = 0; gcur = gs[k];
                }
                acc += vs[k];
                cnt++;
            }
        }
    }
    atomicAdd(&ge[gcur * HH + f], acc);
    if (f == 0) atomicAdd(&counts[gcur], cnt);
}

__global__ void ge_norm(float* __restrict__ ge, const int* __restrict__ counts) {
    int idx = blockIdx.x * blockDim.x + threadIdx.x;
    if (idx < BB * HH) {
        int b = idx >> 7;
        ge[idx] /= fmaxf((float)counts[b], 1.f);
    }
}

// ---------------------------------------------------------------- output heads
__global__ void heads_kernel(const float* __restrict__ ge,
                             const float* Wc, const float* bc, const float* Wh, const float* bh,
                             const float* Wt, const float* bt, const float* Wp1, const float* bp1,
                             const float* Wp2, const float* bp2, const float* Wd, const float* bd,
                             const float* Ws, const float* bs, float* __restrict__ out) {
    int col = blockIdx.x * blockDim.x + threadIdx.x;
    int b = blockIdx.y;
    if (col >= OUTW) return;
    const float* W; const float* bi; int lc, w;
    if (col < 1)         { W = Wc;  bi = bc;  lc = col;        w = 1; }
    else if (col < 5)    { W = Wh;  bi = bh;  lc = col - 1;    w = 4; }
    else if (col < 8)    { W = Wt;  bi = bt;  lc = col - 5;    w = 3; }
    else if (col < 520)  { W = Wp1; bi = bp1; lc = col - 8;    w = 512; }
    else if (col < 1032) { W = Wp2; bi = bp2; lc = col - 520;  w = 512; }
    else if (col < 1544) { W = Wd;  bi = bd;  lc = col - 1032; w = 512; }
    else                 { W = Ws;  bi = bs;  lc = col - 1544; w = 8; }
    float acc = bi[lc];
#pragma unroll 8
    for (int f = 0; f < HH; f++) acc = fmaf(ge[b * HH + f], W[f * w + lc], acc);
    out[(size_t)b * OUTW + col] = acc;
}

// ---------------------------------------------------------------- launch
extern "C" void kernel_launch(void* const* d_in, const int* in_sizes, int n_in,
                              void* d_out, int out_size, void* d_ws, size_t ws_size,
                              hipStream_t stream) {
    const float* nf      = (const float*)d_in[0];
    const int*   ei      = (const int*)d_in[1];
    const int*   batch   = (const int*)d_in[2];
    const float* W_in    = (const float*)d_in[3];
    const float* b_in    = (const float*)d_in[4];
    const float* W_g1    = (const float*)d_in[5];
    const float* b_g1    = (const float*)d_in[6];
    const float* W_g2    = (const float*)d_in[7];
    const float* b_g2    = (const float*)d_in[8];
    const float* W_inproj= (const float*)d_in[9];
    const float* conv_w  = (const float*)d_in[10];
    const float* conv_b  = (const float*)d_in[11];
    const float* W_xproj = (const float*)d_in[12];
    const float* W_dt    = (const float*)d_in[13];
    const float* b_dt    = (const float*)d_in[14];
    const float* A_log   = (const float*)d_in[15];
    const float* D_p     = (const float*)d_in[16];
    const float* W_out   = (const float*)d_in[17];
    const float* gamma   = (const float*)d_in[18];
    const float* beta    = (const float*)d_in[19];
    const float* Wc = (const float*)d_in[20]; const float* bc = (const float*)d_in[21];
    const float* Wh = (const float*)d_in[22]; const float* bh = (const float*)d_in[23];
    const float* Wt = (const float*)d_in[24]; const float* bt = (const float*)d_in[25];
    const float* Wp1= (const float*)d_in[26]; const float* bp1= (const float*)d_in[27];
    const float* Wp2= (const float*)d_in[28]; const float* bp2= (const float*)d_in[29];
    const float* Wd = (const float*)d_in[30]; const float* bd = (const float*)d_in[31];
    const float* Ws = (const float*)d_in[32]; const float* bs = (const float*)d_in[33];

    const int* e_src = ei;
    const int* e_dst = ei + EE;

    // workspace layout (floats, then ints)
    float* w = (float*)d_ws;
    size_t o = 0;
    float* F0   = w + o; o += (size_t)NN * HH;   // dead during scan -> CHP/CHH
    float* F1   = w + o; o += (size_t)NN * HH;   // dead during scan -> INI
    float* F2   = w + o; o += (size_t)NN * HH;
    float* XZ   = w + o; o += (size_t)NN * 512;  // dead after conv_silu_t; reused:
    float* DTT  = XZ;                             //   DT_T [DI][NN]
    float* YT   = XZ + (size_t)NN * DI;           //   y^T  [DI][NN]
    float* XST  = w + o; o += (size_t)NN * DI;   // x (conv+silu), transposed [DI][NN]
    float* SZT  = w + o; o += (size_t)NN * DI;   // silu(z), transposed [DI][NN]
    float* DBL  = w + o; o += (size_t)NN * 40;   // dead after transpose_dbl -> GP/GH/GINI
    float* DBLT = w + o; o += (size_t)NN * 40;   // [40][NN]; rows 8..23 = B^T, 24..39 = C^T
    float* GE   = w + o; o += BB * HH;
    float* DINV = w + o; o += NN;
    int* ip = (int*)(w + o);
    int* CNT    = ip; ip += NN;
    int* ROWPTR = ip; ip += NN + 1;
    int* CURSOR = ip; ip += NN;
    int* COL    = ip; ip += EE;
    int* COUNTS = ip; ip += BB;

    // overlays (regions dead during the scan)
    float* CHP  = F0;                         // NCH*4096 = 1M floats
    float* CHH  = F0 + (size_t)NCH * 4096;    // 1M floats (F0 holds 2M)
    float* INI  = F1;                         // NCH*4096 = 1M floats (F1 holds 2M)
    float* GP   = DBL;                        // NG*4096
    float* GH   = DBL + NG * 4096;
    float* GINI = DBL + 2 * NG * 4096;

    hipMemsetAsync(CNT, 0, NN * sizeof(int), stream);
    hipMemsetAsync(GE, 0, BB * HH * sizeof(float), stream);
    hipMemsetAsync(COUNTS, 0, BB * sizeof(int), stream);

    // CSR build
    deg_kernel<<<EE / 256, 256, 0, stream>>>(e_dst, CNT);
    prefix_kernel<<<1, 1024, 0, stream>>>(CNT, ROWPTR, CURSOR, DINV);
    scatter_kernel<<<EE / 256, 256, 0, stream>>>(e_src, e_dst, CURSOR, COL);

    // h0 = relu(nf @ W_in + b_in)
    gemm_k<<<dim3(2, NN / 64), 256, 0, stream>>>(nf, W_in, b_in, F0, NN, HH, FF, 1);
    // GCN layer 1
    gemm_k<<<dim3(2, NN / 64), 256, 0, stream>>>(F0, W_g1, nullptr, F1, NN, HH, HH, 0);
    gcn_gather<<<NN, HH, 0, stream>>>(F1, ROWPTR, COL, DINV, b_g1, F0);
    // GCN layer 2
    gemm_k<<<dim3(2, NN / 64), 256, 0, stream>>>(F0, W_g2, nullptr, F1, NN, HH, HH, 0);
    gcn_gather<<<NN, HH, 0, stream>>>(F1, ROWPTR, COL, DINV, b_g2, F2);  // F2 = h_gnn

    // xz = h_gnn @ W_inproj
    gemm_k<<<dim3(8, NN / 64), 256, 0, stream>>>(F2, W_inproj, nullptr, XZ, NN, 512, HH, 0);
    // conv + silu -> XST; silu(z) -> SZT (both transposed)
    conv_silu_t<<<dim3(NN / 64, 8), 256, 0, stream>>>(XZ, conv_w, conv_b, XST, SZT);
    // dbl = xs @ W_xproj (A^T layout)
    gemm_at<<<dim3(1, NN / 64), 256, 0, stream>>>(XST, W_xproj, DBL, NN, 40, DI);
    // transpose dbl -> DBLT
    transpose_dbl<<<NN / 64, 256, 0, stream>>>(DBL, DBLT);
    // dt (transposed) — overwrites XZ region (dead)
    dt_t_kernel<<<dim3(NN / 256, DI), 256, 0, stream>>>(DBLT, W_dt, b_dt, DTT);

    // Mamba scan
    scan_phase1<<<dim3(8, NCH), 256, 0, stream>>>(DTT, XST, DBLT, A_log, CHP, CHH);
    scan_phase2a<<<(4096 * NG) / 256, 256, 0, stream>>>(CHP, CHH, GP, GH);
    scan_phase2b<<<16, 256, 0, stream>>>(GP, GH, GINI);
    scan_phase2c<<<(4096 * NG) / 256, 256, 0, stream>>>(CHP, CHH, GINI, INI);
    scan_phase3<<<dim3(8, NCH), 256, 0, stream>>>(DTT, XST, DBLT, A_log, INI, D_p, SZT, YT);

    // h_mamba = y @ W_out -> F1 (y stored transposed)
    gemm_at<<<dim3(2, NN / 64), 256, 0, stream>>>(YT, W_out, F1, NN, HH, DI);
    // hh = h_gnn + h_mamba; LayerNorm -> F0
    add_ln<<<NN / 4, 256, 0, stream>>>(F2, F1, gamma, beta, F0);

    // pooling
    pool_kernel<<<NN / 128, HH, 0, stream>>>(F0, batch, GE, COUNTS);
    ge_norm<<<(BB * HH + 255) / 256, 256, 0, stream>>>(GE, COUNTS);

    // heads
    heads_kernel<<<dim3((OUTW + 127) / 128, BB), 128, 0, stream>>>(
        GE, Wc, bc, Wh, bh, Wt, bt, Wp1, bp1, Wp2, bp2, Wd, bd, Ws, bs, (float*)d_out);
}

// Round 7
// 450.132 us; speedup vs baseline: 2.1842x; 1.6677x over previous
//
#include <hip/hip_runtime.h>
#include <math.h>

#define NN 16384
#define EE 262144
#define FF 32
#define HH 128
#define BB 16
#define DI 256
#define DS 16
#define DC 4
#define DTR 8
#define OUTW 1552
#define NCH 256
#define CHLEN 64    // NCH*CHLEN == NN
#define NG 8        // phase2 groups
#define GL 32       // chunks per group; NG*GL == NCH

// ---------------------------------------------------------------- utilities
__device__ __forceinline__ float siluf(float v) { return v / (1.f + __expf(-v)); }
__device__ __forceinline__ float softplusf(float v) {
    return fmaxf(v, 0.f) + log1pf(expf(-fabsf(v)));
}

// ---------------------------------------------------------------- CSR build
__global__ void deg_kernel(const int* __restrict__ dst, int* __restrict__ cnt) {
    int e = blockIdx.x * blockDim.x + threadIdx.x;
    if (e < EE) atomicAdd(&cnt[dst[e]], 1);
}

__global__ __launch_bounds__(1024) void prefix_kernel(const int* __restrict__ cnt,
                                                      int* __restrict__ rowptr,
                                                      int* __restrict__ cursor,
                                                      float* __restrict__ dinv) {
    __shared__ int part[1024];
    int tid = threadIdx.x;
    int4 c4[4];
#pragma unroll
    for (int j = 0; j < 4; j++) c4[j] = ((const int4*)cnt)[tid * 4 + j];
    int v[16] = {c4[0].x, c4[0].y, c4[0].z, c4[0].w, c4[1].x, c4[1].y, c4[1].z, c4[1].w,
                 c4[2].x, c4[2].y, c4[2].z, c4[2].w, c4[3].x, c4[3].y, c4[3].z, c4[3].w};
    int s = 0;
#pragma unroll
    for (int j = 0; j < 16; j++) s += v[j];
    part[tid] = s;
    __syncthreads();
    for (int off = 1; off < 1024; off <<= 1) {
        int t = (tid >= off) ? part[tid - off] : 0;
        __syncthreads();
        part[tid] += t;
        __syncthreads();
    }
    int running = part[tid] - s;
    int rp[16];
    float dv[16];
#pragma unroll
    for (int j = 0; j < 16; j++) {
        rp[j] = running;
        running += v[j];
        dv[j] = rsqrtf((float)(v[j] + 1));  // +1 self loop
    }
#pragma unroll
    for (int j = 0; j < 4; j++) {
        int4 r4; r4.x = rp[j*4]; r4.y = rp[j*4+1]; r4.z = rp[j*4+2]; r4.w = rp[j*4+3];
        ((int4*)rowptr)[tid * 4 + j] = r4;
        ((int4*)cursor)[tid * 4 + j] = r4;
        float4 d4; d4.x = dv[j*4]; d4.y = dv[j*4+1]; d4.z = dv[j*4+2]; d4.w = dv[j*4+3];
        ((float4*)dinv)[tid * 4 + j] = d4;
    }
    if (tid == 1023) rowptr[NN] = part[1023];
}

__global__ void scatter_kernel(const int* __restrict__ src, const int* __restrict__ dst,
                               int* __restrict__ cursor, int* __restrict__ col) {
    int e = blockIdx.x * blockDim.x + threadIdx.x;
    if (e < EE) {
        int d = dst[e];
        int pos = atomicAdd(&cursor[d], 1);
        col[pos] = src[e];
    }
}

// ---------------------------------------------------------------- GEMM (fp32, 64x64 tile)
__global__ __launch_bounds__(256) void gemm_k(const float* __restrict__ A,
                                              const float* __restrict__ B,
                                              const float* __restrict__ bias,
                                              float* __restrict__ C,
                                              int M, int Nn, int K, int act) {
    __shared__ float As[16][68];
    __shared__ float Bs[16][68];
    int tid = threadIdx.x;
    int m0 = blockIdx.y * 64;
    int n0 = blockIdx.x * 64;
    int ty = tid >> 4, tx = tid & 15;
    float acc[4][4] = {{0.f}};
    for (int k0 = 0; k0 < K; k0 += 16) {
#pragma unroll
        for (int l = 0; l < 4; l++) {
            int idx = tid + l * 256;
            int i = idx >> 4, j = idx & 15;
            As[j][i] = A[(size_t)(m0 + i) * K + k0 + j];
        }
#pragma unroll
        for (int l = 0; l < 4; l++) {
            int idx = tid + l * 256;
            int i = idx >> 6, j = idx & 63;
            int n = n0 + j;
            Bs[i][j] = (n < Nn) ? B[(size_t)(k0 + i) * Nn + n] : 0.f;
        }
        __syncthreads();
#pragma unroll
        for (int kk = 0; kk < 16; kk++) {
            float4 a4 = *(const float4*)&As[kk][ty * 4];
            float4 b4 = *(const float4*)&Bs[kk][tx * 4];
            float av[4] = {a4.x, a4.y, a4.z, a4.w};
            float bv[4] = {b4.x, b4.y, b4.z, b4.w};
#pragma unroll
            for (int r = 0; r < 4; r++)
#pragma unroll
                for (int c = 0; c < 4; c++) acc[r][c] = fmaf(av[r], bv[c], acc[r][c]);
        }
        __syncthreads();
    }
    int nb = n0 + tx * 4;
    if (nb < Nn) {
        float4 bi4 = {0.f, 0.f, 0.f, 0.f};
        if (bias) bi4 = *(const float4*)&bias[nb];
#pragma unroll
        for (int r = 0; r < 4; r++) {
            int m = m0 + ty * 4 + r;
            float4 v;
            v.x = acc[r][0] + bi4.x; v.y = acc[r][1] + bi4.y;
            v.z = acc[r][2] + bi4.z; v.w = acc[r][3] + bi4.w;
            if (act == 1) {
                v.x = fmaxf(v.x, 0.f); v.y = fmaxf(v.y, 0.f);
                v.z = fmaxf(v.z, 0.f); v.w = fmaxf(v.w, 0.f);
            }
            *(float4*)&C[(size_t)m * Nn + nb] = v;
        }
    }
}

// ---------------------------------------------------------------- GEMM with A^T input (A stored [K][M])
__global__ __launch_bounds__(256) void gemm_at(const float* __restrict__ AT,
                                               const float* __restrict__ B,
                                               float* __restrict__ C,
                                               int M, int Nn, int K) {
    __shared__ float As[16][68];
    __shared__ float Bs[16][68];
    int tid = threadIdx.x;
    int m0 = blockIdx.y * 64;
    int n0 = blockIdx.x * 64;
    int ty = tid >> 4, tx = tid & 15;
    float acc[4][4] = {{0.f}};
    for (int k0 = 0; k0 < K; k0 += 16) {
#pragma unroll
        for (int l = 0; l < 4; l++) {
            int idx = tid + l * 256;
            int kk = idx >> 6, i = idx & 63;
            As[kk][i] = AT[(size_t)(k0 + kk) * M + m0 + i];
        }
#pragma unroll
        for (int l = 0; l < 4; l++) {
            int idx = tid + l * 256;
            int i = idx >> 6, j = idx & 63;
            int n = n0 + j;
            Bs[i][j] = (n < Nn) ? B[(size_t)(k0 + i) * Nn + n] : 0.f;
        }
        __syncthreads();
#pragma unroll
        for (int kk = 0; kk < 16; kk++) {
            float4 a4 = *(const float4*)&As[kk][ty * 4];
            float4 b4 = *(const float4*)&Bs[kk][tx * 4];
            float av[4] = {a4.x, a4.y, a4.z, a4.w};
            float bv[4] = {b4.x, b4.y, b4.z, b4.w};
#pragma unroll
            for (int r = 0; r < 4; r++)
#pragma unroll
                for (int c = 0; c < 4; c++) acc[r][c] = fmaf(av[r], bv[c], acc[r][c]);
        }
        __syncthreads();
    }
    int nb = n0 + tx * 4;
    if (nb < Nn) {
#pragma unroll
        for (int r = 0; r < 4; r++) {
            int m = m0 + ty * 4 + r;
            float4 v;
            v.x = acc[r][0]; v.y = acc[r][1]; v.z = acc[r][2]; v.w = acc[r][3];
            *(float4*)&C[(size_t)m * Nn + nb] = v;
        }
    }
}

// ---------------------------------------------------------------- GCN gather (CSR by dest), 4-deep edge unroll
__global__ void gcn_gather(const float* __restrict__ xw, const int* __restrict__ rowptr,
                           const int* __restrict__ col, const float* __restrict__ dinv,
                           const float* __restrict__ b, float* __restrict__ out) {
    int n = blockIdx.x;
    int f = threadIdx.x;  // 128
    float dn = dinv[n];
    float acc = xw[(size_t)n * HH + f] * dn * dn;  // self loop
    int beg = rowptr[n], end = rowptr[n + 1];
    int e = beg;
    for (; e + 4 <= end; e += 4) {
        int s0 = col[e], s1 = col[e + 1], s2 = col[e + 2], s3 = col[e + 3];
        float w0 = dinv[s0] * dn, w1 = dinv[s1] * dn, w2 = dinv[s2] * dn, w3 = dinv[s3] * dn;
        float v0 = xw[(size_t)s0 * HH + f];
        float v1 = xw[(size_t)s1 * HH + f];
        float v2 = xw[(size_t)s2 * HH + f];
        float v3 = xw[(size_t)s3 * HH + f];
        acc = fmaf(v0, w0, acc);
        acc = fmaf(v1, w1, acc);
        acc = fmaf(v2, w2, acc);
        acc = fmaf(v3, w3, acc);
    }
    for (; e < end; e++) {
        int s0 = col[e];
        acc = fmaf(xw[(size_t)s0 * HH + f], dinv[s0] * dn, acc);
    }
    acc += b[f];
    out[(size_t)n * HH + f] = fmaxf(acc, 0.f);
}

// ---------------------------------------------------------------- conv + silu, transposed outputs
__global__ __launch_bounds__(256) void conv_silu_t(const float* __restrict__ xz,
                                                   const float* __restrict__ cw,
                                                   const float* __restrict__ cb,
                                                   float* __restrict__ xst,
                                                   float* __restrict__ szt) {
    __shared__ float tile[67][65];
    int tid = threadIdx.x;
    int t0 = blockIdx.x * 64;
    int c0 = blockIdx.y * 64;
#pragma unroll
    for (int l = 0; l < 17; l++) {
        int idx = tid + l * 256;
        if (idx < 67 * 64) {
            int r = idx >> 6, c = idx & 63;
            int gt = t0 - 3 + r;
            tile[r][c] = (gt >= 0) ? xz[(size_t)gt * 512 + c0 + c] : 0.f;
        }
    }
    __syncthreads();
    int tl = tid & 63;
    int d0 = tid >> 6;
    if (c0 < 256) {
#pragma unroll
        for (int l = 0; l < 16; l++) {
            int dl = d0 + l * 4;
            int dg = c0 + dl;
            float acc = cb[dg];
#pragma unroll
            for (int k = 0; k < DC; k++)
                acc = fmaf(tile[tl + k][dl], cw[dg * DC + k], acc);
            xst[dg * NN + t0 + tl] = siluf(acc);
        }
    } else {
#pragma unroll
        for (int l = 0; l < 16; l++) {
            int dl = d0 + l * 4;
            int dg = c0 - 256 + dl;
            szt[dg * NN + t0 + tl] = siluf(tile[tl + 3][dl]);
        }
    }
}

// ---------------------------------------------------------------- transpose dbl [NN][40] -> [40][NN]
__global__ __launch_bounds__(256) void transpose_dbl(const float* __restrict__ dbl,
                                                     float* __restrict__ dblt) {
    __shared__ float tile[64][41];
    int tid = threadIdx.x;
    int t0 = blockIdx.x * 64;
#pragma unroll
    for (int l = 0; l < 10; l++) {
        int idx = tid + l * 256;
        int r = idx / 40, c = idx - r * 40;
        tile[r][c] = dbl[(size_t)(t0 + r) * 40 + c];
    }
    __syncthreads();
#pragma unroll
    for (int l = 0; l < 10; l++) {
        int idx = tid + l * 256;
        int c = idx >> 6, t = idx & 63;
        dblt[c * NN + t0 + t] = tile[t][c];
    }
}

// ---------------------------------------------------------------- dt (transposed): DT_T[d][t]
__global__ __launch_bounds__(256) void dt_t_kernel(const float* __restrict__ dblt,
                                                   const float* __restrict__ W_dt,
                                                   const float* __restrict__ b_dt,
                                                   float* __restrict__ dtt) {
    int t = blockIdx.x * 256 + threadIdx.x;
    int d = blockIdx.y;
    float acc = b_dt[d];
#pragma unroll
    for (int j = 0; j < DTR; j++)
        acc = fmaf(dblt[j * NN + t], W_dt[j * DI + d], acc);
    dtt[d * NN + t] = softplusf(acc);
}

// ---------------------------------------------------------------- Mamba scan (3-phase)
// All streams staged through LDS with cooperative full-line loads: fetch is
// structurally ideal, immune to cache thrash at any occupancy (R6 lesson:
// 16B/lane strided reads at 8 blocks/CU overflowed L2 -> 7x fetch ampl.).
// Lane layout: sg = lane&7 (states 2sg,2sg+1), dl = lane>>3; block covers 32 d.
// LDS compute reads: d-tiles conflict-free (dl -> disjoint 4-bank groups, sg
// broadcast); B/C 2-way (free, m136).
__global__ __launch_bounds__(256, 8) void scan_phase1(const float* __restrict__ dtt,
                                                      const float* __restrict__ xst,
                                                      const float* __restrict__ dblt,
                                                      const float* __restrict__ A_log,
                                                      float* __restrict__ chkP,
                                                      float* __restrict__ chkH) {
    __shared__ float Td[32][68];
    __shared__ float Tx[32][68];
    __shared__ float Bs[16][68];
    int tid = threadIdx.x;
    int wave = tid >> 6, lane = tid & 63;
    int sg = lane & 7, dl = lane >> 3;
    int dblk = blockIdx.x, chunk = blockIdx.y;
    int t0 = chunk * CHLEN;
    int dloc = wave * 8 + dl;
    int d = dblk * 32 + dloc;
    int s0 = 2 * sg;
#pragma unroll
    for (int p = 0; p < 2; p++) {           // 512 float4 slots: 32 rows x 16
        int linear = tid + p * 256;
        int row = linear >> 4, c4 = (linear & 15) * 4;
        *(float4*)&Td[row][c4] = *(const float4*)&dtt[(size_t)(dblk * 32 + row) * NN + t0 + c4];
        *(float4*)&Tx[row][c4] = *(const float4*)&xst[(size_t)(dblk * 32 + row) * NN + t0 + c4];
    }
    {
        int s = tid >> 4, c4 = (tid & 15) * 4;
        *(float4*)&Bs[s][c4] = *(const float4*)&dblt[(size_t)(8 + s) * NN + t0 + c4];
    }
    float A0 = -expf(A_log[d * DS + s0]);
    float A1 = -expf(A_log[d * DS + s0 + 1]);
    __syncthreads();
    float h0 = 0.f, h1 = 0.f, P0 = 1.f, P1 = 1.f;
    for (int i = 0; i < CHLEN; i += 4) {
        float4 d4 = *(const float4*)&Td[dloc][i];
        float4 x4 = *(const float4*)&Tx[dloc][i];
        float4 b04 = *(const float4*)&Bs[s0][i];
        float4 b14 = *(const float4*)&Bs[s0 + 1][i];
#define P1S(U) { float dtv = d4.U; float a0 = __expf(dtv * A0); float a1 = __expf(dtv * A1); \
        float dx = dtv * x4.U; h0 = fmaf(a0, h0, dx * b04.U); h1 = fmaf(a1, h1, dx * b14.U); \
        P0 *= a0; P1 *= a1; }
        P1S(x) P1S(y) P1S(z) P1S(w)
#undef P1S
    }
    int idx = chunk * 4096 + d * DS + s0;
    float2 vP; vP.x = P0; vP.y = P1;
    float2 vH; vH.x = h0; vH.y = h1;
    *(float2*)(chkP + idx) = vP;
    *(float2*)(chkH + idx) = vH;
}

// phase2a: compose chunks within each group of GL -> (GP, GH) per (group, idx)
__global__ void scan_phase2a(const float* __restrict__ chkP, const float* __restrict__ chkH,
                             float* __restrict__ gp, float* __restrict__ gh) {
    int g = blockIdx.x * blockDim.x + threadIdx.x;  // 4096*NG
    int idx = g & 4095;
    int grp = g >> 12;
    int c0 = grp * GL;
    float P = 1.f, H = 0.f;
    for (int j = 0; j < GL; j += 4) {
        float p[4], q[4];
#pragma unroll
        for (int jj = 0; jj < 4; jj++) {
            p[jj] = chkP[(c0 + j + jj) * 4096 + idx];
            q[jj] = chkH[(c0 + j + jj) * 4096 + idx];
        }
#pragma unroll
        for (int jj = 0; jj < 4; jj++) {
            H = fmaf(p[jj], H, q[jj]);
            P *= p[jj];
        }
    }
    gp[grp * 4096 + idx] = P;
    gh[grp * 4096 + idx] = H;
}

// phase2b: scan across the NG groups -> group-initial states
__global__ void scan_phase2b(const float* __restrict__ gp, const float* __restrict__ gh,
                             float* __restrict__ gini) {
    int idx = blockIdx.x * blockDim.x + threadIdx.x;  // 4096
    float h = 0.f;
#pragma unroll
    for (int g = 0; g < NG; g++) {
        gini[g * 4096 + idx] = h;
        h = fmaf(gp[g * 4096 + idx], h, gh[g * 4096 + idx]);
    }
}

// phase2c: replay within group, writing per-chunk initial states
__global__ void scan_phase2c(const float* __restrict__ chkP, const float* __restrict__ chkH,
                             const float* __restrict__ gini, float* __restrict__ init) {
    int g = blockIdx.x * blockDim.x + threadIdx.x;
    int idx = g & 4095;
    int grp = g >> 12;
    int c0 = grp * GL;
    float h = gini[grp * 4096 + idx];
    for (int j = 0; j < GL; j += 4) {
        float p[4], q[4];
#pragma unroll
        for (int jj = 0; jj < 4; jj++) {
            p[jj] = chkP[(c0 + j + jj) * 4096 + idx];
            q[jj] = chkH[(c0 + j + jj) * 4096 + idx];
        }
#pragma unroll
        for (int jj = 0; jj < 4; jj++) {
            init[(c0 + j + jj) * 4096 + idx] = h;
            h = fmaf(p[jj], h, q[jj]);
        }
    }
}

// phase3: full LDS staging (dt, xs, sz, B, C); y written in-place into the
// consumed dt tile (same wave's rows, program order), stored as full lines.
__global__ __launch_bounds__(256, 4) void scan_phase3(const float* __restrict__ dtt,
                                                      const float* __restrict__ xst,
                                                      const float* __restrict__ dblt,
                                                      const float* __restrict__ A_log,
                                                      const float* __restrict__ init,
                                                      const float* __restrict__ D_p,
                                                      const float* __restrict__ szt,
                                                      float* __restrict__ yt) {
    __shared__ float Td[32][68];
    __shared__ float Tx[32][68];
    __shared__ float Tz[32][68];
    __shared__ float Bs[16][68];
    __shared__ float Cs[16][68];
    int tid = threadIdx.x;
    int wave = tid >> 6, lane = tid & 63;
    int sg = lane & 7, dl = lane >> 3;
    int dblk = blockIdx.x, chunk = blockIdx.y;
    int t0 = chunk * CHLEN;
    int dloc = wave * 8 + dl;
    int d = dblk * 32 + dloc;
    int s0 = 2 * sg;
#pragma unroll
    for (int p = 0; p < 2; p++) {
        int linear = tid + p * 256;
        int row = linear >> 4, c4 = (linear & 15) * 4;
        *(float4*)&Td[row][c4] = *(const float4*)&dtt[(size_t)(dblk * 32 + row) * NN + t0 + c4];
        *(float4*)&Tx[row][c4] = *(const float4*)&xst[(size_t)(dblk * 32 + row) * NN + t0 + c4];
        *(float4*)&Tz[row][c4] = *(const float4*)&szt[(size_t)(dblk * 32 + row) * NN + t0 + c4];
    }
    {
        int s = tid >> 4, c4 = (tid & 15) * 4;
        *(float4*)&Bs[s][c4] = *(const float4*)&dblt[(size_t)(8 + s) * NN + t0 + c4];
        *(float4*)&Cs[s][c4] = *(const float4*)&dblt[(size_t)(24 + s) * NN + t0 + c4];
    }
    float A0 = -expf(A_log[d * DS + s0]);
    float A1 = -expf(A_log[d * DS + s0 + 1]);
    float Dd = D_p[d];
    float2 ini = *(const float2*)(init + chunk * 4096 + d * DS + s0);
    float h0 = ini.x, h1 = ini.y;
    __syncthreads();
    for (int i = 0; i < CHLEN; i += 4) {
        float4 d4 = *(const float4*)&Td[dloc][i];
        float4 x4 = *(const float4*)&Tx[dloc][i];
        float4 z4 = *(const float4*)&Tz[dloc][i];
        float4 b04 = *(const float4*)&Bs[s0][i];
        float4 b14 = *(const float4*)&Bs[s0 + 1][i];
        float4 c04 = *(const float4*)&Cs[s0][i];
        float4 c14 = *(const float4*)&Cs[s0 + 1][i];
        float4 yv;
#define P3S(U) { float dtv = d4.U; float a0 = __expf(dtv * A0); float a1 = __expf(dtv * A1); \
        float dx = dtv * x4.U; h0 = fmaf(a0, h0, dx * b04.U); h1 = fmaf(a1, h1, dx * b14.U); \
        float c = fmaf(h1, c14.U, h0 * c04.U); \
        c += __shfl_xor(c, 1); c += __shfl_xor(c, 2); c += __shfl_xor(c, 4); \
        yv.U = (c + Dd * x4.U) * z4.U; }
        P3S(x) P3S(y) P3S(z) P3S(w)
#undef P3S
        if (sg == 0) *(float4*)&Td[dloc][i] = yv;  // in-place: this wave's row only
    }
    // per-wave rows, no barrier needed (same wave wrote them)
#pragma unroll
    for (int r = 0; r < 8; r++)
        yt[(size_t)(dblk * 32 + wave * 8 + r) * NN + t0 + lane] = Td[wave * 8 + r][lane];
}

// ---------------------------------------------------------------- add + LayerNorm (wave per row)
__global__ void add_ln(const float* __restrict__ hg, const float* __restrict__ hm,
                       const float* __restrict__ gamma, const float* __restrict__ beta,
                       float* __restrict__ out) {
    int row = blockIdx.x * 4 + (threadIdx.x >> 6);
    int lane = threadIdx.x & 63;
    size_t base = (size_t)row * HH;
    float v0 = hg[base + lane] + hm[base + lane];
    float v1 = hg[base + 64 + lane] + hm[base + 64 + lane];
    float sum = v0 + v1;
#pragma unroll
    for (int m = 32; m >= 1; m >>= 1) sum += __shfl_xor(sum, m);
    float mu = sum * (1.f / 128.f);
    float d0 = v0 - mu, d1 = v1 - mu;
    float vs = d0 * d0 + d1 * d1;
#pragma unroll
    for (int m = 32; m >= 1; m >>= 1) vs += __shfl_xor(vs, m);
    float inv = rsqrtf(vs * (1.f / 128.f) + 1e-5f);
    out[base + lane] = d0 * inv * gamma[lane] + beta[lane];
    out[base + 64 + lane] = d1 * inv * gamma[64 + lane] + beta[64 + lane];
}

// ---------------------------------------------------------------- pooling (batch sorted), 4-row unroll
__global__ void pool_kernel(const float* __restrict__ hf, const int* __restrict__ batch,
                            float* __restrict__ ge, int* __restrict__ counts) {
    int f = threadIdx.x;  // 128
    int r0 = blockIdx.x * 128;
    int gcur = batch[r0];
    float acc = 0.f;
    int cnt = 0;
    for (int i = 0; i < 128; i += 4) {
        int r = r0 + i;
        int g0 = batch[r], g3 = batch[r + 3];
        float v0 = hf[(size_t)r * HH + f];
        float v1 = hf[(size_t)(r + 1) * HH + f];
        float v2 = hf[(size_t)(r + 2) * HH + f];
        float v3 = hf[(size_t)(r + 3) * HH + f];
        if (g0 == gcur && g3 == gcur) {
            acc += (v0 + v1) + (v2 + v3);
            cnt += 4;
        } else {
            int gs[4] = {g0, batch[r + 1], batch[r + 2], g3};
            float vs[4] = {v0, v1, v2, v3};
#pragma unroll
            for (int k = 0; k < 4; k++) {
                if (gs[k] != gcur) {
                    atomicAdd(&ge[gcur * HH + f], acc);
                    if (f == 0) atomicAdd(&counts[gcur], cnt);
                    acc = 0.f; cnt = 0; gcur = gs[k];
                }
                acc += vs[k];
                cnt++;
            }
        }
    }
    atomicAdd(&ge[gcur * HH + f], acc);
    if (f == 0) atomicAdd(&counts[gcur], cnt);
}

__global__ void ge_norm(float* __restrict__ ge, const int* __restrict__ counts) {
    int idx = blockIdx.x * blockDim.x + threadIdx.x;
    if (idx < BB * HH) {
        int b = idx >> 7;
        ge[idx] /= fmaxf((float)counts[b], 1.f);
    }
}

// ---------------------------------------------------------------- output heads
__global__ void heads_kernel(const float* __restrict__ ge,
                             const float* Wc, const float* bc, const float* Wh, const float* bh,
                             const float* Wt, const float* bt, const float* Wp1, const float* bp1,
                             const float* Wp2, const float* bp2, const float* Wd, const float* bd,
                             const float* Ws, const float* bs, float* __restrict__ out) {
    int col = blockIdx.x * blockDim.x + threadIdx.x;
    int b = blockIdx.y;
    if (col >= OUTW) return;
    const float* W; const float* bi; int lc, w;
    if (col < 1)         { W = Wc;  bi = bc;  lc = col;        w = 1; }
    else if (col < 5)    { W = Wh;  bi = bh;  lc = col - 1;    w = 4; }
    else if (col < 8)    { W = Wt;  bi = bt;  lc = col - 5;    w = 3; }
    else if (col < 520)  { W = Wp1; bi = bp1; lc = col - 8;    w = 512; }
    else if (col < 1032) { W = Wp2; bi = bp2; lc = col - 520;  w = 512; }
    else if (col < 1544) { W = Wd;  bi = bd;  lc = col - 1032; w = 512; }
    else                 { W = Ws;  bi = bs;  lc = col - 1544; w = 8; }
    float acc = bi[lc];
#pragma unroll 8
    for (int f = 0; f < HH; f++) acc = fmaf(ge[b * HH + f], W[f * w + lc], acc);
    out[(size_t)b * OUTW + col] = acc;
}

// ---------------------------------------------------------------- launch
extern "C" void kernel_launch(void* const* d_in, const int* in_sizes, int n_in,
                              void* d_out, int out_size, void* d_ws, size_t ws_size,
                              hipStream_t stream) {
    const float* nf      = (const float*)d_in[0];
    const int*   ei      = (const int*)d_in[1];
    const int*   batch   = (const int*)d_in[2];
    const float* W_in    = (const float*)d_in[3];
    const float* b_in    = (const float*)d_in[4];
    const float* W_g1    = (const float*)d_in[5];
    const float* b_g1    = (const float*)d_in[6];
    const float* W_g2    = (const float*)d_in[7];
    const float* b_g2    = (const float*)d_in[8];
    const float* W_inproj= (const float*)d_in[9];
    const float* conv_w  = (const float*)d_in[10];
    const float* conv_b  = (const float*)d_in[11];
    const float* W_xproj = (const float*)d_in[12];
    const float* W_dt    = (const float*)d_in[13];
    const float* b_dt    = (const float*)d_in[14];
    const float* A_log   = (const float*)d_in[15];
    const float* D_p     = (const float*)d_in[16];
    const float* W_out   = (const float*)d_in[17];
    const float* gamma   = (const float*)d_in[18];
    const float* beta    = (const float*)d_in[19];
    const float* Wc = (const float*)d_in[20]; const float* bc = (const float*)d_in[21];
    const float* Wh = (const float*)d_in[22]; const float* bh = (const float*)d_in[23];
    const float* Wt = (const float*)d_in[24]; const float* bt = (const float*)d_in[25];
    const float* Wp1= (const float*)d_in[26]; const float* bp1= (const float*)d_in[27];
    const float* Wp2= (const float*)d_in[28]; const float* bp2= (const float*)d_in[29];
    const float* Wd = (const float*)d_in[30]; const float* bd = (const float*)d_in[31];
    const float* Ws = (const float*)d_in[32]; const float* bs = (const float*)d_in[33];

    const int* e_src = ei;
    const int* e_dst = ei + EE;

    // workspace layout (floats, then ints)
    float* w = (float*)d_ws;
    size_t o = 0;
    float* F0   = w + o; o += (size_t)NN * HH;   // dead during scan -> CHP/CHH
    float* F1   = w + o; o += (size_t)NN * HH;   // dead during scan -> INI
    float* F2   = w + o; o += (size_t)NN * HH;
    float* XZ   = w + o; o += (size_t)NN * 512;  // dead after conv_silu_t; reused:
    float* DTT  = XZ;                             //   DT_T [DI][NN]
    float* YT   = XZ + (size_t)NN * DI;           //   y^T  [DI][NN]
    float* XST  = w + o; o += (size_t)NN * DI;   // x (conv+silu), transposed [DI][NN]
    float* SZT  = w + o; o += (size_t)NN * DI;   // silu(z), transposed [DI][NN]
    float* DBL  = w + o; o += (size_t)NN * 40;   // dead after transpose_dbl -> GP/GH/GINI
    float* DBLT = w + o; o += (size_t)NN * 40;   // [40][NN]; rows 8..23 = B^T, 24..39 = C^T
    float* GE   = w + o; o += BB * HH;
    float* DINV = w + o; o += NN;
    int* ip = (int*)(w + o);
    int* CNT    = ip; ip += NN;
    int* ROWPTR = ip; ip += NN + 1;
    int* CURSOR = ip; ip += NN;
    int* COL    = ip; ip += EE;
    int* COUNTS = ip; ip += BB;

    // overlays (regions dead during the scan)
    float* CHP  = F0;                         // NCH*4096 = 1M floats
    float* CHH  = F0 + (size_t)NCH * 4096;    // 1M floats (F0 holds 2M)
    float* INI  = F1;                         // NCH*4096 = 1M floats (F1 holds 2M)
    float* GP   = DBL;                        // NG*4096
    float* GH   = DBL + NG * 4096;
    float* GINI = DBL + 2 * NG * 4096;

    hipMemsetAsync(CNT, 0, NN * sizeof(int), stream);
    hipMemsetAsync(GE, 0, BB * HH * sizeof(float), stream);
    hipMemsetAsync(COUNTS, 0, BB * sizeof(int), stream);

    // CSR build
    deg_kernel<<<EE / 256, 256, 0, stream>>>(e_dst, CNT);
    prefix_kernel<<<1, 1024, 0, stream>>>(CNT, ROWPTR, CURSOR, DINV);
    scatter_kernel<<<EE / 256, 256, 0, stream>>>(e_src, e_dst, CURSOR, COL);

    // h0 = relu(nf @ W_in + b_in)
    gemm_k<<<dim3(2, NN / 64), 256, 0, stream>>>(nf, W_in, b_in, F0, NN, HH, FF, 1);
    // GCN layer 1
    gemm_k<<<dim3(2, NN / 64), 256, 0, stream>>>(F0, W_g1, nullptr, F1, NN, HH, HH, 0);
    gcn_gather<<<NN, HH, 0, stream>>>(F1, ROWPTR, COL, DINV, b_g1, F0);
    // GCN layer 2
    gemm_k<<<dim3(2, NN / 64), 256, 0, stream>>>(F0, W_g2, nullptr, F1, NN, HH, HH, 0);
    gcn_gather<<<NN, HH, 0, stream>>>(F1, ROWPTR, COL, DINV, b_g2, F2);  // F2 = h_gnn

    // xz = h_gnn @ W_inproj
    gemm_k<<<dim3(8, NN / 64), 256, 0, stream>>>(F2, W_inproj, nullptr, XZ, NN, 512, HH, 0);
    // conv + silu -> XST; silu(z) -> SZT (both transposed)
    conv_silu_t<<<dim3(NN / 64, 8), 256, 0, stream>>>(XZ, conv_w, conv_b, XST, SZT);
    // dbl = xs @ W_xproj (A^T layout)
    gemm_at<<<dim3(1, NN / 64), 256, 0, stream>>>(XST, W_xproj, DBL, NN, 40, DI);
    // transpose dbl -> DBLT
    transpose_dbl<<<NN / 64, 256, 0, stream>>>(DBL, DBLT);
    // dt (transposed) — overwrites XZ region (dead)
    dt_t_kernel<<<dim3(NN / 256, DI), 256, 0, stream>>>(DBLT, W_dt, b_dt, DTT);

    // Mamba scan
    scan_phase1<<<dim3(8, NCH), 256, 0, stream>>>(DTT, XST, DBLT, A_log, CHP, CHH);
    scan_phase2a<<<(4096 * NG) / 256, 256, 0, stream>>>(CHP, CHH, GP, GH);
    scan_phase2b<<<16, 256, 0, stream>>>(GP, GH, GINI);
    scan_phase2c<<<(4096 * NG) / 256, 256, 0, stream>>>(CHP, CHH, GINI, INI);
    scan_phase3<<<dim3(8, NCH), 256, 0, stream>>>(DTT, XST, DBLT, A_log, INI, D_p, SZT, YT);

    // h_mamba = y @ W_out -> F1 (y stored transposed)
    gemm_at<<<dim3(2, NN / 64), 256, 0, stream>>>(YT, W_out, F1, NN, HH, DI);
    // hh = h_gnn + h_mamba; LayerNorm -> F0
    add_ln<<<NN / 4, 256, 0, stream>>>(F2, F1, gamma, beta, F0);

    // pooling
    pool_kernel<<<NN / 128, HH, 0, stream>>>(F0, batch, GE, COUNTS);
    ge_norm<<<(BB * HH + 255) / 256, 256, 0, stream>>>(GE, COUNTS);

    // heads
    heads_kernel<<<dim3((OUTW + 127) / 128, BB), 128, 0, stream>>>(
        GE, Wc, bc, Wh, bh, Wt, bt, Wp1, bp1, Wp2, bp2, Wd, bd, Ws, bs, (float*)d_out);
}

// Round 8
// 448.962 us; speedup vs baseline: 2.1898x; 1.0026x over previous
//
#include <hip/hip_runtime.h>
#include <math.h>

#define NN 16384
#define EE 262144
#define FF 32
#define HH 128
#define BB 16
#define DI 256
#define DS 16
#define DC 4
#define DTR 8
#define OUTW 1552
#define NCH 256
#define CHLEN 64    // NCH*CHLEN == NN
#define NG 8        // phase2 groups
#define GL 32       // chunks per group; NG*GL == NCH

// ---------------------------------------------------------------- utilities
__device__ __forceinline__ float siluf(float v) { return v / (1.f + __expf(-v)); }
__device__ __forceinline__ float softplusf(float v) {
    return fmaxf(v, 0.f) + __logf(1.f + __expf(-fabsf(v)));
}

// ---------------------------------------------------------------- CSR build
__global__ void deg_kernel(const int* __restrict__ dst, int* __restrict__ cnt) {
    int e = blockIdx.x * blockDim.x + threadIdx.x;
    if (e < EE) atomicAdd(&cnt[dst[e]], 1);
}

__global__ __launch_bounds__(1024) void prefix_kernel(const int* __restrict__ cnt,
                                                      int* __restrict__ rowptr,
                                                      int* __restrict__ cursor,
                                                      float* __restrict__ dinv) {
    __shared__ int part[1024];
    int tid = threadIdx.x;
    int4 c4[4];
#pragma unroll
    for (int j = 0; j < 4; j++) c4[j] = ((const int4*)cnt)[tid * 4 + j];
    int v[16] = {c4[0].x, c4[0].y, c4[0].z, c4[0].w, c4[1].x, c4[1].y, c4[1].z, c4[1].w,
                 c4[2].x, c4[2].y, c4[2].z, c4[2].w, c4[3].x, c4[3].y, c4[3].z, c4[3].w};
    int s = 0;
#pragma unroll
    for (int j = 0; j < 16; j++) s += v[j];
    part[tid] = s;
    __syncthreads();
    for (int off = 1; off < 1024; off <<= 1) {
        int t = (tid >= off) ? part[tid - off] : 0;
        __syncthreads();
        part[tid] += t;
        __syncthreads();
    }
    int running = part[tid] - s;
    int rp[16];
    float dv[16];
#pragma unroll
    for (int j = 0; j < 16; j++) {
        rp[j] = running;
        running += v[j];
        dv[j] = rsqrtf((float)(v[j] + 1));  // +1 self loop
    }
#pragma unroll
    for (int j = 0; j < 4; j++) {
        int4 r4; r4.x = rp[j*4]; r4.y = rp[j*4+1]; r4.z = rp[j*4+2]; r4.w = rp[j*4+3];
        ((int4*)rowptr)[tid * 4 + j] = r4;
        ((int4*)cursor)[tid * 4 + j] = r4;
        float4 d4; d4.x = dv[j*4]; d4.y = dv[j*4+1]; d4.z = dv[j*4+2]; d4.w = dv[j*4+3];
        ((float4*)dinv)[tid * 4 + j] = d4;
    }
    if (tid == 1023) rowptr[NN] = part[1023];
}

__global__ void scatter_kernel(const int* __restrict__ src, const int* __restrict__ dst,
                               int* __restrict__ cursor, int* __restrict__ col) {
    int e = blockIdx.x * blockDim.x + threadIdx.x;
    if (e < EE) {
        int d = dst[e];
        int pos = atomicAdd(&cursor[d], 1);
        col[pos] = src[e];
    }
}

// ---------------------------------------------------------------- GEMM (fp32, 64x64 tile)
__global__ __launch_bounds__(256) void gemm_k(const float* __restrict__ A,
                                              const float* __restrict__ B,
                                              const float* __restrict__ bias,
                                              float* __restrict__ C,
                                              int M, int Nn, int K, int act) {
    __shared__ float As[16][68];
    __shared__ float Bs[16][68];
    int tid = threadIdx.x;
    int m0 = blockIdx.y * 64;
    int n0 = blockIdx.x * 64;
    int ty = tid >> 4, tx = tid & 15;
    float acc[4][4] = {{0.f}};
    for (int k0 = 0; k0 < K; k0 += 16) {
#pragma unroll
        for (int l = 0; l < 4; l++) {
            int idx = tid + l * 256;
            int i = idx >> 4, j = idx & 15;
            As[j][i] = A[(size_t)(m0 + i) * K + k0 + j];
        }
#pragma unroll
        for (int l = 0; l < 4; l++) {
            int idx = tid + l * 256;
            int i = idx >> 6, j = idx & 63;
            int n = n0 + j;
            Bs[i][j] = (n < Nn) ? B[(size_t)(k0 + i) * Nn + n] : 0.f;
        }
        __syncthreads();
#pragma unroll
        for (int kk = 0; kk < 16; kk++) {
            float4 a4 = *(const float4*)&As[kk][ty * 4];
            float4 b4 = *(const float4*)&Bs[kk][tx * 4];
            float av[4] = {a4.x, a4.y, a4.z, a4.w};
            float bv[4] = {b4.x, b4.y, b4.z, b4.w};
#pragma unroll
            for (int r = 0; r < 4; r++)
#pragma unroll
                for (int c = 0; c < 4; c++) acc[r][c] = fmaf(av[r], bv[c], acc[r][c]);
        }
        __syncthreads();
    }
    int nb = n0 + tx * 4;
    if (nb < Nn) {
        float4 bi4 = {0.f, 0.f, 0.f, 0.f};
        if (bias) bi4 = *(const float4*)&bias[nb];
#pragma unroll
        for (int r = 0; r < 4; r++) {
            int m = m0 + ty * 4 + r;
            float4 v;
            v.x = acc[r][0] + bi4.x; v.y = acc[r][1] + bi4.y;
            v.z = acc[r][2] + bi4.z; v.w = acc[r][3] + bi4.w;
            if (act == 1) {
                v.x = fmaxf(v.x, 0.f); v.y = fmaxf(v.y, 0.f);
                v.z = fmaxf(v.z, 0.f); v.w = fmaxf(v.w, 0.f);
            }
            *(float4*)&C[(size_t)m * Nn + nb] = v;
        }
    }
}

// ---------------------------------------------------------------- big-tile GEMM (128x128, 8x8/thread)
// micro-tile is 2x2 blocks of 4x4 (m at ty*4 and 64+ty*4; n at tx*4 and 64+tx*4)
// so all LDS reads are <=2-way (free). Used for inproj (N=512).
__global__ __launch_bounds__(256, 2) void gemm_big(const float* __restrict__ A,
                                                   const float* __restrict__ B,
                                                   float* __restrict__ C,
                                                   int M, int Nn, int K) {
    __shared__ float As[16][132];
    __shared__ float Bs[16][132];
    int tid = threadIdx.x;
    int m0 = blockIdx.y * 128;
    int n0 = blockIdx.x * 128;
    int ty = tid >> 4, tx = tid & 15;
    float acc[8][8] = {{0.f}};
    for (int k0 = 0; k0 < K; k0 += 16) {
        {   // A: 128 m x 16 k -> As[k][m]
            int m = tid >> 1;
            int kc = (tid & 1) * 8;
            const float* ap = &A[(size_t)(m0 + m) * K + k0 + kc];
            float4 a0 = *(const float4*)ap;
            float4 a1 = *(const float4*)(ap + 4);
            As[kc + 0][m] = a0.x; As[kc + 1][m] = a0.y;
            As[kc + 2][m] = a0.z; As[kc + 3][m] = a0.w;
            As[kc + 4][m] = a1.x; As[kc + 5][m] = a1.y;
            As[kc + 6][m] = a1.z; As[kc + 7][m] = a1.w;
        }
        {   // B: 16 k x 128 n
            int krow = tid >> 4;
            int c8 = (tid & 15) * 8;
            const float* bp = &B[(size_t)(k0 + krow) * Nn + n0 + c8];
            *(float4*)&Bs[krow][c8] = *(const float4*)bp;
            *(float4*)&Bs[krow][c8 + 4] = *(const float4*)(bp + 4);
        }
        __syncthreads();
#pragma unroll
        for (int kk = 0; kk < 16; kk++) {
            float4 a0 = *(const float4*)&As[kk][ty * 4];
            float4 a1 = *(const float4*)&As[kk][64 + ty * 4];
            float4 b0 = *(const float4*)&Bs[kk][tx * 4];
            float4 b1 = *(const float4*)&Bs[kk][64 + tx * 4];
            float av[8] = {a0.x, a0.y, a0.z, a0.w, a1.x, a1.y, a1.z, a1.w};
            float bv[8] = {b0.x, b0.y, b0.z, b0.w, b1.x, b1.y, b1.z, b1.w};
#pragma unroll
            for (int r = 0; r < 8; r++)
#pragma unroll
                for (int c = 0; c < 8; c++) acc[r][c] = fmaf(av[r], bv[c], acc[r][c]);
        }
        __syncthreads();
    }
#pragma unroll
    for (int r = 0; r < 8; r++) {
        int m = m0 + ((r < 4) ? (ty * 4 + r) : (64 + ty * 4 + r - 4));
        float4 v0, v1;
        v0.x = acc[r][0]; v0.y = acc[r][1]; v0.z = acc[r][2]; v0.w = acc[r][3];
        v1.x = acc[r][4]; v1.y = acc[r][5]; v1.z = acc[r][6]; v1.w = acc[r][7];
        *(float4*)&C[(size_t)m * Nn + n0 + tx * 4] = v0;
        *(float4*)&C[(size_t)m * Nn + n0 + 64 + tx * 4] = v1;
    }
}

// ---------------------------------------------------------------- GEMM with A^T input (A stored [K][M])
__global__ __launch_bounds__(256) void gemm_at(const float* __restrict__ AT,
                                               const float* __restrict__ B,
                                               float* __restrict__ C,
                                               int M, int Nn, int K) {
    __shared__ float As[16][68];
    __shared__ float Bs[16][68];
    int tid = threadIdx.x;
    int m0 = blockIdx.y * 64;
    int n0 = blockIdx.x * 64;
    int ty = tid >> 4, tx = tid & 15;
    float acc[4][4] = {{0.f}};
    for (int k0 = 0; k0 < K; k0 += 16) {
#pragma unroll
        for (int l = 0; l < 4; l++) {
            int idx = tid + l * 256;
            int kk = idx >> 6, i = idx & 63;
            As[kk][i] = AT[(size_t)(k0 + kk) * M + m0 + i];
        }
#pragma unroll
        for (int l = 0; l < 4; l++) {
            int idx = tid + l * 256;
            int i = idx >> 6, j = idx & 63;
            int n = n0 + j;
            Bs[i][j] = (n < Nn) ? B[(size_t)(k0 + i) * Nn + n] : 0.f;
        }
        __syncthreads();
#pragma unroll
        for (int kk = 0; kk < 16; kk++) {
            float4 a4 = *(const float4*)&As[kk][ty * 4];
            float4 b4 = *(const float4*)&Bs[kk][tx * 4];
            float av[4] = {a4.x, a4.y, a4.z, a4.w};
            float bv[4] = {b4.x, b4.y, b4.z, b4.w};
#pragma unroll
            for (int r = 0; r < 4; r++)
#pragma unroll
                for (int c = 0; c < 4; c++) acc[r][c] = fmaf(av[r], bv[c], acc[r][c]);
        }
        __syncthreads();
    }
    int nb = n0 + tx * 4;
    if (nb < Nn) {
#pragma unroll
        for (int r = 0; r < 4; r++) {
            int m = m0 + ty * 4 + r;
            float4 v;
            v.x = acc[r][0]; v.y = acc[r][1]; v.z = acc[r][2]; v.w = acc[r][3];
            *(float4*)&C[(size_t)m * Nn + nb] = v;
        }
    }
}

// ---------------------------------------------------------------- GCN gather (CSR by dest), 4-deep edge unroll
__global__ void gcn_gather(const float* __restrict__ xw, const int* __restrict__ rowptr,
                           const int* __restrict__ col, const float* __restrict__ dinv,
                           const float* __restrict__ b, float* __restrict__ out) {
    int n = blockIdx.x;
    int f = threadIdx.x;  // 128
    float dn = dinv[n];
    float acc = xw[(size_t)n * HH + f] * dn * dn;  // self loop
    int beg = rowptr[n], end = rowptr[n + 1];
    int e = beg;
    for (; e + 4 <= end; e += 4) {
        int s0 = col[e], s1 = col[e + 1], s2 = col[e + 2], s3 = col[e + 3];
        float w0 = dinv[s0] * dn, w1 = dinv[s1] * dn, w2 = dinv[s2] * dn, w3 = dinv[s3] * dn;
        float v0 = xw[(size_t)s0 * HH + f];
        float v1 = xw[(size_t)s1 * HH + f];
        float v2 = xw[(size_t)s2 * HH + f];
        float v3 = xw[(size_t)s3 * HH + f];
        acc = fmaf(v0, w0, acc);
        acc = fmaf(v1, w1, acc);
        acc = fmaf(v2, w2, acc);
        acc = fmaf(v3, w3, acc);
    }
    for (; e < end; e++) {
        int s0 = col[e];
        acc = fmaf(xw[(size_t)s0 * HH + f], dinv[s0] * dn, acc);
    }
    acc += b[f];
    out[(size_t)n * HH + f] = fmaxf(acc, 0.f);
}

// ---------------------------------------------------------------- conv + silu, transposed outputs
__global__ __launch_bounds__(256) void conv_silu_t(const float* __restrict__ xz,
                                                   const float* __restrict__ cw,
                                                   const float* __restrict__ cb,
                                                   float* __restrict__ xst,
                                                   float* __restrict__ szt) {
    __shared__ float tile[67][65];
    int tid = threadIdx.x;
    int t0 = blockIdx.x * 64;
    int c0 = blockIdx.y * 64;
#pragma unroll
    for (int l = 0; l < 17; l++) {
        int idx = tid + l * 256;
        if (idx < 67 * 64) {
            int r = idx >> 6, c = idx & 63;
            int gt = t0 - 3 + r;
            tile[r][c] = (gt >= 0) ? xz[(size_t)gt * 512 + c0 + c] : 0.f;
        }
    }
    __syncthreads();
    int tl = tid & 63;
    int d0 = tid >> 6;
    if (c0 < 256) {
#pragma unroll
        for (int l = 0; l < 16; l++) {
            int dl = d0 + l * 4;
            int dg = c0 + dl;
            float acc = cb[dg];
#pragma unroll
            for (int k = 0; k < DC; k++)
                acc = fmaf(tile[tl + k][dl], cw[dg * DC + k], acc);
            xst[dg * NN + t0 + tl] = siluf(acc);
        }
    } else {
#pragma unroll
        for (int l = 0; l < 16; l++) {
            int dl = d0 + l * 4;
            int dg = c0 - 256 + dl;
            szt[dg * NN + t0 + tl] = siluf(tile[tl + 3][dl]);
        }
    }
}

// ---------------------------------------------------------------- transpose dbl [NN][40] -> [40][NN]
__global__ __launch_bounds__(256) void transpose_dbl(const float* __restrict__ dbl,
                                                     float* __restrict__ dblt) {
    __shared__ float tile[64][41];
    int tid = threadIdx.x;
    int t0 = blockIdx.x * 64;
#pragma unroll
    for (int l = 0; l < 10; l++) {
        int idx = tid + l * 256;
        int r = idx / 40, c = idx - r * 40;
        tile[r][c] = dbl[(size_t)(t0 + r) * 40 + c];
    }
    __syncthreads();
#pragma unroll
    for (int l = 0; l < 10; l++) {
        int idx = tid + l * 256;
        int c = idx >> 6, t = idx & 63;
        dblt[c * NN + t0 + t] = tile[t][c];
    }
}

// ---------------------------------------------------------------- Mamba scan (3-phase)
// All streams staged through LDS with cooperative full-line loads (R6/R7 lesson).
// dt computed IN-KERNEL from dblt rows 0..7 (8 FMA + softplus) — no DT_T buffer.
// Lane layout: sg = lane&7 (states 2sg,2sg+1), dl = lane>>3; block covers 32 d.
__global__ __launch_bounds__(256, 6) void scan_phase1(const float* __restrict__ xst,
                                                      const float* __restrict__ dblt,
                                                      const float* __restrict__ A_log,
                                                      const float* __restrict__ W_dt,
                                                      const float* __restrict__ b_dt,
                                                      float* __restrict__ chkP,
                                                      float* __restrict__ chkH) {
    __shared__ float Td[32][68];
    __shared__ float Tx[32][68];
    __shared__ float Bs[16][68];
    __shared__ float D8[8][68];
    int tid = threadIdx.x;
    int wave = tid >> 6, lane = tid & 63;
    int sg = lane & 7, dl = lane >> 3;
    int dblk = blockIdx.x, chunk = blockIdx.y;
    int t0 = chunk * CHLEN;
    int dloc = wave * 8 + dl;
    int d = dblk * 32 + dloc;
    int s0 = 2 * sg;
#pragma unroll
    for (int p = 0; p < 2; p++) {
        int linear = tid + p * 256;
        int row = linear >> 4, c4 = (linear & 15) * 4;
        *(float4*)&Tx[row][c4] = *(const float4*)&xst[(size_t)(dblk * 32 + row) * NN + t0 + c4];
    }
    if (tid < 128) {
        int r = tid >> 4, c4 = (tid & 15) * 4;
        *(float4*)&D8[r][c4] = *(const float4*)&dblt[(size_t)r * NN + t0 + c4];
    }
    {
        int s = tid >> 4, c4 = (tid & 15) * 4;
        *(float4*)&Bs[s][c4] = *(const float4*)&dblt[(size_t)(8 + s) * NN + t0 + c4];
    }
    float A0 = -expf(A_log[d * DS + s0]);
    float A1 = -expf(A_log[d * DS + s0 + 1]);
    __syncthreads();
    {   // dt tile: 32 d x 64 t; thread computes 8 consecutive t for one d-row
        int row = tid >> 3;
        int tb = (tid & 7) * 8;
        int dd = dblk * 32 + row;
        float bd = b_dt[dd];
        float wv[8];
#pragma unroll
        for (int j = 0; j < 8; j++) wv[j] = W_dt[j * DI + dd];
#pragma unroll
        for (int j = 0; j < 8; j++) {
            int t = tb + j;
            float acc = bd;
#pragma unroll
            for (int k = 0; k < 8; k++) acc = fmaf(D8[k][t], wv[k], acc);
            Td[row][t] = softplusf(acc);
        }
    }
    __syncthreads();
    float h0 = 0.f, h1 = 0.f, P0 = 1.f, P1 = 1.f;
    for (int i = 0; i < CHLEN; i += 4) {
        float4 d4 = *(const float4*)&Td[dloc][i];
        float4 x4 = *(const float4*)&Tx[dloc][i];
        float4 b04 = *(const float4*)&Bs[s0][i];
        float4 b14 = *(const float4*)&Bs[s0 + 1][i];
#define P1S(U) { float dtv = d4.U; float a0 = __expf(dtv * A0); float a1 = __expf(dtv * A1); \
        float dx = dtv * x4.U; h0 = fmaf(a0, h0, dx * b04.U); h1 = fmaf(a1, h1, dx * b14.U); \
        P0 *= a0; P1 *= a1; }
        P1S(x) P1S(y) P1S(z) P1S(w)
#undef P1S
    }
    int idx = chunk * 4096 + d * DS + s0;
    float2 vP; vP.x = P0; vP.y = P1;
    float2 vH; vH.x = h0; vH.y = h1;
    *(float2*)(chkP + idx) = vP;
    *(float2*)(chkH + idx) = vH;
}

// phase2a: compose chunks within each group of GL -> (GP, GH) per (group, idx)
__global__ void scan_phase2a(const float* __restrict__ chkP, const float* __restrict__ chkH,
                             float* __restrict__ gp, float* __restrict__ gh) {
    int g = blockIdx.x * blockDim.x + threadIdx.x;  // 4096*NG
    int idx = g & 4095;
    int grp = g >> 12;
    int c0 = grp * GL;
    float P = 1.f, H = 0.f;
    for (int j = 0; j < GL; j += 4) {
        float p[4], q[4];
#pragma unroll
        for (int jj = 0; jj < 4; jj++) {
            p[jj] = chkP[(c0 + j + jj) * 4096 + idx];
            q[jj] = chkH[(c0 + j + jj) * 4096 + idx];
        }
#pragma unroll
        for (int jj = 0; jj < 4; jj++) {
            H = fmaf(p[jj], H, q[jj]);
            P *= p[jj];
        }
    }
    gp[grp * 4096 + idx] = P;
    gh[grp * 4096 + idx] = H;
}

// phase2b: scan across the NG groups -> group-initial states
__global__ void scan_phase2b(const float* __restrict__ gp, const float* __restrict__ gh,
                             float* __restrict__ gini) {
    int idx = blockIdx.x * blockDim.x + threadIdx.x;  // 4096
    float h = 0.f;
#pragma unroll
    for (int g = 0; g < NG; g++) {
        gini[g * 4096 + idx] = h;
        h = fmaf(gp[g * 4096 + idx], h, gh[g * 4096 + idx]);
    }
}

// phase2c: replay within group, writing per-chunk initial states
__global__ void scan_phase2c(const float* __restrict__ chkP, const float* __restrict__ chkH,
                             const float* __restrict__ gini, float* __restrict__ init) {
    int g = blockIdx.x * blockDim.x + threadIdx.x;
    int idx = g & 4095;
    int grp = g >> 12;
    int c0 = grp * GL;
    float h = gini[grp * 4096 + idx];
    for (int j = 0; j < GL; j += 4) {
        float p[4], q[4];
#pragma unroll
        for (int jj = 0; jj < 4; jj++) {
            p[jj] = chkP[(c0 + j + jj) * 4096 + idx];
            q[jj] = chkH[(c0 + j + jj) * 4096 + idx];
        }
#pragma unroll
        for (int jj = 0; jj < 4; jj++) {
            init[(c0 + j + jj) * 4096 + idx] = h;
            h = fmaf(p[jj], h, q[jj]);
        }
    }
}

// phase3: LDS staging (xs, B, C, dbl0..7 -> dt computed in-kernel); y written
// in-place into consumed dt tile rows (same wave, program order), multiplied by
// silu(z) at store time (coalesced global read; saves the Tz LDS slot).
__global__ __launch_bounds__(256, 5) void scan_phase3(const float* __restrict__ xst,
                                                      const float* __restrict__ dblt,
                                                      const float* __restrict__ A_log,
                                                      const float* __restrict__ W_dt,
                                                      const float* __restrict__ b_dt,
                                                      const float* __restrict__ init,
                                                      const float* __restrict__ D_p,
                                                      const float* __restrict__ szt,
                                                      float* __restrict__ yt) {
    __shared__ float Td[32][68];
    __shared__ float Tx[32][68];
    __shared__ float Bs[16][68];
    __shared__ float Cs[16][68];
    __shared__ float D8[8][68];
    int tid = threadIdx.x;
    int wave = tid >> 6, lane = tid & 63;
    int sg = lane & 7, dl = lane >> 3;
    int dblk = blockIdx.x, chunk = blockIdx.y;
    int t0 = chunk * CHLEN;
    int dloc = wave * 8 + dl;
    int d = dblk * 32 + dloc;
    int s0 = 2 * sg;
#pragma unroll
    for (int p = 0; p < 2; p++) {
        int linear = tid + p * 256;
        int row = linear >> 4, c4 = (linear & 15) * 4;
        *(float4*)&Tx[row][c4] = *(const float4*)&xst[(size_t)(dblk * 32 + row) * NN + t0 + c4];
    }
    if (tid < 128) {
        int r = tid >> 4, c4 = (tid & 15) * 4;
        *(float4*)&D8[r][c4] = *(const float4*)&dblt[(size_t)r * NN + t0 + c4];
    }
    {
        int s = tid >> 4, c4 = (tid & 15) * 4;
        *(float4*)&Bs[s][c4] = *(const float4*)&dblt[(size_t)(8 + s) * NN + t0 + c4];
        *(float4*)&Cs[s][c4] = *(const float4*)&dblt[(size_t)(24 + s) * NN + t0 + c4];
    }
    float A0 = -expf(A_log[d * DS + s0]);
    float A1 = -expf(A_log[d * DS + s0 + 1]);
    float Dd = D_p[d];
    float2 ini = *(const float2*)(init + chunk * 4096 + d * DS + s0);
    float h0 = ini.x, h1 = ini.y;
    __syncthreads();
    {   // dt tile
        int row = tid >> 3;
        int tb = (tid & 7) * 8;
        int dd = dblk * 32 + row;
        float bd = b_dt[dd];
        float wv[8];
#pragma unroll
        for (int j = 0; j < 8; j++) wv[j] = W_dt[j * DI + dd];
#pragma unroll
        for (int j = 0; j < 8; j++) {
            int t = tb + j;
            float acc = bd;
#pragma unroll
            for (int k = 0; k < 8; k++) acc = fmaf(D8[k][t], wv[k], acc);
            Td[row][t] = softplusf(acc);
        }
    }
    __syncthreads();
    for (int i = 0; i < CHLEN; i += 4) {
        float4 d4 = *(const float4*)&Td[dloc][i];
        float4 x4 = *(const float4*)&Tx[dloc][i];
        float4 b04 = *(const float4*)&Bs[s0][i];
        float4 b14 = *(const float4*)&Bs[s0 + 1][i];
        float4 c04 = *(const float4*)&Cs[s0][i];
        float4 c14 = *(const float4*)&Cs[s0 + 1][i];
        float4 yv;
#define P3S(U) { float dtv = d4.U; float a0 = __expf(dtv * A0); float a1 = __expf(dtv * A1); \
        float dx = dtv * x4.U; h0 = fmaf(a0, h0, dx * b04.U); h1 = fmaf(a1, h1, dx * b14.U); \
        float c = fmaf(h1, c14.U, h0 * c04.U); \
        c += __shfl_xor(c, 1); c += __shfl_xor(c, 2); c += __shfl_xor(c, 4); \
        yv.U = c + Dd * x4.U; }
        P3S(x) P3S(y) P3S(z) P3S(w)
#undef P3S
        if (sg == 0) *(float4*)&Td[dloc][i] = yv;  // in-place: this wave's row only
    }
    // per-wave rows (written by this wave), multiply silu(z) at store time
#pragma unroll
    for (int r = 0; r < 8; r++) {
        int row = wave * 8 + r;
        float sz = szt[(size_t)(dblk * 32 + row) * NN + t0 + lane];
        yt[(size_t)(dblk * 32 + row) * NN + t0 + lane] = Td[row][lane] * sz;
    }
}

// ---------------------------------------------------------------- add + LayerNorm (wave per row)
__global__ void add_ln(const float* __restrict__ hg, const float* __restrict__ hm,
                       const float* __restrict__ gamma, const float* __restrict__ beta,
                       float* __restrict__ out) {
    int row = blockIdx.x * 4 + (threadIdx.x >> 6);
    int lane = threadIdx.x & 63;
    size_t base = (size_t)row * HH;
    float v0 = hg[base + lane] + hm[base + lane];
    float v1 = hg[base + 64 + lane] + hm[base + 64 + lane];
    float sum = v0 + v1;
#pragma unroll
    for (int m = 32; m >= 1; m >>= 1) sum += __shfl_xor(sum, m);
    float mu = sum * (1.f / 128.f);
    float d0 = v0 - mu, d1 = v1 - mu;
    float vs = d0 * d0 + d1 * d1;
#pragma unroll
    for (int m = 32; m >= 1; m >>= 1) vs += __shfl_xor(vs, m);
    float inv = rsqrtf(vs * (1.f / 128.f) + 1e-5f);
    out[base + lane] = d0 * inv * gamma[lane] + beta[lane];
    out[base + 64 + lane] = d1 * inv * gamma[64 + lane] + beta[64 + lane];
}

// ---------------------------------------------------------------- pooling (batch sorted), 4-row unroll
__global__ void pool_kernel(const float* __restrict__ hf, const int* __restrict__ batch,
                            float* __restrict__ ge, int* __restrict__ counts) {
    int f = threadIdx.x;  // 128
    int r0 = blockIdx.x * 128;
    int gcur = batch[r0];
    float acc = 0.f;
    int cnt = 0;
    for (int i = 0; i < 128; i += 4) {
        int r = r0 + i;
        int g0 = batch[r], g3 = batch[r + 3];
        float v0 = hf[(size_t)r * HH + f];
        float v1 = hf[(size_t)(r + 1) * HH + f];
        float v2 = hf[(size_t)(r + 2) * HH + f];
        float v3 = hf[(size_t)(r + 3) * HH + f];
        if (g0 == gcur && g3 == gcur) {
            acc += (v0 + v1) + (v2 + v3);
            cnt += 4;
        } else {
            int gs[4] = {g0, batch[r + 1], batch[r + 2], g3};
            float vs[4] = {v0, v1, v2, v3};
#pragma unroll
            for (int k = 0; k < 4; k++) {
                if (gs[k] != gcur) {
                    atomicAdd(&ge[gcur * HH + f], acc);
                    if (f == 0) atomicAdd(&counts[gcur], cnt);
                    acc = 0.f; cnt = 0; gcur = gs[k];
                }
                acc += vs[k];
                cnt++;
            }
        }
    }
    atomicAdd(&ge[gcur * HH + f], acc);
    if (f == 0) atomicAdd(&counts[gcur], cnt);
}

__global__ void ge_norm(float* __restrict__ ge, const int* __restrict__ counts) {
    int idx = blockIdx.x * blockDim.x + threadIdx.x;
    if (idx < BB * HH) {
        int b = idx >> 7;
        ge[idx] /= fmaxf((float)counts[b], 1.f);
    }
}

// ---------------------------------------------------------------- output heads
__global__ void heads_kernel(const float* __restrict__ ge,
                             const float* Wc, const float* bc, const float* Wh, const float* bh,
                             const float* Wt, const float* bt, const float* Wp1, const float* bp1,
                             const float* Wp2, const float* bp2, const float* Wd, const float* bd,
                             const float* Ws, const float* bs, float* __restrict__ out) {
    int col = blockIdx.x * blockDim.x + threadIdx.x;
    int b = blockIdx.y;
    if (col >= OUTW) return;
    const float* W; const float* bi; int lc, w;
    if (col < 1)         { W = Wc;  bi = bc;  lc = col;        w = 1; }
    else if (col < 5)    { W = Wh;  bi = bh;  lc = col - 1;    w = 4; }
    else if (col < 8)    { W = Wt;  bi = bt;  lc = col - 5;    w = 3; }
    else if (col < 520)  { W = Wp1; bi = bp1; lc = col - 8;    w = 512; }
    else if (col < 1032) { W = Wp2; bi = bp2; lc = col - 520;  w = 512; }
    else if (col < 1544) { W = Wd;  bi = bd;  lc = col - 1032; w = 512; }
    else                 { W = Ws;  bi = bs;  lc = col - 1544; w = 8; }
    float acc = bi[lc];
#pragma unroll 8
    for (int f = 0; f < HH; f++) acc = fmaf(ge[b * HH + f], W[f * w + lc], acc);
    out[(size_t)b * OUTW + col] = acc;
}

// ---------------------------------------------------------------- launch
extern "C" void kernel_launch(void* const* d_in, const int* in_sizes, int n_in,
                              void* d_out, int out_size, void* d_ws, size_t ws_size,
                              hipStream_t stream) {
    const float* nf      = (const float*)d_in[0];
    const int*   ei      = (const int*)d_in[1];
    const int*   batch   = (const int*)d_in[2];
    const float* W_in    = (const float*)d_in[3];
    const float* b_in    = (const float*)d_in[4];
    const float* W_g1    = (const float*)d_in[5];
    const float* b_g1    = (const float*)d_in[6];
    const float* W_g2    = (const float*)d_in[7];
    const float* b_g2    = (const float*)d_in[8];
    const float* W_inproj= (const float*)d_in[9];
    const float* conv_w  = (const float*)d_in[10];
    const float* conv_b  = (const float*)d_in[11];
    const float* W_xproj = (const float*)d_in[12];
    const float* W_dt    = (const float*)d_in[13];
    const float* b_dt    = (const float*)d_in[14];
    const float* A_log   = (const float*)d_in[15];
    const float* D_p     = (const float*)d_in[16];
    const float* W_out   = (const float*)d_in[17];
    const float* gamma   = (const float*)d_in[18];
    const float* beta    = (const float*)d_in[19];
    const float* Wc = (const float*)d_in[20]; const float* bc = (const float*)d_in[21];
    const float* Wh = (const float*)d_in[22]; const float* bh = (const float*)d_in[23];
    const float* Wt = (const float*)d_in[24]; const float* bt = (const float*)d_in[25];
    const float* Wp1= (const float*)d_in[26]; const float* bp1= (const float*)d_in[27];
    const float* Wp2= (const float*)d_in[28]; const float* bp2= (const float*)d_in[29];
    const float* Wd = (const float*)d_in[30]; const float* bd = (const float*)d_in[31];
    const float* Ws = (const float*)d_in[32]; const float* bs = (const float*)d_in[33];

    const int* e_src = ei;
    const int* e_dst = ei + EE;

    // workspace layout (floats, then ints)
    float* w = (float*)d_ws;
    size_t o = 0;
    float* F0   = w + o; o += (size_t)NN * HH;   // dead during scan -> CHP/CHH
    float* F1   = w + o; o += (size_t)NN * HH;   // dead during scan -> INI
    float* F2   = w + o; o += (size_t)NN * HH;
    float* XZ   = w + o; o += (size_t)NN * 512;  // dead after conv_silu_t; reused:
    float* YT   = XZ;                             //   y^T [DI][NN]
    float* XST  = w + o; o += (size_t)NN * DI;   // x (conv+silu), transposed [DI][NN]
    float* SZT  = w + o; o += (size_t)NN * DI;   // silu(z), transposed [DI][NN]
    float* DBL  = w + o; o += (size_t)NN * 40;   // dead after transpose_dbl -> GP/GH/GINI
    float* DBLT = w + o; o += (size_t)NN * 40;   // [40][NN]; 0..7 = dt-proj^T, 8..23 = B^T, 24..39 = C^T
    float* GE   = w + o; o += BB * HH;
    float* DINV = w + o; o += NN;
    int* ip = (int*)(w + o);
    int* CNT    = ip; ip += NN;
    int* ROWPTR = ip; ip += NN + 1;
    int* CURSOR = ip; ip += NN;
    int* COL    = ip; ip += EE;
    int* COUNTS = ip; ip += BB;

    // overlays (regions dead during the scan)
    float* CHP  = F0;                         // NCH*4096 = 1M floats
    float* CHH  = F0 + (size_t)NCH * 4096;    // 1M floats (F0 holds 2M)
    float* INI  = F1;                         // NCH*4096 = 1M floats (F1 holds 2M)
    float* GP   = DBL;                        // NG*4096
    float* GH   = DBL + NG * 4096;
    float* GINI = DBL + 2 * NG * 4096;

    hipMemsetAsync(CNT, 0, NN * sizeof(int), stream);
    hipMemsetAsync(GE, 0, BB * HH * sizeof(float), stream);
    hipMemsetAsync(COUNTS, 0, BB * sizeof(int), stream);

    // CSR build
    deg_kernel<<<EE / 256, 256, 0, stream>>>(e_dst, CNT);
    prefix_kernel<<<1, 1024, 0, stream>>>(CNT, ROWPTR, CURSOR, DINV);
    scatter_kernel<<<EE / 256, 256, 0, stream>>>(e_src, e_dst, CURSOR, COL);

    // h0 = relu(nf @ W_in + b_in)
    gemm_k<<<dim3(2, NN / 64), 256, 0, stream>>>(nf, W_in, b_in, F0, NN, HH, FF, 1);
    // GCN layer 1
    gemm_k<<<dim3(2, NN / 64), 256, 0, stream>>>(F0, W_g1, nullptr, F1, NN, HH, HH, 0);
    gcn_gather<<<NN, HH, 0, stream>>>(F1, ROWPTR, COL, DINV, b_g1, F0);
    // GCN layer 2
    gemm_k<<<dim3(2, NN / 64), 256, 0, stream>>>(F0, W_g2, nullptr, F1, NN, HH, HH, 0);
    gcn_gather<<<NN, HH, 0, stream>>>(F1, ROWPTR, COL, DINV, b_g2, F2);  // F2 = h_gnn

    // xz = h_gnn @ W_inproj (big-tile GEMM)
    gemm_big<<<dim3(4, NN / 128), 256, 0, stream>>>(F2, W_inproj, XZ, NN, 512, HH);
    // conv + silu -> XST; silu(z) -> SZT (both transposed)
    conv_silu_t<<<dim3(NN / 64, 8), 256, 0, stream>>>(XZ, conv_w, conv_b, XST, SZT);
    // dbl = xs @ W_xproj (A^T layout)
    gemm_at<<<dim3(1, NN / 64), 256, 0, stream>>>(XST, W_xproj, DBL, NN, 40, DI);
    // transpose dbl -> DBLT
    transpose_dbl<<<NN / 64, 256, 0, stream>>>(DBL, DBLT);

    // Mamba scan (dt fused into phase1/phase3)
    scan_phase1<<<dim3(8, NCH), 256, 0, stream>>>(XST, DBLT, A_log, W_dt, b_dt, CHP, CHH);
    scan_phase2a<<<(4096 * NG) / 256, 256, 0, stream>>>(CHP, CHH, GP, GH);
    scan_phase2b<<<16, 256, 0, stream>>>(GP, GH, GINI);
    scan_phase2c<<<(4096 * NG) / 256, 256, 0, stream>>>(CHP, CHH, GINI, INI);
    scan_phase3<<<dim3(8, NCH), 256, 0, stream>>>(XST, DBLT, A_log, W_dt, b_dt, INI, D_p, SZT, YT);

    // h_mamba = y @ W_out -> F1 (y stored transposed)
    gemm_at<<<dim3(2, NN / 64), 256, 0, stream>>>(YT, W_out, F1, NN, HH, DI);
    // hh = h_gnn + h_mamba; LayerNorm -> F0
    add_ln<<<NN / 4, 256, 0, stream>>>(F2, F1, gamma, beta, F0);

    // pooling
    pool_kernel<<<NN / 128, HH, 0, stream>>>(F0, batch, GE, COUNTS);
    ge_norm<<<(BB * HH + 255) / 256, 256, 0, stream>>>(GE, COUNTS);

    // heads
    heads_kernel<<<dim3((OUTW + 127) / 128, BB), 128, 0, stream>>>(
        GE, Wc, bc, Wh, bh, Wt, bt, Wp1, bp1, Wp2, bp2, Wd, bd, Ws, bs, (float*)d_out);
}

// Round 9
// 425.275 us; speedup vs baseline: 2.3118x; 1.0557x over previous
//
#include <hip/hip_runtime.h>
#include <math.h>

#define NN 16384
#define EE 262144
#define FF 32
#define HH 128
#define BB 16
#define DI 256
#define DS 16
#define DC 4
#define DTR 8
#define OUTW 1552
#define NCH 256
#define CHLEN 64    // NCH*CHLEN == NN
#define NG 8        // phase2 groups
#define GL 32       // chunks per group; NG*GL == NCH

// ---------------------------------------------------------------- utilities
__device__ __forceinline__ float siluf(float v) { return v / (1.f + __expf(-v)); }
__device__ __forceinline__ float softplusf(float v) {
    return fmaxf(v, 0.f) + __logf(1.f + __expf(-fabsf(v)));
}

// ---------------------------------------------------------------- CSR build
__global__ void deg_kernel(const int* __restrict__ dst, int* __restrict__ cnt) {
    int e = blockIdx.x * blockDim.x + threadIdx.x;
    if (e < EE) atomicAdd(&cnt[dst[e]], 1);
}

__global__ __launch_bounds__(1024) void prefix_kernel(const int* __restrict__ cnt,
                                                      int* __restrict__ rowptr,
                                                      int* __restrict__ cursor,
                                                      float* __restrict__ dinv) {
    __shared__ int part[1024];
    int tid = threadIdx.x;
    int4 c4[4];
#pragma unroll
    for (int j = 0; j < 4; j++) c4[j] = ((const int4*)cnt)[tid * 4 + j];
    int v[16] = {c4[0].x, c4[0].y, c4[0].z, c4[0].w, c4[1].x, c4[1].y, c4[1].z, c4[1].w,
                 c4[2].x, c4[2].y, c4[2].z, c4[2].w, c4[3].x, c4[3].y, c4[3].z, c4[3].w};
    int s = 0;
#pragma unroll
    for (int j = 0; j < 16; j++) s += v[j];
    part[tid] = s;
    __syncthreads();
    for (int off = 1; off < 1024; off <<= 1) {
        int t = (tid >= off) ? part[tid - off] : 0;
        __syncthreads();
        part[tid] += t;
        __syncthreads();
    }
    int running = part[tid] - s;
    int rp[16];
    float dv[16];
#pragma unroll
    for (int j = 0; j < 16; j++) {
        rp[j] = running;
        running += v[j];
        dv[j] = rsqrtf((float)(v[j] + 1));  // +1 self loop
    }
#pragma unroll
    for (int j = 0; j < 4; j++) {
        int4 r4; r4.x = rp[j*4]; r4.y = rp[j*4+1]; r4.z = rp[j*4+2]; r4.w = rp[j*4+3];
        ((int4*)rowptr)[tid * 4 + j] = r4;
        ((int4*)cursor)[tid * 4 + j] = r4;
        float4 d4; d4.x = dv[j*4]; d4.y = dv[j*4+1]; d4.z = dv[j*4+2]; d4.w = dv[j*4+3];
        ((float4*)dinv)[tid * 4 + j] = d4;
    }
    if (tid == 1023) rowptr[NN] = part[1023];
}

__global__ void scatter_kernel(const int* __restrict__ src, const int* __restrict__ dst,
                               int* __restrict__ cursor, int* __restrict__ col) {
    int e = blockIdx.x * blockDim.x + threadIdx.x;
    if (e < EE) {
        int d = dst[e];
        int pos = atomicAdd(&cursor[d], 1);
        col[pos] = src[e];
    }
}

// ---------------------------------------------------------------- GEMM (fp32, 64x64 tile)
__global__ __launch_bounds__(256) void gemm_k(const float* __restrict__ A,
                                              const float* __restrict__ B,
                                              const float* __restrict__ bias,
                                              float* __restrict__ C,
                                              int M, int Nn, int K, int act) {
    __shared__ float As[16][68];
    __shared__ float Bs[16][68];
    int tid = threadIdx.x;
    int m0 = blockIdx.y * 64;
    int n0 = blockIdx.x * 64;
    int ty = tid >> 4, tx = tid & 15;
    float acc[4][4] = {{0.f}};
    for (int k0 = 0; k0 < K; k0 += 16) {
#pragma unroll
        for (int l = 0; l < 4; l++) {
            int idx = tid + l * 256;
            int i = idx >> 4, j = idx & 15;
            As[j][i] = A[(size_t)(m0 + i) * K + k0 + j];
        }
#pragma unroll
        for (int l = 0; l < 4; l++) {
            int idx = tid + l * 256;
            int i = idx >> 6, j = idx & 63;
            int n = n0 + j;
            Bs[i][j] = (n < Nn) ? B[(size_t)(k0 + i) * Nn + n] : 0.f;
        }
        __syncthreads();
#pragma unroll
        for (int kk = 0; kk < 16; kk++) {
            float4 a4 = *(const float4*)&As[kk][ty * 4];
            float4 b4 = *(const float4*)&Bs[kk][tx * 4];
            float av[4] = {a4.x, a4.y, a4.z, a4.w};
            float bv[4] = {b4.x, b4.y, b4.z, b4.w};
#pragma unroll
            for (int r = 0; r < 4; r++)
#pragma unroll
                for (int c = 0; c < 4; c++) acc[r][c] = fmaf(av[r], bv[c], acc[r][c]);
        }
        __syncthreads();
    }
    int nb = n0 + tx * 4;
    if (nb < Nn) {
        float4 bi4 = {0.f, 0.f, 0.f, 0.f};
        if (bias) bi4 = *(const float4*)&bias[nb];
#pragma unroll
        for (int r = 0; r < 4; r++) {
            int m = m0 + ty * 4 + r;
            float4 v;
            v.x = acc[r][0] + bi4.x; v.y = acc[r][1] + bi4.y;
            v.z = acc[r][2] + bi4.z; v.w = acc[r][3] + bi4.w;
            if (act == 1) {
                v.x = fmaxf(v.x, 0.f); v.y = fmaxf(v.y, 0.f);
                v.z = fmaxf(v.z, 0.f); v.w = fmaxf(v.w, 0.f);
            }
            *(float4*)&C[(size_t)m * Nn + nb] = v;
        }
    }
}

// ---------------------------------------------------------------- big-tile GEMM (128x128, 8x8/thread)
__global__ __launch_bounds__(256, 4) void gemm_big(const float* __restrict__ A,
                                                   const float* __restrict__ B,
                                                   float* __restrict__ C,
                                                   int M, int Nn, int K) {
    __shared__ float As[16][132];
    __shared__ float Bs[16][132];
    int tid = threadIdx.x;
    int m0 = blockIdx.y * 128;
    int n0 = blockIdx.x * 128;
    int ty = tid >> 4, tx = tid & 15;
    float acc[8][8] = {{0.f}};
    for (int k0 = 0; k0 < K; k0 += 16) {
        {   // A: 128 m x 16 k -> As[k][m]
            int m = tid >> 1;
            int kc = (tid & 1) * 8;
            const float* ap = &A[(size_t)(m0 + m) * K + k0 + kc];
            float4 a0 = *(const float4*)ap;
            float4 a1 = *(const float4*)(ap + 4);
            As[kc + 0][m] = a0.x; As[kc + 1][m] = a0.y;
            As[kc + 2][m] = a0.z; As[kc + 3][m] = a0.w;
            As[kc + 4][m] = a1.x; As[kc + 5][m] = a1.y;
            As[kc + 6][m] = a1.z; As[kc + 7][m] = a1.w;
        }
        {   // B: 16 k x 128 n
            int krow = tid >> 4;
            int c8 = (tid & 15) * 8;
            const float* bp = &B[(size_t)(k0 + krow) * Nn + n0 + c8];
            *(float4*)&Bs[krow][c8] = *(const float4*)bp;
            *(float4*)&Bs[krow][c8 + 4] = *(const float4*)(bp + 4);
        }
        __syncthreads();
#pragma unroll
        for (int kk = 0; kk < 16; kk++) {
            float4 a0 = *(const float4*)&As[kk][ty * 4];
            float4 a1 = *(const float4*)&As[kk][64 + ty * 4];
            float4 b0 = *(const float4*)&Bs[kk][tx * 4];
            float4 b1 = *(const float4*)&Bs[kk][64 + tx * 4];
            float av[8] = {a0.x, a0.y, a0.z, a0.w, a1.x, a1.y, a1.z, a1.w};
            float bv[8] = {b0.x, b0.y, b0.z, b0.w, b1.x, b1.y, b1.z, b1.w};
#pragma unroll
            for (int r = 0; r < 8; r++)
#pragma unroll
                for (int c = 0; c < 8; c++) acc[r][c] = fmaf(av[r], bv[c], acc[r][c]);
        }
        __syncthreads();
    }
#pragma unroll
    for (int r = 0; r < 8; r++) {
        int m = m0 + ((r < 4) ? (ty * 4 + r) : (64 + ty * 4 + r - 4));
        float4 v0, v1;
        v0.x = acc[r][0]; v0.y = acc[r][1]; v0.z = acc[r][2]; v0.w = acc[r][3];
        v1.x = acc[r][4]; v1.y = acc[r][5]; v1.z = acc[r][6]; v1.w = acc[r][7];
        *(float4*)&C[(size_t)m * Nn + n0 + tx * 4] = v0;
        *(float4*)&C[(size_t)m * Nn + n0 + 64 + tx * 4] = v1;
    }
}

// ---------------------------------------------------------------- GEMM with A^T input (A stored [K][M])
__global__ __launch_bounds__(256) void gemm_at(const float* __restrict__ AT,
                                               const float* __restrict__ B,
                                               float* __restrict__ C,
                                               int M, int Nn, int K) {
    __shared__ float As[16][68];
    __shared__ float Bs[16][68];
    int tid = threadIdx.x;
    int m0 = blockIdx.y * 64;
    int n0 = blockIdx.x * 64;
    int ty = tid >> 4, tx = tid & 15;
    float acc[4][4] = {{0.f}};
    for (int k0 = 0; k0 < K; k0 += 16) {
#pragma unroll
        for (int l = 0; l < 4; l++) {
            int idx = tid + l * 256;
            int kk = idx >> 6, i = idx & 63;
            As[kk][i] = AT[(size_t)(k0 + kk) * M + m0 + i];
        }
#pragma unroll
        for (int l = 0; l < 4; l++) {
            int idx = tid + l * 256;
            int i = idx >> 6, j = idx & 63;
            int n = n0 + j;
            Bs[i][j] = (n < Nn) ? B[(size_t)(k0 + i) * Nn + n] : 0.f;
        }
        __syncthreads();
#pragma unroll
        for (int kk = 0; kk < 16; kk++) {
            float4 a4 = *(const float4*)&As[kk][ty * 4];
            float4 b4 = *(const float4*)&Bs[kk][tx * 4];
            float av[4] = {a4.x, a4.y, a4.z, a4.w};
            float bv[4] = {b4.x, b4.y, b4.z, b4.w};
#pragma unroll
            for (int r = 0; r < 4; r++)
#pragma unroll
                for (int c = 0; c < 4; c++) acc[r][c] = fmaf(av[r], bv[c], acc[r][c]);
        }
        __syncthreads();
    }
    int nb = n0 + tx * 4;
    if (nb < Nn) {
#pragma unroll
        for (int r = 0; r < 4; r++) {
            int m = m0 + ty * 4 + r;
            float4 v;
            v.x = acc[r][0]; v.y = acc[r][1]; v.z = acc[r][2]; v.w = acc[r][3];
            *(float4*)&C[(size_t)m * Nn + nb] = v;
        }
    }
}

// ---------------------------------------------------------------- fused W_out GEMM + add + LayerNorm
// AT = y^T [K=256][M], B = W_out [256][128], hg = h_gnn [M][128].
// Tile 64m x 128n per block -> full rows in-block; LN via 16-lane shfl_xor.
__global__ __launch_bounds__(256) void gemm_at_ln(const float* __restrict__ AT,
                                                  const float* __restrict__ B,
                                                  const float* __restrict__ hg,
                                                  const float* __restrict__ gamma,
                                                  const float* __restrict__ beta,
                                                  float* __restrict__ out) {
    __shared__ float As[16][68];
    __shared__ float Bs[16][132];
    int tid = threadIdx.x;
    int m0 = blockIdx.x * 64;
    int ty = tid >> 4, tx = tid & 15;
    float acc[4][8] = {{0.f}};
    for (int k0 = 0; k0 < 256; k0 += 16) {
#pragma unroll
        for (int l = 0; l < 4; l++) {
            int idx = tid + l * 256;
            int kk = idx >> 6, i = idx & 63;
            As[kk][i] = AT[(size_t)(k0 + kk) * NN + m0 + i];
        }
        {
            int krow = tid >> 4;
            int c8 = (tid & 15) * 8;
            const float* bp = &B[(size_t)(k0 + krow) * HH + c8];
            *(float4*)&Bs[krow][c8] = *(const float4*)bp;
            *(float4*)&Bs[krow][c8 + 4] = *(const float4*)(bp + 4);
        }
        __syncthreads();
#pragma unroll
        for (int kk = 0; kk < 16; kk++) {
            float4 a4 = *(const float4*)&As[kk][ty * 4];
            float4 b0 = *(const float4*)&Bs[kk][tx * 4];
            float4 b1 = *(const float4*)&Bs[kk][64 + tx * 4];
            float av[4] = {a4.x, a4.y, a4.z, a4.w};
            float bv[8] = {b0.x, b0.y, b0.z, b0.w, b1.x, b1.y, b1.z, b1.w};
#pragma unroll
            for (int r = 0; r < 4; r++)
#pragma unroll
                for (int c = 0; c < 8; c++) acc[r][c] = fmaf(av[r], bv[c], acc[r][c]);
        }
        __syncthreads();
    }
    // epilogue: hh = acc + hg; LayerNorm per row (16 lanes x 8 cols = 128)
    float4 g0 = *(const float4*)&gamma[tx * 4];
    float4 g1 = *(const float4*)&gamma[64 + tx * 4];
    float4 be0 = *(const float4*)&beta[tx * 4];
    float4 be1 = *(const float4*)&beta[64 + tx * 4];
    float gv[8] = {g0.x, g0.y, g0.z, g0.w, g1.x, g1.y, g1.z, g1.w};
    float bv[8] = {be0.x, be0.y, be0.z, be0.w, be1.x, be1.y, be1.z, be1.w};
#pragma unroll
    for (int r = 0; r < 4; r++) {
        int m = m0 + ty * 4 + r;
        float4 h0 = *(const float4*)&hg[(size_t)m * HH + tx * 4];
        float4 h1 = *(const float4*)&hg[(size_t)m * HH + 64 + tx * 4];
        float v[8] = {acc[r][0] + h0.x, acc[r][1] + h0.y, acc[r][2] + h0.z, acc[r][3] + h0.w,
                      acc[r][4] + h1.x, acc[r][5] + h1.y, acc[r][6] + h1.z, acc[r][7] + h1.w};
        float sum = 0.f;
#pragma unroll
        for (int c = 0; c < 8; c++) sum += v[c];
        sum += __shfl_xor(sum, 1); sum += __shfl_xor(sum, 2);
        sum += __shfl_xor(sum, 4); sum += __shfl_xor(sum, 8);
        float mu = sum * (1.f / 128.f);
        float vs = 0.f;
#pragma unroll
        for (int c = 0; c < 8; c++) { float dd = v[c] - mu; vs += dd * dd; }
        vs += __shfl_xor(vs, 1); vs += __shfl_xor(vs, 2);
        vs += __shfl_xor(vs, 4); vs += __shfl_xor(vs, 8);
        float inv = rsqrtf(vs * (1.f / 128.f) + 1e-5f);
        float4 o0, o1;
        o0.x = (v[0] - mu) * inv * gv[0] + bv[0];
        o0.y = (v[1] - mu) * inv * gv[1] + bv[1];
        o0.z = (v[2] - mu) * inv * gv[2] + bv[2];
        o0.w = (v[3] - mu) * inv * gv[3] + bv[3];
        o1.x = (v[4] - mu) * inv * gv[4] + bv[4];
        o1.y = (v[5] - mu) * inv * gv[5] + bv[5];
        o1.z = (v[6] - mu) * inv * gv[6] + bv[6];
        o1.w = (v[7] - mu) * inv * gv[7] + bv[7];
        *(float4*)&out[(size_t)m * HH + tx * 4] = o0;
        *(float4*)&out[(size_t)m * HH + 64 + tx * 4] = o1;
    }
}

// ---------------------------------------------------------------- GCN gather, float4 (32 lanes/node)
__global__ __launch_bounds__(256) void gcn_gather4(const float* __restrict__ xw,
                                                   const int* __restrict__ rowptr,
                                                   const int* __restrict__ col,
                                                   const float* __restrict__ dinv,
                                                   const float* __restrict__ b,
                                                   float* __restrict__ out) {
    int tid = threadIdx.x;
    int sub = tid & 31;          // 32 lanes x float4 = 128 floats (one row)
    int n = blockIdx.x * 8 + (tid >> 5);
    float dn = dinv[n];
    const float4* xw4 = (const float4*)xw;
    float4 a = xw4[(size_t)n * 32 + sub];
    float ws = dn * dn;
    float4 acc;
    acc.x = a.x * ws; acc.y = a.y * ws; acc.z = a.z * ws; acc.w = a.w * ws;
    int beg = rowptr[n], end = rowptr[n + 1];
    int e = beg;
    for (; e + 2 <= end; e += 2) {
        int s0 = col[e], s1 = col[e + 1];
        float w0 = dinv[s0] * dn, w1 = dinv[s1] * dn;
        float4 v0 = xw4[(size_t)s0 * 32 + sub];
        float4 v1 = xw4[(size_t)s1 * 32 + sub];
        acc.x = fmaf(v0.x, w0, acc.x); acc.y = fmaf(v0.y, w0, acc.y);
        acc.z = fmaf(v0.z, w0, acc.z); acc.w = fmaf(v0.w, w0, acc.w);
        acc.x = fmaf(v1.x, w1, acc.x); acc.y = fmaf(v1.y, w1, acc.y);
        acc.z = fmaf(v1.z, w1, acc.z); acc.w = fmaf(v1.w, w1, acc.w);
    }
    if (e < end) {
        int s0 = col[e];
        float w0 = dinv[s0] * dn;
        float4 v0 = xw4[(size_t)s0 * 32 + sub];
        acc.x = fmaf(v0.x, w0, acc.x); acc.y = fmaf(v0.y, w0, acc.y);
        acc.z = fmaf(v0.z, w0, acc.z); acc.w = fmaf(v0.w, w0, acc.w);
    }
    float4 b4 = ((const float4*)b)[sub];
    acc.x = fmaxf(acc.x + b4.x, 0.f);
    acc.y = fmaxf(acc.y + b4.y, 0.f);
    acc.z = fmaxf(acc.z + b4.z, 0.f);
    acc.w = fmaxf(acc.w + b4.w, 0.f);
    ((float4*)out)[(size_t)n * 32 + sub] = acc;
}

// ---------------------------------------------------------------- conv + silu, transposed outputs
__global__ __launch_bounds__(256) void conv_silu_t(const float* __restrict__ xz,
                                                   const float* __restrict__ cw,
                                                   const float* __restrict__ cb,
                                                   float* __restrict__ xst,
                                                   float* __restrict__ szt) {
    __shared__ float tile[67][65];
    int tid = threadIdx.x;
    int t0 = blockIdx.x * 64;
    int c0 = blockIdx.y * 64;
#pragma unroll
    for (int l = 0; l < 17; l++) {
        int idx = tid + l * 256;
        if (idx < 67 * 64) {
            int r = idx >> 6, c = idx & 63;
            int gt = t0 - 3 + r;
            tile[r][c] = (gt >= 0) ? xz[(size_t)gt * 512 + c0 + c] : 0.f;
        }
    }
    __syncthreads();
    int tl = tid & 63;
    int d0 = tid >> 6;
    if (c0 < 256) {
#pragma unroll
        for (int l = 0; l < 16; l++) {
            int dl = d0 + l * 4;
            int dg = c0 + dl;
            float acc = cb[dg];
#pragma unroll
            for (int k = 0; k < DC; k++)
                acc = fmaf(tile[tl + k][dl], cw[dg * DC + k], acc);
            xst[dg * NN + t0 + tl] = siluf(acc);
        }
    } else {
#pragma unroll
        for (int l = 0; l < 16; l++) {
            int dl = d0 + l * 4;
            int dg = c0 - 256 + dl;
            szt[dg * NN + t0 + tl] = siluf(tile[tl + 3][dl]);
        }
    }
}

// ---------------------------------------------------------------- transpose dbl [NN][40] -> [40][NN]
__global__ __launch_bounds__(256) void transpose_dbl(const float* __restrict__ dbl,
                                                     float* __restrict__ dblt) {
    __shared__ float tile[64][41];
    int tid = threadIdx.x;
    int t0 = blockIdx.x * 64;
#pragma unroll
    for (int l = 0; l < 10; l++) {
        int idx = tid + l * 256;
        int r = idx / 40, c = idx - r * 40;
        tile[r][c] = dbl[(size_t)(t0 + r) * 40 + c];
    }
    __syncthreads();
#pragma unroll
    for (int l = 0; l < 10; l++) {
        int idx = tid + l * 256;
        int c = idx >> 6, t = idx & 63;
        dblt[c * NN + t0 + t] = tile[t][c];
    }
}

// ---------------------------------------------------------------- Mamba scan (3-phase, LDS-staged)
__global__ __launch_bounds__(256, 6) void scan_phase1(const float* __restrict__ xst,
                                                      const float* __restrict__ dblt,
                                                      const float* __restrict__ A_log,
                                                      const float* __restrict__ W_dt,
                                                      const float* __restrict__ b_dt,
                                                      float* __restrict__ chkP,
                                                      float* __restrict__ chkH) {
    __shared__ float Td[32][68];
    __shared__ float Tx[32][68];
    __shared__ float Bs[16][68];
    __shared__ float D8[8][68];
    int tid = threadIdx.x;
    int wave = tid >> 6, lane = tid & 63;
    int sg = lane & 7, dl = lane >> 3;
    int dblk = blockIdx.x, chunk = blockIdx.y;
    int t0 = chunk * CHLEN;
    int dloc = wave * 8 + dl;
    int d = dblk * 32 + dloc;
    int s0 = 2 * sg;
#pragma unroll
    for (int p = 0; p < 2; p++) {
        int linear = tid + p * 256;
        int row = linear >> 4, c4 = (linear & 15) * 4;
        *(float4*)&Tx[row][c4] = *(const float4*)&xst[(size_t)(dblk * 32 + row) * NN + t0 + c4];
    }
    if (tid < 128) {
        int r = tid >> 4, c4 = (tid & 15) * 4;
        *(float4*)&D8[r][c4] = *(const float4*)&dblt[(size_t)r * NN + t0 + c4];
    }
    {
        int s = tid >> 4, c4 = (tid & 15) * 4;
        *(float4*)&Bs[s][c4] = *(const float4*)&dblt[(size_t)(8 + s) * NN + t0 + c4];
    }
    float A0 = -expf(A_log[d * DS + s0]);
    float A1 = -expf(A_log[d * DS + s0 + 1]);
    __syncthreads();
    {   // dt tile: 32 d x 64 t
        int row = tid >> 3;
        int tb = (tid & 7) * 8;
        int dd = dblk * 32 + row;
        float bd = b_dt[dd];
        float wv[8];
#pragma unroll
        for (int j = 0; j < 8; j++) wv[j] = W_dt[j * DI + dd];
#pragma unroll
        for (int j = 0; j < 8; j++) {
            int t = tb + j;
            float acc = bd;
#pragma unroll
            for (int k = 0; k < 8; k++) acc = fmaf(D8[k][t], wv[k], acc);
            Td[row][t] = softplusf(acc);
        }
    }
    __syncthreads();
    float h0 = 0.f, h1 = 0.f, P0 = 1.f, P1 = 1.f;
    for (int i = 0; i < CHLEN; i += 4) {
        float4 d4 = *(const float4*)&Td[dloc][i];
        float4 x4 = *(const float4*)&Tx[dloc][i];
        float4 b04 = *(const float4*)&Bs[s0][i];
        float4 b14 = *(const float4*)&Bs[s0 + 1][i];
#define P1S(U) { float dtv = d4.U; float a0 = __expf(dtv * A0); float a1 = __expf(dtv * A1); \
        float dx = dtv * x4.U; h0 = fmaf(a0, h0, dx * b04.U); h1 = fmaf(a1, h1, dx * b14.U); \
        P0 *= a0; P1 *= a1; }
        P1S(x) P1S(y) P1S(z) P1S(w)
#undef P1S
    }
    int idx = chunk * 4096 + d * DS + s0;
    float2 vP; vP.x = P0; vP.y = P1;
    float2 vH; vH.x = h0; vH.y = h1;
    *(float2*)(chkP + idx) = vP;
    *(float2*)(chkH + idx) = vH;
}

__global__ void scan_phase2a(const float* __restrict__ chkP, const float* __restrict__ chkH,
                             float* __restrict__ gp, float* __restrict__ gh) {
    int g = blockIdx.x * blockDim.x + threadIdx.x;  // 4096*NG
    int idx = g & 4095;
    int grp = g >> 12;
    int c0 = grp * GL;
    float P = 1.f, H = 0.f;
    for (int j = 0; j < GL; j += 4) {
        float p[4], q[4];
#pragma unroll
        for (int jj = 0; jj < 4; jj++) {
            p[jj] = chkP[(c0 + j + jj) * 4096 + idx];
            q[jj] = chkH[(c0 + j + jj) * 4096 + idx];
        }
#pragma unroll
        for (int jj = 0; jj < 4; jj++) {
            H = fmaf(p[jj], H, q[jj]);
            P *= p[jj];
        }
    }
    gp[grp * 4096 + idx] = P;
    gh[grp * 4096 + idx] = H;
}

__global__ void scan_phase2b(const float* __restrict__ gp, const float* __restrict__ gh,
                             float* __restrict__ gini) {
    int idx = blockIdx.x * blockDim.x + threadIdx.x;  // 4096
    float h = 0.f;
#pragma unroll
    for (int g = 0; g < NG; g++) {
        gini[g * 4096 + idx] = h;
        h = fmaf(gp[g * 4096 + idx], h, gh[g * 4096 + idx]);
    }
}

__global__ void scan_phase2c(const float* __restrict__ chkP, const float* __restrict__ chkH,
                             const float* __restrict__ gini, float* __restrict__ init) {
    int g = blockIdx.x * blockDim.x + threadIdx.x;
    int idx = g & 4095;
    int grp = g >> 12;
    int c0 = grp * GL;
    float h = gini[grp * 4096 + idx];
    for (int j = 0; j < GL; j += 4) {
        float p[4], q[4];
#pragma unroll
        for (int jj = 0; jj < 4; jj++) {
            p[jj] = chkP[(c0 + j + jj) * 4096 + idx];
            q[jj] = chkH[(c0 + j + jj) * 4096 + idx];
        }
#pragma unroll
        for (int jj = 0; jj < 4; jj++) {
            init[(c0 + j + jj) * 4096 + idx] = h;
            h = fmaf(p[jj], h, q[jj]);
        }
    }
}

__global__ __launch_bounds__(256, 5) void scan_phase3(const float* __restrict__ xst,
                                                      const float* __restrict__ dblt,
                                                      const float* __restrict__ A_log,
                                                      const float* __restrict__ W_dt,
                                                      const float* __restrict__ b_dt,
                                                      const float* __restrict__ init,
                                                      const float* __restrict__ D_p,
                                                      const float* __restrict__ szt,
                                                      float* __restrict__ yt) {
    __shared__ float Td[32][68];
    __shared__ float Tx[32][68];
    __shared__ float Bs[16][68];
    __shared__ float Cs[16][68];
    __shared__ float D8[8][68];
    int tid = threadIdx.x;
    int wave = tid >> 6, lane = tid & 63;
    int sg = lane & 7, dl = lane >> 3;
    int dblk = blockIdx.x, chunk = blockIdx.y;
    int t0 = chunk * CHLEN;
    int dloc = wave * 8 + dl;
    int d = dblk * 32 + dloc;
    int s0 = 2 * sg;
#pragma unroll
    for (int p = 0; p < 2; p++) {
        int linear = tid + p * 256;
        int row = linear >> 4, c4 = (linear & 15) * 4;
        *(float4*)&Tx[row][c4] = *(const float4*)&xst[(size_t)(dblk * 32 + row) * NN + t0 + c4];
    }
    if (tid < 128) {
        int r = tid >> 4, c4 = (tid & 15) * 4;
        *(float4*)&D8[r][c4] = *(const float4*)&dblt[(size_t)r * NN + t0 + c4];
    }
    {
        int s = tid >> 4, c4 = (tid & 15) * 4;
        *(float4*)&Bs[s][c4] = *(const float4*)&dblt[(size_t)(8 + s) * NN + t0 + c4];
        *(float4*)&Cs[s][c4] = *(const float4*)&dblt[(size_t)(24 + s) * NN + t0 + c4];
    }
    float A0 = -expf(A_log[d * DS + s0]);
    float A1 = -expf(A_log[d * DS + s0 + 1]);
    float Dd = D_p[d];
    float2 ini = *(const float2*)(init + chunk * 4096 + d * DS + s0);
    float h0 = ini.x, h1 = ini.y;
    __syncthreads();
    {   // dt tile
        int row = tid >> 3;
        int tb = (tid & 7) * 8;
        int dd = dblk * 32 + row;
        float bd = b_dt[dd];
        float wv[8];
#pragma unroll
        for (int j = 0; j < 8; j++) wv[j] = W_dt[j * DI + dd];
#pragma unroll
        for (int j = 0; j < 8; j++) {
            int t = tb + j;
            float acc = bd;
#pragma unroll
            for (int k = 0; k < 8; k++) acc = fmaf(D8[k][t], wv[k], acc);
            Td[row][t] = softplusf(acc);
        }
    }
    __syncthreads();
    for (int i = 0; i < CHLEN; i += 4) {
        float4 d4 = *(const float4*)&Td[dloc][i];
        float4 x4 = *(const float4*)&Tx[dloc][i];
        float4 b04 = *(const float4*)&Bs[s0][i];
        float4 b14 = *(const float4*)&Bs[s0 + 1][i];
        float4 c04 = *(const float4*)&Cs[s0][i];
        float4 c14 = *(const float4*)&Cs[s0 + 1][i];
        float4 yv;
#define P3S(U) { float dtv = d4.U; float a0 = __expf(dtv * A0); float a1 = __expf(dtv * A1); \
        float dx = dtv * x4.U; h0 = fmaf(a0, h0, dx * b04.U); h1 = fmaf(a1, h1, dx * b14.U); \
        float c = fmaf(h1, c14.U, h0 * c04.U); \
        c += __shfl_xor(c, 1); c += __shfl_xor(c, 2); c += __shfl_xor(c, 4); \
        yv.U = c + Dd * x4.U; }
        P3S(x) P3S(y) P3S(z) P3S(w)
#undef P3S
        if (sg == 0) *(float4*)&Td[dloc][i] = yv;  // in-place: this wave's row only
    }
#pragma unroll
    for (int r = 0; r < 8; r++) {
        int row = wave * 8 + r;
        float sz = szt[(size_t)(dblk * 32 + row) * NN + t0 + lane];
        yt[(size_t)(dblk * 32 + row) * NN + t0 + lane] = Td[row][lane] * sz;
    }
}

// ---------------------------------------------------------------- pooling (batch sorted), 4-row unroll
__global__ void pool_kernel(const float* __restrict__ hf, const int* __restrict__ batch,
                            float* __restrict__ ge, int* __restrict__ counts) {
    int f = threadIdx.x;  // 128
    int r0 = blockIdx.x * 128;
    int gcur = batch[r0];
    float acc = 0.f;
    int cnt = 0;
    for (int i = 0; i < 128; i += 4) {
        int r = r0 + i;
        int g0 = batch[r], g3 = batch[r + 3];
        float v0 = hf[(size_t)r * HH + f];
        float v1 = hf[(size_t)(r + 1) * HH + f];
        float v2 = hf[(size_t)(r + 2) * HH + f];
        float v3 = hf[(size_t)(r + 3) * HH + f];
        if (g0 == gcur && g3 == gcur) {
            acc += (v0 + v1) + (v2 + v3);
            cnt += 4;
        } else {
            int gs[4] = {g0, batch[r + 1], batch[r + 2], g3};
            float vs[4] = {v0, v1, v2, v3};
#pragma unroll
            for (int k = 0; k < 4; k++) {
                if (gs[k] != gcur) {
                    atomicAdd(&ge[gcur * HH + f], acc);
                    if (f == 0) atomicAdd(&counts[gcur], cnt);
                    acc = 0.f; cnt = 0; gcur = gs[k];
                }
                acc += vs[k];
                cnt++;
            }
        }
    }
    atomicAdd(&ge[gcur * HH + f], acc);
    if (f == 0) atomicAdd(&counts[gcur], cnt);
}

// ---------------------------------------------------------------- output heads (ge_norm folded in)
__global__ void heads_kernel(const float* __restrict__ ge, const int* __restrict__ counts,
                             const float* Wc, const float* bc, const float* Wh, const float* bh,
                             const float* Wt, const float* bt, const float* Wp1, const float* bp1,
                             const float* Wp2, const float* bp2, const float* Wd, const float* bd,
                             const float* Ws, const float* bs, float* __restrict__ out) {
    int col = blockIdx.x * blockDim.x + threadIdx.x;
    int b = blockIdx.y;
    if (col >= OUTW) return;
    const float* W; const float* bi; int lc, w;
    if (col < 1)         { W = Wc;  bi = bc;  lc = col;        w = 1; }
    else if (col < 5)    { W = Wh;  bi = bh;  lc = col - 1;    w = 4; }
    else if (col < 8)    { W = Wt;  bi = bt;  lc = col - 5;    w = 3; }
    else if (col < 520)  { W = Wp1; bi = bp1; lc = col - 8;    w = 512; }
    else if (col < 1032) { W = Wp2; bi = bp2; lc = col - 520;  w = 512; }
    else if (col < 1544) { W = Wd;  bi = bd;  lc = col - 1032; w = 512; }
    else                 { W = Ws;  bi = bs;  lc = col - 1544; w = 8; }
    float scale = 1.f / fmaxf((float)counts[b], 1.f);
    float dot = 0.f;
#pragma unroll 8
    for (int f = 0; f < HH; f++) dot = fmaf(ge[b * HH + f], W[f * w + lc], dot);
    out[(size_t)b * OUTW + col] = bi[lc] + scale * dot;
}

// ---------------------------------------------------------------- launch
extern "C" void kernel_launch(void* const* d_in, const int* in_sizes, int n_in,
                              void* d_out, int out_size, void* d_ws, size_t ws_size,
                              hipStream_t stream) {
    const float* nf      = (const float*)d_in[0];
    const int*   ei      = (const int*)d_in[1];
    const int*   batch   = (const int*)d_in[2];
    const float* W_in    = (const float*)d_in[3];
    const float* b_in    = (const float*)d_in[4];
    const float* W_g1    = (const float*)d_in[5];
    const float* b_g1    = (const float*)d_in[6];
    const float* W_g2    = (const float*)d_in[7];
    const float* b_g2    = (const float*)d_in[8];
    const float* W_inproj= (const float*)d_in[9];
    const float* conv_w  = (const float*)d_in[10];
    const float* conv_b  = (const float*)d_in[11];
    const float* W_xproj = (const float*)d_in[12];
    const float* W_dt    = (const float*)d_in[13];
    const float* b_dt    = (const float*)d_in[14];
    const float* A_log   = (const float*)d_in[15];
    const float* D_p     = (const float*)d_in[16];
    const float* W_out   = (const float*)d_in[17];
    const float* gamma   = (const float*)d_in[18];
    const float* beta    = (const float*)d_in[19];
    const float* Wc = (const float*)d_in[20]; const float* bc = (const float*)d_in[21];
    const float* Wh = (const float*)d_in[22]; const float* bh = (const float*)d_in[23];
    const float* Wt = (const float*)d_in[24]; const float* bt = (const float*)d_in[25];
    const float* Wp1= (const float*)d_in[26]; const float* bp1= (const float*)d_in[27];
    const float* Wp2= (const float*)d_in[28]; const float* bp2= (const float*)d_in[29];
    const float* Wd = (const float*)d_in[30]; const float* bd = (const float*)d_in[31];
    const float* Ws = (const float*)d_in[32]; const float* bs = (const float*)d_in[33];

    const int* e_src = ei;
    const int* e_dst = ei + EE;

    // workspace layout (floats, then ints)
    float* w = (float*)d_ws;
    size_t o = 0;
    float* F0   = w + o; o += (size_t)NN * HH;   // dead during scan -> CHP/CHH
    float* F1   = w + o; o += (size_t)NN * HH;   // dead during scan -> INI
    float* F2   = w + o; o += (size_t)NN * HH;
    float* XZ   = w + o; o += (size_t)NN * 512;  // dead after conv_silu_t; reused:
    float* YT   = XZ;                             //   y^T [DI][NN]
    float* XST  = w + o; o += (size_t)NN * DI;   // x (conv+silu), transposed [DI][NN]
    float* SZT  = w + o; o += (size_t)NN * DI;   // silu(z), transposed [DI][NN]
    float* DBL  = w + o; o += (size_t)NN * 40;   // dead after transpose_dbl -> GP/GH/GINI
    float* DBLT = w + o; o += (size_t)NN * 40;   // [40][NN]; 0..7 = dt-proj^T, 8..23 = B^T, 24..39 = C^T
    float* GE   = w + o; o += BB * HH;
    float* DINV = w + o; o += NN;
    int* ip = (int*)(w + o);
    int* CNT    = ip; ip += NN;
    int* ROWPTR = ip; ip += NN + 1;
    int* CURSOR = ip; ip += NN;
    int* COL    = ip; ip += EE;
    int* COUNTS = ip; ip += BB;

    // overlays (regions dead during the scan)
    float* CHP  = F0;                         // NCH*4096 = 1M floats
    float* CHH  = F0 + (size_t)NCH * 4096;    // 1M floats (F0 holds 2M)
    float* INI  = F1;                         // NCH*4096 = 1M floats (F1 holds 2M)
    float* GP   = DBL;                        // NG*4096
    float* GH   = DBL + NG * 4096;
    float* GINI = DBL + 2 * NG * 4096;

    hipMemsetAsync(CNT, 0, NN * sizeof(int), stream);
    hipMemsetAsync(GE, 0, BB * HH * sizeof(float), stream);
    hipMemsetAsync(COUNTS, 0, BB * sizeof(int), stream);

    // CSR build
    deg_kernel<<<EE / 256, 256, 0, stream>>>(e_dst, CNT);
    prefix_kernel<<<1, 1024, 0, stream>>>(CNT, ROWPTR, CURSOR, DINV);
    scatter_kernel<<<EE / 256, 256, 0, stream>>>(e_src, e_dst, CURSOR, COL);

    // h0 = relu(nf @ W_in + b_in)
    gemm_k<<<dim3(2, NN / 64), 256, 0, stream>>>(nf, W_in, b_in, F0, NN, HH, FF, 1);
    // GCN layer 1
    gemm_k<<<dim3(2, NN / 64), 256, 0, stream>>>(F0, W_g1, nullptr, F1, NN, HH, HH, 0);
    gcn_gather4<<<NN / 8, 256, 0, stream>>>(F1, ROWPTR, COL, DINV, b_g1, F0);
    // GCN layer 2
    gemm_k<<<dim3(2, NN / 64), 256, 0, stream>>>(F0, W_g2, nullptr, F1, NN, HH, HH, 0);
    gcn_gather4<<<NN / 8, 256, 0, stream>>>(F1, ROWPTR, COL, DINV, b_g2, F2);  // F2 = h_gnn

    // xz = h_gnn @ W_inproj (big-tile GEMM)
    gemm_big<<<dim3(4, NN / 128), 256, 0, stream>>>(F2, W_inproj, XZ, NN, 512, HH);
    // conv + silu -> XST; silu(z) -> SZT (both transposed)
    conv_silu_t<<<dim3(NN / 64, 8), 256, 0, stream>>>(XZ, conv_w, conv_b, XST, SZT);
    // dbl = xs @ W_xproj (A^T layout)
    gemm_at<<<dim3(1, NN / 64), 256, 0, stream>>>(XST, W_xproj, DBL, NN, 40, DI);
    // transpose dbl -> DBLT
    transpose_dbl<<<NN / 64, 256, 0, stream>>>(DBL, DBLT);

    // Mamba scan (dt fused into phase1/phase3)
    scan_phase1<<<dim3(8, NCH), 256, 0, stream>>>(XST, DBLT, A_log, W_dt, b_dt, CHP, CHH);
    scan_phase2a<<<(4096 * NG) / 256, 256, 0, stream>>>(CHP, CHH, GP, GH);
    scan_phase2b<<<16, 256, 0, stream>>>(GP, GH, GINI);
    scan_phase2c<<<(4096 * NG) / 256, 256, 0, stream>>>(CHP, CHH, GINI, INI);
    scan_phase3<<<dim3(8, NCH), 256, 0, stream>>>(XST, DBLT, A_log, W_dt, b_dt, INI, D_p, SZT, YT);

    // h_mamba = y @ W_out; + h_gnn; LayerNorm -> F0 (fused)
    gemm_at_ln<<<NN / 64, 256, 0, stream>>>(YT, W_out, F2, gamma, beta, F0);

    // pooling
    pool_kernel<<<NN / 128, HH, 0, stream>>>(F0, batch, GE, COUNTS);

    // heads (ge_norm folded in)
    heads_kernel<<<dim3((OUTW + 127) / 128, BB), 128, 0, stream>>>(
        GE, COUNTS, Wc, bc, Wh, bh, Wt, bt, Wp1, bp1, Wp2, bp2, Wd, bd, Ws, bs, (float*)d_out);
}

// Round 10
// 412.778 us; speedup vs baseline: 2.3818x; 1.0303x over previous
//
#include <hip/hip_runtime.h>
#include <math.h>

#define NN 16384
#define EE 262144
#define FF 32
#define HH 128
#define BB 16
#define DI 256
#define DS 16
#define DC 4
#define DTR 8
#define OUTW 1552
#define NCH 256
#define CHLEN 64    // NCH*CHLEN == NN
#define NG 8        // phase2 groups
#define GL 32       // chunks per group; NG*GL == NCH

// ---------------------------------------------------------------- utilities
__device__ __forceinline__ float siluf(float v) { return v / (1.f + __expf(-v)); }
__device__ __forceinline__ float softplusf(float v) {
    return fmaxf(v, 0.f) + __logf(1.f + __expf(-fabsf(v)));
}

// ---------------------------------------------------------------- CSR build
__global__ void deg_kernel(const int* __restrict__ dst, int* __restrict__ cnt) {
    int e = blockIdx.x * blockDim.x + threadIdx.x;
    if (e < EE) atomicAdd(&cnt[dst[e]], 1);
}

__global__ __launch_bounds__(1024) void prefix_kernel(const int* __restrict__ cnt,
                                                      int* __restrict__ rowptr,
                                                      int* __restrict__ cursor,
                                                      float* __restrict__ dinv) {
    __shared__ int part[1024];
    int tid = threadIdx.x;
    int4 c4[4];
#pragma unroll
    for (int j = 0; j < 4; j++) c4[j] = ((const int4*)cnt)[tid * 4 + j];
    int v[16] = {c4[0].x, c4[0].y, c4[0].z, c4[0].w, c4[1].x, c4[1].y, c4[1].z, c4[1].w,
                 c4[2].x, c4[2].y, c4[2].z, c4[2].w, c4[3].x, c4[3].y, c4[3].z, c4[3].w};
    int s = 0;
#pragma unroll
    for (int j = 0; j < 16; j++) s += v[j];
    part[tid] = s;
    __syncthreads();
    for (int off = 1; off < 1024; off <<= 1) {
        int t = (tid >= off) ? part[tid - off] : 0;
        __syncthreads();
        part[tid] += t;
        __syncthreads();
    }
    int running = part[tid] - s;
    int rp[16];
    float dv[16];
#pragma unroll
    for (int j = 0; j < 16; j++) {
        rp[j] = running;
        running += v[j];
        dv[j] = rsqrtf((float)(v[j] + 1));  // +1 self loop
    }
#pragma unroll
    for (int j = 0; j < 4; j++) {
        int4 r4; r4.x = rp[j*4]; r4.y = rp[j*4+1]; r4.z = rp[j*4+2]; r4.w = rp[j*4+3];
        ((int4*)rowptr)[tid * 4 + j] = r4;
        ((int4*)cursor)[tid * 4 + j] = r4;
        float4 d4; d4.x = dv[j*4]; d4.y = dv[j*4+1]; d4.z = dv[j*4+2]; d4.w = dv[j*4+3];
        ((float4*)dinv)[tid * 4 + j] = d4;
    }
    if (tid == 1023) rowptr[NN] = part[1023];
}

__global__ void scatter_kernel(const int* __restrict__ src, const int* __restrict__ dst,
                               int* __restrict__ cursor, int* __restrict__ col) {
    int e = blockIdx.x * blockDim.x + threadIdx.x;
    if (e < EE) {
        int d = dst[e];
        int pos = atomicAdd(&cursor[d], 1);
        col[pos] = src[e];
    }
}

// ---------------------------------------------------------------- GEMM (fp32, 64x64 tile)
__global__ __launch_bounds__(256) void gemm_k(const float* __restrict__ A,
                                              const float* __restrict__ B,
                                              const float* __restrict__ bias,
                                              float* __restrict__ C,
                                              int M, int Nn, int K, int act) {
    __shared__ float As[16][68];
    __shared__ float Bs[16][68];
    int tid = threadIdx.x;
    int m0 = blockIdx.y * 64;
    int n0 = blockIdx.x * 64;
    int ty = tid >> 4, tx = tid & 15;
    float acc[4][4] = {{0.f}};
    for (int k0 = 0; k0 < K; k0 += 16) {
#pragma unroll
        for (int l = 0; l < 4; l++) {
            int idx = tid + l * 256;
            int i = idx >> 4, j = idx & 15;
            As[j][i] = A[(size_t)(m0 + i) * K + k0 + j];
        }
#pragma unroll
        for (int l = 0; l < 4; l++) {
            int idx = tid + l * 256;
            int i = idx >> 6, j = idx & 63;
            int n = n0 + j;
            Bs[i][j] = (n < Nn) ? B[(size_t)(k0 + i) * Nn + n] : 0.f;
        }
        __syncthreads();
#pragma unroll
        for (int kk = 0; kk < 16; kk++) {
            float4 a4 = *(const float4*)&As[kk][ty * 4];
            float4 b4 = *(const float4*)&Bs[kk][tx * 4];
            float av[4] = {a4.x, a4.y, a4.z, a4.w};
            float bv[4] = {b4.x, b4.y, b4.z, b4.w};
#pragma unroll
            for (int r = 0; r < 4; r++)
#pragma unroll
                for (int c = 0; c < 4; c++) acc[r][c] = fmaf(av[r], bv[c], acc[r][c]);
        }
        __syncthreads();
    }
    int nb = n0 + tx * 4;
    if (nb < Nn) {
        float4 bi4 = {0.f, 0.f, 0.f, 0.f};
        if (bias) bi4 = *(const float4*)&bias[nb];
#pragma unroll
        for (int r = 0; r < 4; r++) {
            int m = m0 + ty * 4 + r;
            float4 v;
            v.x = acc[r][0] + bi4.x; v.y = acc[r][1] + bi4.y;
            v.z = acc[r][2] + bi4.z; v.w = acc[r][3] + bi4.w;
            if (act == 1) {
                v.x = fmaxf(v.x, 0.f); v.y = fmaxf(v.y, 0.f);
                v.z = fmaxf(v.z, 0.f); v.w = fmaxf(v.w, 0.f);
            }
            *(float4*)&C[(size_t)m * Nn + nb] = v;
        }
    }
}

// ---------------------------------------------------------------- big-tile GEMM (128x128, 8x8/thread)
__global__ __launch_bounds__(256, 4) void gemm_big(const float* __restrict__ A,
                                                   const float* __restrict__ B,
                                                   float* __restrict__ C,
                                                   int M, int Nn, int K) {
    __shared__ float As[16][132];
    __shared__ float Bs[16][132];
    int tid = threadIdx.x;
    int m0 = blockIdx.y * 128;
    int n0 = blockIdx.x * 128;
    int ty = tid >> 4, tx = tid & 15;
    float acc[8][8] = {{0.f}};
    for (int k0 = 0; k0 < K; k0 += 16) {
        {   // A: 128 m x 16 k -> As[k][m]
            int m = tid >> 1;
            int kc = (tid & 1) * 8;
            const float* ap = &A[(size_t)(m0 + m) * K + k0 + kc];
            float4 a0 = *(const float4*)ap;
            float4 a1 = *(const float4*)(ap + 4);
            As[kc + 0][m] = a0.x; As[kc + 1][m] = a0.y;
            As[kc + 2][m] = a0.z; As[kc + 3][m] = a0.w;
            As[kc + 4][m] = a1.x; As[kc + 5][m] = a1.y;
            As[kc + 6][m] = a1.z; As[kc + 7][m] = a1.w;
        }
        {   // B: 16 k x 128 n
            int krow = tid >> 4;
            int c8 = (tid & 15) * 8;
            const float* bp = &B[(size_t)(k0 + krow) * Nn + n0 + c8];
            *(float4*)&Bs[krow][c8] = *(const float4*)bp;
            *(float4*)&Bs[krow][c8 + 4] = *(const float4*)(bp + 4);
        }
        __syncthreads();
#pragma unroll
        for (int kk = 0; kk < 16; kk++) {
            float4 a0 = *(const float4*)&As[kk][ty * 4];
            float4 a1 = *(const float4*)&As[kk][64 + ty * 4];
            float4 b0 = *(const float4*)&Bs[kk][tx * 4];
            float4 b1 = *(const float4*)&Bs[kk][64 + tx * 4];
            float av[8] = {a0.x, a0.y, a0.z, a0.w, a1.x, a1.y, a1.z, a1.w};
            float bv[8] = {b0.x, b0.y, b0.z, b0.w, b1.x, b1.y, b1.z, b1.w};
#pragma unroll
            for (int r = 0; r < 8; r++)
#pragma unroll
                for (int c = 0; c < 8; c++) acc[r][c] = fmaf(av[r], bv[c], acc[r][c]);
        }
        __syncthreads();
    }
#pragma unroll
    for (int r = 0; r < 8; r++) {
        int m = m0 + ((r < 4) ? (ty * 4 + r) : (64 + ty * 4 + r - 4));
        float4 v0, v1;
        v0.x = acc[r][0]; v0.y = acc[r][1]; v0.z = acc[r][2]; v0.w = acc[r][3];
        v1.x = acc[r][4]; v1.y = acc[r][5]; v1.z = acc[r][6]; v1.w = acc[r][7];
        *(float4*)&C[(size_t)m * Nn + n0 + tx * 4] = v0;
        *(float4*)&C[(size_t)m * Nn + n0 + 64 + tx * 4] = v1;
    }
}

// ---------------------------------------------------------------- xproj GEMM (A^T) + transposed output
// AT = XST [256][NN]; B = W_xproj [256][40]; writes DBLT[n][m] directly (LDS transpose).
__global__ __launch_bounds__(256) void gemm_at_dblt(const float* __restrict__ AT,
                                                    const float* __restrict__ B,
                                                    float* __restrict__ dblt) {
    __shared__ float As[16][68];
    __shared__ float Bs[16][68];
    __shared__ float Ct[64][41];
    int tid = threadIdx.x;
    int m0 = blockIdx.x * 64;
    int ty = tid >> 4, tx = tid & 15;
    float acc[4][4] = {{0.f}};
    for (int k0 = 0; k0 < DI; k0 += 16) {
#pragma unroll
        for (int l = 0; l < 4; l++) {
            int idx = tid + l * 256;
            int kk = idx >> 6, i = idx & 63;
            As[kk][i] = AT[(size_t)(k0 + kk) * NN + m0 + i];
        }
#pragma unroll
        for (int l = 0; l < 4; l++) {
            int idx = tid + l * 256;
            int i = idx >> 6, j = idx & 63;
            Bs[i][j] = (j < 40) ? B[(size_t)(k0 + i) * 40 + j] : 0.f;
        }
        __syncthreads();
#pragma unroll
        for (int kk = 0; kk < 16; kk++) {
            float4 a4 = *(const float4*)&As[kk][ty * 4];
            float4 b4 = *(const float4*)&Bs[kk][tx * 4];
            float av[4] = {a4.x, a4.y, a4.z, a4.w};
            float bv[4] = {b4.x, b4.y, b4.z, b4.w};
#pragma unroll
            for (int r = 0; r < 4; r++)
#pragma unroll
                for (int c = 0; c < 4; c++) acc[r][c] = fmaf(av[r], bv[c], acc[r][c]);
        }
        __syncthreads();
    }
    // stage C tile (m x n) into LDS, write DBLT rows coalesced
    if (tx * 4 < 40) {
#pragma unroll
        for (int r = 0; r < 4; r++) {
            int m = ty * 4 + r;
            Ct[m][tx * 4 + 0] = acc[r][0];
            Ct[m][tx * 4 + 1] = acc[r][1];
            Ct[m][tx * 4 + 2] = acc[r][2];
            Ct[m][tx * 4 + 3] = acc[r][3];
        }
    }
    __syncthreads();
#pragma unroll
    for (int l = 0; l < 10; l++) {
        int idx = tid + l * 256;
        int n = idx >> 6, m = idx & 63;
        dblt[(size_t)n * NN + m0 + m] = Ct[m][n];
    }
}

// ---------------------------------------------------------------- fused W_out GEMM + add + LayerNorm
// 32m x 128n tile per block (512 blocks); LN via 16-lane shfl.
__global__ __launch_bounds__(256) void gemm_at_ln(const float* __restrict__ AT,
                                                  const float* __restrict__ B,
                                                  const float* __restrict__ hg,
                                                  const float* __restrict__ gamma,
                                                  const float* __restrict__ beta,
                                                  float* __restrict__ out) {
    __shared__ float As[16][36];
    __shared__ float Bs[16][132];
    int tid = threadIdx.x;
    int m0 = blockIdx.x * 32;
    int ty = tid >> 4, tx = tid & 15;
    float acc[2][8] = {{0.f}};
    for (int k0 = 0; k0 < 256; k0 += 16) {
        {   // A: 16 k x 32 m -> 512 floats, 2/thread
            int idx = tid * 2;
            int kk = idx >> 5, i = idx & 31;
            As[kk][i] = AT[(size_t)(k0 + kk) * NN + m0 + i];
            As[kk][i + 1] = AT[(size_t)(k0 + kk) * NN + m0 + i + 1];
        }
        {
            int krow = tid >> 4;
            int c8 = (tid & 15) * 8;
            const float* bp = &B[(size_t)(k0 + krow) * HH + c8];
            *(float4*)&Bs[krow][c8] = *(const float4*)bp;
            *(float4*)&Bs[krow][c8 + 4] = *(const float4*)(bp + 4);
        }
        __syncthreads();
#pragma unroll
        for (int kk = 0; kk < 16; kk++) {
            float a0 = As[kk][ty * 2];
            float a1 = As[kk][ty * 2 + 1];
            float4 b0 = *(const float4*)&Bs[kk][tx * 4];
            float4 b1 = *(const float4*)&Bs[kk][64 + tx * 4];
            float bv[8] = {b0.x, b0.y, b0.z, b0.w, b1.x, b1.y, b1.z, b1.w};
#pragma unroll
            for (int c = 0; c < 8; c++) {
                acc[0][c] = fmaf(a0, bv[c], acc[0][c]);
                acc[1][c] = fmaf(a1, bv[c], acc[1][c]);
            }
        }
        __syncthreads();
    }
    float4 g0 = *(const float4*)&gamma[tx * 4];
    float4 g1 = *(const float4*)&gamma[64 + tx * 4];
    float4 be0 = *(const float4*)&beta[tx * 4];
    float4 be1 = *(const float4*)&beta[64 + tx * 4];
    float gv[8] = {g0.x, g0.y, g0.z, g0.w, g1.x, g1.y, g1.z, g1.w};
    float bv[8] = {be0.x, be0.y, be0.z, be0.w, be1.x, be1.y, be1.z, be1.w};
#pragma unroll
    for (int r = 0; r < 2; r++) {
        int m = m0 + ty * 2 + r;
        float4 h0 = *(const float4*)&hg[(size_t)m * HH + tx * 4];
        float4 h1 = *(const float4*)&hg[(size_t)m * HH + 64 + tx * 4];
        float v[8] = {acc[r][0] + h0.x, acc[r][1] + h0.y, acc[r][2] + h0.z, acc[r][3] + h0.w,
                      acc[r][4] + h1.x, acc[r][5] + h1.y, acc[r][6] + h1.z, acc[r][7] + h1.w};
        float sum = 0.f;
#pragma unroll
        for (int c = 0; c < 8; c++) sum += v[c];
        sum += __shfl_xor(sum, 1); sum += __shfl_xor(sum, 2);
        sum += __shfl_xor(sum, 4); sum += __shfl_xor(sum, 8);
        float mu = sum * (1.f / 128.f);
        float vs = 0.f;
#pragma unroll
        for (int c = 0; c < 8; c++) { float dd = v[c] - mu; vs += dd * dd; }
        vs += __shfl_xor(vs, 1); vs += __shfl_xor(vs, 2);
        vs += __shfl_xor(vs, 4); vs += __shfl_xor(vs, 8);
        float inv = rsqrtf(vs * (1.f / 128.f) + 1e-5f);
        float4 o0, o1;
        o0.x = (v[0] - mu) * inv * gv[0] + bv[0];
        o0.y = (v[1] - mu) * inv * gv[1] + bv[1];
        o0.z = (v[2] - mu) * inv * gv[2] + bv[2];
        o0.w = (v[3] - mu) * inv * gv[3] + bv[3];
        o1.x = (v[4] - mu) * inv * gv[4] + bv[4];
        o1.y = (v[5] - mu) * inv * gv[5] + bv[5];
        o1.z = (v[6] - mu) * inv * gv[6] + bv[6];
        o1.w = (v[7] - mu) * inv * gv[7] + bv[7];
        *(float4*)&out[(size_t)m * HH + tx * 4] = o0;
        *(float4*)&out[(size_t)m * HH + 64 + tx * 4] = o1;
    }
}

// ---------------------------------------------------------------- GCN gather, float4, 4-edge unroll
__global__ __launch_bounds__(256) void gcn_gather4(const float* __restrict__ xw,
                                                   const int* __restrict__ rowptr,
                                                   const int* __restrict__ col,
                                                   const float* __restrict__ dinv,
                                                   const float* __restrict__ b,
                                                   float* __restrict__ out) {
    int tid = threadIdx.x;
    int sub = tid & 31;          // 32 lanes x float4 = 128 floats (one row)
    int n = blockIdx.x * 8 + (tid >> 5);
    float dn = dinv[n];
    const float4* xw4 = (const float4*)xw;
    float4 a = xw4[(size_t)n * 32 + sub];
    float ws = dn * dn;
    float4 acc;
    acc.x = a.x * ws; acc.y = a.y * ws; acc.z = a.z * ws; acc.w = a.w * ws;
    int beg = rowptr[n], end = rowptr[n + 1];
    int e = beg;
    for (; e + 4 <= end; e += 4) {
        int s0 = col[e], s1 = col[e + 1], s2 = col[e + 2], s3 = col[e + 3];
        float w0 = dinv[s0] * dn, w1 = dinv[s1] * dn;
        float w2 = dinv[s2] * dn, w3 = dinv[s3] * dn;
        float4 v0 = xw4[(size_t)s0 * 32 + sub];
        float4 v1 = xw4[(size_t)s1 * 32 + sub];
        float4 v2 = xw4[(size_t)s2 * 32 + sub];
        float4 v3 = xw4[(size_t)s3 * 32 + sub];
        acc.x = fmaf(v0.x, w0, acc.x); acc.y = fmaf(v0.y, w0, acc.y);
        acc.z = fmaf(v0.z, w0, acc.z); acc.w = fmaf(v0.w, w0, acc.w);
        acc.x = fmaf(v1.x, w1, acc.x); acc.y = fmaf(v1.y, w1, acc.y);
        acc.z = fmaf(v1.z, w1, acc.z); acc.w = fmaf(v1.w, w1, acc.w);
        acc.x = fmaf(v2.x, w2, acc.x); acc.y = fmaf(v2.y, w2, acc.y);
        acc.z = fmaf(v2.z, w2, acc.z); acc.w = fmaf(v2.w, w2, acc.w);
        acc.x = fmaf(v3.x, w3, acc.x); acc.y = fmaf(v3.y, w3, acc.y);
        acc.z = fmaf(v3.z, w3, acc.z); acc.w = fmaf(v3.w, w3, acc.w);
    }
    for (; e < end; e++) {
        int s0 = col[e];
        float w0 = dinv[s0] * dn;
        float4 v0 = xw4[(size_t)s0 * 32 + sub];
        acc.x = fmaf(v0.x, w0, acc.x); acc.y = fmaf(v0.y, w0, acc.y);
        acc.z = fmaf(v0.z, w0, acc.z); acc.w = fmaf(v0.w, w0, acc.w);
    }
    float4 b4 = ((const float4*)b)[sub];
    acc.x = fmaxf(acc.x + b4.x, 0.f);
    acc.y = fmaxf(acc.y + b4.y, 0.f);
    acc.z = fmaxf(acc.z + b4.z, 0.f);
    acc.w = fmaxf(acc.w + b4.w, 0.f);
    ((float4*)out)[(size_t)n * 32 + sub] = acc;
}

// ---------------------------------------------------------------- conv + silu, transposed outputs
__global__ __launch_bounds__(256) void conv_silu_t(const float* __restrict__ xz,
                                                   const float* __restrict__ cw,
                                                   const float* __restrict__ cb,
                                                   float* __restrict__ xst,
                                                   float* __restrict__ szt) {
    __shared__ float tile[67][65];
    int tid = threadIdx.x;
    int t0 = blockIdx.x * 64;
    int c0 = blockIdx.y * 64;
#pragma unroll
    for (int l = 0; l < 17; l++) {
        int idx = tid + l * 256;
        if (idx < 67 * 64) {
            int r = idx >> 6, c = idx & 63;
            int gt = t0 - 3 + r;
            tile[r][c] = (gt >= 0) ? xz[(size_t)gt * 512 + c0 + c] : 0.f;
        }
    }
    __syncthreads();
    int tl = tid & 63;
    int d0 = tid >> 6;
    if (c0 < 256) {
#pragma unroll
        for (int l = 0; l < 16; l++) {
            int dl = d0 + l * 4;
            int dg = c0 + dl;
            float acc = cb[dg];
#pragma unroll
            for (int k = 0; k < DC; k++)
                acc = fmaf(tile[tl + k][dl], cw[dg * DC + k], acc);
            xst[dg * NN + t0 + tl] = siluf(acc);
        }
    } else {
#pragma unroll
        for (int l = 0; l < 16; l++) {
            int dl = d0 + l * 4;
            int dg = c0 - 256 + dl;
            szt[dg * NN + t0 + tl] = siluf(tile[tl + 3][dl]);
        }
    }
}

// ---------------------------------------------------------------- Mamba scan (3-phase, LDS-staged)
__global__ __launch_bounds__(256, 6) void scan_phase1(const float* __restrict__ xst,
                                                      const float* __restrict__ dblt,
                                                      const float* __restrict__ A_log,
                                                      const float* __restrict__ W_dt,
                                                      const float* __restrict__ b_dt,
                                                      float* __restrict__ chkP,
                                                      float* __restrict__ chkH) {
    __shared__ float Td[32][68];
    __shared__ float Tx[32][68];
    __shared__ float Bs[16][68];
    __shared__ float D8[8][68];
    int tid = threadIdx.x;
    int wave = tid >> 6, lane = tid & 63;
    int sg = lane & 7, dl = lane >> 3;
    int dblk = blockIdx.x, chunk = blockIdx.y;
    int t0 = chunk * CHLEN;
    int dloc = wave * 8 + dl;
    int d = dblk * 32 + dloc;
    int s0 = 2 * sg;
#pragma unroll
    for (int p = 0; p < 2; p++) {
        int linear = tid + p * 256;
        int row = linear >> 4, c4 = (linear & 15) * 4;
        *(float4*)&Tx[row][c4] = *(const float4*)&xst[(size_t)(dblk * 32 + row) * NN + t0 + c4];
    }
    if (tid < 128) {
        int r = tid >> 4, c4 = (tid & 15) * 4;
        *(float4*)&D8[r][c4] = *(const float4*)&dblt[(size_t)r * NN + t0 + c4];
    }
    {
        int s = tid >> 4, c4 = (tid & 15) * 4;
        *(float4*)&Bs[s][c4] = *(const float4*)&dblt[(size_t)(8 + s) * NN + t0 + c4];
    }
    float A0 = -expf(A_log[d * DS + s0]);
    float A1 = -expf(A_log[d * DS + s0 + 1]);
    __syncthreads();
    {   // dt tile: 32 d x 64 t
        int row = tid >> 3;
        int tb = (tid & 7) * 8;
        int dd = dblk * 32 + row;
        float bd = b_dt[dd];
        float wv[8];
#pragma unroll
        for (int j = 0; j < 8; j++) wv[j] = W_dt[j * DI + dd];
#pragma unroll
        for (int j = 0; j < 8; j++) {
            int t = tb + j;
            float acc = bd;
#pragma unroll
            for (int k = 0; k < 8; k++) acc = fmaf(D8[k][t], wv[k], acc);
            Td[row][t] = softplusf(acc);
        }
    }
    __syncthreads();
    float h0 = 0.f, h1 = 0.f, P0 = 1.f, P1 = 1.f;
    for (int i = 0; i < CHLEN; i += 4) {
        float4 d4 = *(const float4*)&Td[dloc][i];
        float4 x4 = *(const float4*)&Tx[dloc][i];
        float4 b04 = *(const float4*)&Bs[s0][i];
        float4 b14 = *(const float4*)&Bs[s0 + 1][i];
#define P1S(U) { float dtv = d4.U; float a0 = __expf(dtv * A0); float a1 = __expf(dtv * A1); \
        float dx = dtv * x4.U; h0 = fmaf(a0, h0, dx * b04.U); h1 = fmaf(a1, h1, dx * b14.U); \
        P0 *= a0; P1 *= a1; }
        P1S(x) P1S(y) P1S(z) P1S(w)
#undef P1S
    }
    int idx = chunk * 4096 + d * DS + s0;
    float2 vP; vP.x = P0; vP.y = P1;
    float2 vH; vH.x = h0; vH.y = h1;
    *(float2*)(chkP + idx) = vP;
    *(float2*)(chkH + idx) = vH;
}

__global__ void scan_phase2a(const float* __restrict__ chkP, const float* __restrict__ chkH,
                             float* __restrict__ gp, float* __restrict__ gh) {
    int g = blockIdx.x * blockDim.x + threadIdx.x;  // 4096*NG
    int idx = g & 4095;
    int grp = g >> 12;
    int c0 = grp * GL;
    float P = 1.f, H = 0.f;
    for (int j = 0; j < GL; j += 4) {
        float p[4], q[4];
#pragma unroll
        for (int jj = 0; jj < 4; jj++) {
            p[jj] = chkP[(c0 + j + jj) * 4096 + idx];
            q[jj] = chkH[(c0 + j + jj) * 4096 + idx];
        }
#pragma unroll
        for (int jj = 0; jj < 4; jj++) {
            H = fmaf(p[jj], H, q[jj]);
            P *= p[jj];
        }
    }
    gp[grp * 4096 + idx] = P;
    gh[grp * 4096 + idx] = H;
}

// phase2c (2b folded in): compose group prefix inline, then replay within group
__global__ void scan_phase2c(const float* __restrict__ chkP, const float* __restrict__ chkH,
                             const float* __restrict__ gp, const float* __restrict__ gh,
                             float* __restrict__ init) {
    int g = blockIdx.x * blockDim.x + threadIdx.x;
    int idx = g & 4095;
    int grp = g >> 12;
    int c0 = grp * GL;
    float h = 0.f;
    for (int gg = 0; gg < grp; gg++)
        h = fmaf(gp[gg * 4096 + idx], h, gh[gg * 4096 + idx]);
    for (int j = 0; j < GL; j += 4) {
        float p[4], q[4];
#pragma unroll
        for (int jj = 0; jj < 4; jj++) {
            p[jj] = chkP[(c0 + j + jj) * 4096 + idx];
            q[jj] = chkH[(c0 + j + jj) * 4096 + idx];
        }
#pragma unroll
        for (int jj = 0; jj < 4; jj++) {
            init[(c0 + j + jj) * 4096 + idx] = h;
            h = fmaf(p[jj], h, q[jj]);
        }
    }
}

__global__ __launch_bounds__(256, 5) void scan_phase3(const float* __restrict__ xst,
                                                      const float* __restrict__ dblt,
                                                      const float* __restrict__ A_log,
                                                      const float* __restrict__ W_dt,
                                                      const float* __restrict__ b_dt,
                                                      const float* __restrict__ init,
                                                      const float* __restrict__ D_p,
                                                      const float* __restrict__ szt,
                                                      float* __restrict__ yt) {
    __shared__ float Td[32][68];
    __shared__ float Tx[32][68];
    __shared__ float Bs[16][68];
    __shared__ float Cs[16][68];
    __shared__ float D8[8][68];
    int tid = threadIdx.x;
    int wave = tid >> 6, lane = tid & 63;
    int sg = lane & 7, dl = lane >> 3;
    int dblk = blockIdx.x, chunk = blockIdx.y;
    int t0 = chunk * CHLEN;
    int dloc = wave * 8 + dl;
    int d = dblk * 32 + dloc;
    int s0 = 2 * sg;
#pragma unroll
    for (int p = 0; p < 2; p++) {
        int linear = tid + p * 256;
        int row = linear >> 4, c4 = (linear & 15) * 4;
        *(float4*)&Tx[row][c4] = *(const float4*)&xst[(size_t)(dblk * 32 + row) * NN + t0 + c4];
    }
    if (tid < 128) {
        int r = tid >> 4, c4 = (tid & 15) * 4;
        *(float4*)&D8[r][c4] = *(const float4*)&dblt[(size_t)r * NN + t0 + c4];
    }
    {
        int s = tid >> 4, c4 = (tid & 15) * 4;
        *(float4*)&Bs[s][c4] = *(const float4*)&dblt[(size_t)(8 + s) * NN + t0 + c4];
        *(float4*)&Cs[s][c4] = *(const float4*)&dblt[(size_t)(24 + s) * NN + t0 + c4];
    }
    float A0 = -expf(A_log[d * DS + s0]);
    float A1 = -expf(A_log[d * DS + s0 + 1]);
    float Dd = D_p[d];
    float2 ini = *(const float2*)(init + chunk * 4096 + d * DS + s0);
    float h0 = ini.x, h1 = ini.y;
    __syncthreads();
    {   // dt tile
        int row = tid >> 3;
        int tb = (tid & 7) * 8;
        int dd = dblk * 32 + row;
        float bd = b_dt[dd];
        float wv[8];
#pragma unroll
        for (int j = 0; j < 8; j++) wv[j] = W_dt[j * DI + dd];
#pragma unroll
        for (int j = 0; j < 8; j++) {
            int t = tb + j;
            float acc = bd;
#pragma unroll
            for (int k = 0; k < 8; k++) acc = fmaf(D8[k][t], wv[k], acc);
            Td[row][t] = softplusf(acc);
        }
    }
    __syncthreads();
    for (int i = 0; i < CHLEN; i += 4) {
        float4 d4 = *(const float4*)&Td[dloc][i];
        float4 x4 = *(const float4*)&Tx[dloc][i];
        float4 b04 = *(const float4*)&Bs[s0][i];
        float4 b14 = *(const float4*)&Bs[s0 + 1][i];
        float4 c04 = *(const float4*)&Cs[s0][i];
        float4 c14 = *(const float4*)&Cs[s0 + 1][i];
        float4 yv;
#define P3S(U) { float dtv = d4.U; float a0 = __expf(dtv * A0); float a1 = __expf(dtv * A1); \
        float dx = dtv * x4.U; h0 = fmaf(a0, h0, dx * b04.U); h1 = fmaf(a1, h1, dx * b14.U); \
        float c = fmaf(h1, c14.U, h0 * c04.U); \
        c += __shfl_xor(c, 1); c += __shfl_xor(c, 2); c += __shfl_xor(c, 4); \
        yv.U = c + Dd * x4.U; }
        P3S(x) P3S(y) P3S(z) P3S(w)
#undef P3S
        if (sg == 0) *(float4*)&Td[dloc][i] = yv;  // in-place: this wave's row only
    }
#pragma unroll
    for (int r = 0; r < 8; r++) {
        int row = wave * 8 + r;
        float sz = szt[(size_t)(dblk * 32 + row) * NN + t0 + lane];
        yt[(size_t)(dblk * 32 + row) * NN + t0 + lane] = Td[row][lane] * sz;
    }
}

// ---------------------------------------------------------------- pooling (batch sorted), 4-row unroll
__global__ void pool_kernel(const float* __restrict__ hf, const int* __restrict__ batch,
                            float* __restrict__ ge, int* __restrict__ counts) {
    int f = threadIdx.x;  // 128
    int r0 = blockIdx.x * 128;
    int gcur = batch[r0];
    float acc = 0.f;
    int cnt = 0;
    for (int i = 0; i < 128; i += 4) {
        int r = r0 + i;
        int g0 = batch[r], g3 = batch[r + 3];
        float v0 = hf[(size_t)r * HH + f];
        float v1 = hf[(size_t)(r + 1) * HH + f];
        float v2 = hf[(size_t)(r + 2) * HH + f];
        float v3 = hf[(size_t)(r + 3) * HH + f];
        if (g0 == gcur && g3 == gcur) {
            acc += (v0 + v1) + (v2 + v3);
            cnt += 4;
        } else {
            int gs[4] = {g0, batch[r + 1], batch[r + 2], g3};
            float vs[4] = {v0, v1, v2, v3};
#pragma unroll
            for (int k = 0; k < 4; k++) {
                if (gs[k] != gcur) {
                    atomicAdd(&ge[gcur * HH + f], acc);
                    if (f == 0) atomicAdd(&counts[gcur], cnt);
                    acc = 0.f; cnt = 0; gcur = gs[k];
                }
                acc += vs[k];
                cnt++;
            }
        }
    }
    atomicAdd(&ge[gcur * HH + f], acc);
    if (f == 0) atomicAdd(&counts[gcur], cnt);
}

// ---------------------------------------------------------------- output heads (ge_norm folded in)
__global__ void heads_kernel(const float* __restrict__ ge, const int* __restrict__ counts,
                             const float* Wc, const float* bc, const float* Wh, const float* bh,
                             const float* Wt, const float* bt, const float* Wp1, const float* bp1,
                             const float* Wp2, const float* bp2, const float* Wd, const float* bd,
                             const float* Ws, const float* bs, float* __restrict__ out) {
    int col = blockIdx.x * blockDim.x + threadIdx.x;
    int b = blockIdx.y;
    if (col >= OUTW) return;
    const float* W; const float* bi; int lc, w;
    if (col < 1)         { W = Wc;  bi = bc;  lc = col;        w = 1; }
    else if (col < 5)    { W = Wh;  bi = bh;  lc = col - 1;    w = 4; }
    else if (col < 8)    { W = Wt;  bi = bt;  lc = col - 5;    w = 3; }
    else if (col < 520)  { W = Wp1; bi = bp1; lc = col - 8;    w = 512; }
    else if (col < 1032) { W = Wp2; bi = bp2; lc = col - 520;  w = 512; }
    else if (col < 1544) { W = Wd;  bi = bd;  lc = col - 1032; w = 512; }
    else                 { W = Ws;  bi = bs;  lc = col - 1544; w = 8; }
    float scale = 1.f / fmaxf((float)counts[b], 1.f);
    float dot = 0.f;
#pragma unroll 8
    for (int f = 0; f < HH; f++) dot = fmaf(ge[b * HH + f], W[f * w + lc], dot);
    out[(size_t)b * OUTW + col] = bi[lc] + scale * dot;
}

// ---------------------------------------------------------------- launch
extern "C" void kernel_launch(void* const* d_in, const int* in_sizes, int n_in,
                              void* d_out, int out_size, void* d_ws, size_t ws_size,
                              hipStream_t stream) {
    const float* nf      = (const float*)d_in[0];
    const int*   ei      = (const int*)d_in[1];
    const int*   batch   = (const int*)d_in[2];
    const float* W_in    = (const float*)d_in[3];
    const float* b_in    = (const float*)d_in[4];
    const float* W_g1    = (const float*)d_in[5];
    const float* b_g1    = (const float*)d_in[6];
    const float* W_g2    = (const float*)d_in[7];
    const float* b_g2    = (const float*)d_in[8];
    const float* W_inproj= (const float*)d_in[9];
    const float* conv_w  = (const float*)d_in[10];
    const float* conv_b  = (const float*)d_in[11];
    const float* W_xproj = (const float*)d_in[12];
    const float* W_dt    = (const float*)d_in[13];
    const float* b_dt    = (const float*)d_in[14];
    const float* A_log   = (const float*)d_in[15];
    const float* D_p     = (const float*)d_in[16];
    const float* W_out   = (const float*)d_in[17];
    const float* gamma   = (const float*)d_in[18];
    const float* beta    = (const float*)d_in[19];
    const float* Wc = (const float*)d_in[20]; const float* bc = (const float*)d_in[21];
    const float* Wh = (const float*)d_in[22]; const float* bh = (const float*)d_in[23];
    const float* Wt = (const float*)d_in[24]; const float* bt = (const float*)d_in[25];
    const float* Wp1= (const float*)d_in[26]; const float* bp1= (const float*)d_in[27];
    const float* Wp2= (const float*)d_in[28]; const float* bp2= (const float*)d_in[29];
    const float* Wd = (const float*)d_in[30]; const float* bd = (const float*)d_in[31];
    const float* Ws = (const float*)d_in[32]; const float* bs = (const float*)d_in[33];

    const int* e_src = ei;
    const int* e_dst = ei + EE;

    // workspace layout (floats, then ints)
    float* w = (float*)d_ws;
    size_t o = 0;
    float* F0   = w + o; o += (size_t)NN * HH;   // dead during scan -> CHP/CHH
    float* F1   = w + o; o += (size_t)NN * HH;   // dead during scan -> INI
    float* F2   = w + o; o += (size_t)NN * HH;
    float* XZ   = w + o; o += (size_t)NN * 512;  // dead after conv_silu_t; reused:
    float* YT   = XZ;                             //   y^T [DI][NN]
    float* XST  = w + o; o += (size_t)NN * DI;   // x (conv+silu), transposed [DI][NN]
    float* SZT  = w + o; o += (size_t)NN * DI;   // silu(z), transposed [DI][NN]
    float* DBL  = w + o; o += (size_t)NN * 40;   // scan-time: GP/GH overlays
    float* DBLT = w + o; o += (size_t)NN * 40;   // [40][NN]; 0..7 = dt-proj^T, 8..23 = B^T, 24..39 = C^T
    float* GE   = w + o; o += BB * HH;
    float* DINV = w + o; o += NN;
    int* ip = (int*)(w + o);
    int* CNT    = ip; ip += NN;
    int* ROWPTR = ip; ip += NN + 1;
    int* CURSOR = ip; ip += NN;
    int* COL    = ip; ip += EE;
    int* COUNTS = ip; ip += BB;

    // overlays (regions dead during the scan)
    float* CHP  = F0;                         // NCH*4096 = 1M floats
    float* CHH  = F0 + (size_t)NCH * 4096;    // 1M floats (F0 holds 2M)
    float* INI  = F1;                         // NCH*4096 = 1M floats (F1 holds 2M)
    float* GP   = DBL;                        // NG*4096
    float* GH   = DBL + NG * 4096;

    hipMemsetAsync(CNT, 0, NN * sizeof(int), stream);
    hipMemsetAsync(GE, 0, BB * HH * sizeof(float), stream);
    hipMemsetAsync(COUNTS, 0, BB * sizeof(int), stream);

    // CSR build
    deg_kernel<<<EE / 256, 256, 0, stream>>>(e_dst, CNT);
    prefix_kernel<<<1, 1024, 0, stream>>>(CNT, ROWPTR, CURSOR, DINV);
    scatter_kernel<<<EE / 256, 256, 0, stream>>>(e_src, e_dst, CURSOR, COL);

    // h0 = relu(nf @ W_in + b_in)
    gemm_k<<<dim3(2, NN / 64), 256, 0, stream>>>(nf, W_in, b_in, F0, NN, HH, FF, 1);
    // GCN layer 1
    gemm_k<<<dim3(2, NN / 64), 256, 0, stream>>>(F0, W_g1, nullptr, F1, NN, HH, HH, 0);
    gcn_gather4<<<NN / 8, 256, 0, stream>>>(F1, ROWPTR, COL, DINV, b_g1, F0);
    // GCN layer 2
    gemm_k<<<dim3(2, NN / 64), 256, 0, stream>>>(F0, W_g2, nullptr, F1, NN, HH, HH, 0);
    gcn_gather4<<<NN / 8, 256, 0, stream>>>(F1, ROWPTR, COL, DINV, b_g2, F2);  // F2 = h_gnn

    // xz = h_gnn @ W_inproj (big-tile GEMM)
    gemm_big<<<dim3(4, NN / 128), 256, 0, stream>>>(F2, W_inproj, XZ, NN, 512, HH);
    // conv + silu -> XST; silu(z) -> SZT (both transposed)
    conv_silu_t<<<dim3(NN / 64, 8), 256, 0, stream>>>(XZ, conv_w, conv_b, XST, SZT);
    // dbl = xs @ W_xproj, written directly transposed -> DBLT (fused)
    gemm_at_dblt<<<NN / 64, 256, 0, stream>>>(XST, W_xproj, DBLT);

    // Mamba scan (dt fused into phase1/phase3; phase2b folded into 2c)
    scan_phase1<<<dim3(8, NCH), 256, 0, stream>>>(XST, DBLT, A_log, W_dt, b_dt, CHP, CHH);
    scan_phase2a<<<(4096 * NG) / 256, 256, 0, stream>>>(CHP, CHH, GP, GH);
    scan_phase2c<<<(4096 * NG) / 256, 256, 0, stream>>>(CHP, CHH, GP, GH, INI);
    scan_phase3<<<dim3(8, NCH), 256, 0, stream>>>(XST, DBLT, A_log, W_dt, b_dt, INI, D_p, SZT, YT);

    // h_mamba = y @ W_out; + h_gnn; LayerNorm -> F0 (fused, 32-row tiles)
    gemm_at_ln<<<NN / 32, 256, 0, stream>>>(YT, W_out, F2, gamma, beta, F0);

    // pooling
    pool_kernel<<<NN / 128, HH, 0, stream>>>(F0, batch, GE, COUNTS);

    // heads (ge_norm folded in)
    heads_kernel<<<dim3((OUTW + 127) / 128, BB), 128, 0, stream>>>(
        GE, COUNTS, Wc, bc, Wh, bh, Wt, bt, Wp1, bp1, Wp2, bp2, Wd, bd, Ws, bs, (float*)d_out);
}

// Round 11
// 407.909 us; speedup vs baseline: 2.4102x; 1.0119x over previous
//
#include <hip/hip_runtime.h>
#include <math.h>

#define NN 16384
#define EE 262144
#define FF 32
#define HH 128
#define BB 16
#define DI 256
#define DS 16
#define DC 4
#define DTR 8
#define OUTW 1552
#define NCH 256
#define CHLEN 64    // NCH*CHLEN == NN

// ---------------------------------------------------------------- utilities
__device__ __forceinline__ float siluf(float v) { return v / (1.f + __expf(-v)); }
__device__ __forceinline__ float softplusf(float v) {
    return fmaxf(v, 0.f) + __logf(1.f + __expf(-fabsf(v)));
}

// ---------------------------------------------------------------- zero scratch (replaces 3 memsets)
__global__ void zero_kernel(int* __restrict__ cnt, float* __restrict__ ge,
                            int* __restrict__ counts) {
    int idx = blockIdx.x * blockDim.x + threadIdx.x;
    if (idx < NN) cnt[idx] = 0;
    if (idx < BB * HH) ge[idx] = 0.f;
    if (idx < BB) counts[idx] = 0;
}

// ---------------------------------------------------------------- CSR build
__global__ void deg_kernel(const int* __restrict__ dst, int* __restrict__ cnt) {
    int e = blockIdx.x * blockDim.x + threadIdx.x;
    if (e < EE) atomicAdd(&cnt[dst[e]], 1);
}

__global__ __launch_bounds__(1024) void prefix_kernel(const int* __restrict__ cnt,
                                                      int* __restrict__ rowptr,
                                                      int* __restrict__ cursor,
                                                      float* __restrict__ dinv) {
    __shared__ int part[1024];
    int tid = threadIdx.x;
    int4 c4[4];
#pragma unroll
    for (int j = 0; j < 4; j++) c4[j] = ((const int4*)cnt)[tid * 4 + j];
    int v[16] = {c4[0].x, c4[0].y, c4[0].z, c4[0].w, c4[1].x, c4[1].y, c4[1].z, c4[1].w,
                 c4[2].x, c4[2].y, c4[2].z, c4[2].w, c4[3].x, c4[3].y, c4[3].z, c4[3].w};
    int s = 0;
#pragma unroll
    for (int j = 0; j < 16; j++) s += v[j];
    part[tid] = s;
    __syncthreads();
    for (int off = 1; off < 1024; off <<= 1) {
        int t = (tid >= off) ? part[tid - off] : 0;
        __syncthreads();
        part[tid] += t;
        __syncthreads();
    }
    int running = part[tid] - s;
    int rp[16];
    float dv[16];
#pragma unroll
    for (int j = 0; j < 16; j++) {
        rp[j] = running;
        running += v[j];
        dv[j] = rsqrtf((float)(v[j] + 1));  // +1 self loop
    }
#pragma unroll
    for (int j = 0; j < 4; j++) {
        int4 r4; r4.x = rp[j*4]; r4.y = rp[j*4+1]; r4.z = rp[j*4+2]; r4.w = rp[j*4+3];
        ((int4*)rowptr)[tid * 4 + j] = r4;
        ((int4*)cursor)[tid * 4 + j] = r4;
        float4 d4; d4.x = dv[j*4]; d4.y = dv[j*4+1]; d4.z = dv[j*4+2]; d4.w = dv[j*4+3];
        ((float4*)dinv)[tid * 4 + j] = d4;
    }
    if (tid == 1023) rowptr[NN] = part[1023];
}

__global__ void scatter_kernel(const int* __restrict__ src, const int* __restrict__ dst,
                               int* __restrict__ cursor, int* __restrict__ col) {
    int e = blockIdx.x * blockDim.x + threadIdx.x;
    if (e < EE) {
        int d = dst[e];
        int pos = atomicAdd(&cursor[d], 1);
        col[pos] = src[e];
    }
}

// ---------------------------------------------------------------- GEMM (fp32, 64x64 tile)
__global__ __launch_bounds__(256) void gemm_k(const float* __restrict__ A,
                                              const float* __restrict__ B,
                                              const float* __restrict__ bias,
                                              float* __restrict__ C,
                                              int M, int Nn, int K, int act) {
    __shared__ float As[16][68];
    __shared__ float Bs[16][68];
    int tid = threadIdx.x;
    int m0 = blockIdx.y * 64;
    int n0 = blockIdx.x * 64;
    int ty = tid >> 4, tx = tid & 15;
    float acc[4][4] = {{0.f}};
    for (int k0 = 0; k0 < K; k0 += 16) {
#pragma unroll
        for (int l = 0; l < 4; l++) {
            int idx = tid + l * 256;
            int i = idx >> 4, j = idx & 15;
            As[j][i] = A[(size_t)(m0 + i) * K + k0 + j];
        }
#pragma unroll
        for (int l = 0; l < 4; l++) {
            int idx = tid + l * 256;
            int i = idx >> 6, j = idx & 63;
            int n = n0 + j;
            Bs[i][j] = (n < Nn) ? B[(size_t)(k0 + i) * Nn + n] : 0.f;
        }
        __syncthreads();
#pragma unroll
        for (int kk = 0; kk < 16; kk++) {
            float4 a4 = *(const float4*)&As[kk][ty * 4];
            float4 b4 = *(const float4*)&Bs[kk][tx * 4];
            float av[4] = {a4.x, a4.y, a4.z, a4.w};
            float bv[4] = {b4.x, b4.y, b4.z, b4.w};
#pragma unroll
            for (int r = 0; r < 4; r++)
#pragma unroll
                for (int c = 0; c < 4; c++) acc[r][c] = fmaf(av[r], bv[c], acc[r][c]);
        }
        __syncthreads();
    }
    int nb = n0 + tx * 4;
    if (nb < Nn) {
        float4 bi4 = {0.f, 0.f, 0.f, 0.f};
        if (bias) bi4 = *(const float4*)&bias[nb];
#pragma unroll
        for (int r = 0; r < 4; r++) {
            int m = m0 + ty * 4 + r;
            float4 v;
            v.x = acc[r][0] + bi4.x; v.y = acc[r][1] + bi4.y;
            v.z = acc[r][2] + bi4.z; v.w = acc[r][3] + bi4.w;
            if (act == 1) {
                v.x = fmaxf(v.x, 0.f); v.y = fmaxf(v.y, 0.f);
                v.z = fmaxf(v.z, 0.f); v.w = fmaxf(v.w, 0.f);
            }
            *(float4*)&C[(size_t)m * Nn + nb] = v;
        }
    }
}

// ---------------------------------------------------------------- big-tile GEMM (128x128, 8x8/thread)
__global__ __launch_bounds__(256, 4) void gemm_big(const float* __restrict__ A,
                                                   const float* __restrict__ B,
                                                   float* __restrict__ C,
                                                   int M, int Nn, int K) {
    __shared__ float As[16][132];
    __shared__ float Bs[16][132];
    int tid = threadIdx.x;
    int m0 = blockIdx.y * 128;
    int n0 = blockIdx.x * 128;
    int ty = tid >> 4, tx = tid & 15;
    float acc[8][8] = {{0.f}};
    for (int k0 = 0; k0 < K; k0 += 16) {
        {   // A: 128 m x 16 k -> As[k][m]
            int m = tid >> 1;
            int kc = (tid & 1) * 8;
            const float* ap = &A[(size_t)(m0 + m) * K + k0 + kc];
            float4 a0 = *(const float4*)ap;
            float4 a1 = *(const float4*)(ap + 4);
            As[kc + 0][m] = a0.x; As[kc + 1][m] = a0.y;
            As[kc + 2][m] = a0.z; As[kc + 3][m] = a0.w;
            As[kc + 4][m] = a1.x; As[kc + 5][m] = a1.y;
            As[kc + 6][m] = a1.z; As[kc + 7][m] = a1.w;
        }
        {   // B: 16 k x 128 n
            int krow = tid >> 4;
            int c8 = (tid & 15) * 8;
            const float* bp = &B[(size_t)(k0 + krow) * Nn + n0 + c8];
            *(float4*)&Bs[krow][c8] = *(const float4*)bp;
            *(float4*)&Bs[krow][c8 + 4] = *(const float4*)(bp + 4);
        }
        __syncthreads();
#pragma unroll
        for (int kk = 0; kk < 16; kk++) {
            float4 a0 = *(const float4*)&As[kk][ty * 4];
            float4 a1 = *(const float4*)&As[kk][64 + ty * 4];
            float4 b0 = *(const float4*)&Bs[kk][tx * 4];
            float4 b1 = *(const float4*)&Bs[kk][64 + tx * 4];
            float av[8] = {a0.x, a0.y, a0.z, a0.w, a1.x, a1.y, a1.z, a1.w};
            float bv[8] = {b0.x, b0.y, b0.z, b0.w, b1.x, b1.y, b1.z, b1.w};
#pragma unroll
            for (int r = 0; r < 8; r++)
#pragma unroll
                for (int c = 0; c < 8; c++) acc[r][c] = fmaf(av[r], bv[c], acc[r][c]);
        }
        __syncthreads();
    }
#pragma unroll
    for (int r = 0; r < 8; r++) {
        int m = m0 + ((r < 4) ? (ty * 4 + r) : (64 + ty * 4 + r - 4));
        float4 v0, v1;
        v0.x = acc[r][0]; v0.y = acc[r][1]; v0.z = acc[r][2]; v0.w = acc[r][3];
        v1.x = acc[r][4]; v1.y = acc[r][5]; v1.z = acc[r][6]; v1.w = acc[r][7];
        *(float4*)&C[(size_t)m * Nn + n0 + tx * 4] = v0;
        *(float4*)&C[(size_t)m * Nn + n0 + 64 + tx * 4] = v1;
    }
}

// ---------------------------------------------------------------- xproj GEMM (A^T) + transposed output
__global__ __launch_bounds__(256) void gemm_at_dblt(const float* __restrict__ AT,
                                                    const float* __restrict__ B,
                                                    float* __restrict__ dblt) {
    __shared__ float As[16][68];
    __shared__ float Bs[16][68];
    __shared__ float Ct[64][41];
    int tid = threadIdx.x;
    int m0 = blockIdx.x * 64;
    int ty = tid >> 4, tx = tid & 15;
    float acc[4][4] = {{0.f}};
    for (int k0 = 0; k0 < DI; k0 += 16) {
#pragma unroll
        for (int l = 0; l < 4; l++) {
            int idx = tid + l * 256;
            int kk = idx >> 6, i = idx & 63;
            As[kk][i] = AT[(size_t)(k0 + kk) * NN + m0 + i];
        }
#pragma unroll
        for (int l = 0; l < 4; l++) {
            int idx = tid + l * 256;
            int i = idx >> 6, j = idx & 63;
            Bs[i][j] = (j < 40) ? B[(size_t)(k0 + i) * 40 + j] : 0.f;
        }
        __syncthreads();
#pragma unroll
        for (int kk = 0; kk < 16; kk++) {
            float4 a4 = *(const float4*)&As[kk][ty * 4];
            float4 b4 = *(const float4*)&Bs[kk][tx * 4];
            float av[4] = {a4.x, a4.y, a4.z, a4.w};
            float bv[4] = {b4.x, b4.y, b4.z, b4.w};
#pragma unroll
            for (int r = 0; r < 4; r++)
#pragma unroll
                for (int c = 0; c < 4; c++) acc[r][c] = fmaf(av[r], bv[c], acc[r][c]);
        }
        __syncthreads();
    }
    if (tx * 4 < 40) {
#pragma unroll
        for (int r = 0; r < 4; r++) {
            int m = ty * 4 + r;
            Ct[m][tx * 4 + 0] = acc[r][0];
            Ct[m][tx * 4 + 1] = acc[r][1];
            Ct[m][tx * 4 + 2] = acc[r][2];
            Ct[m][tx * 4 + 3] = acc[r][3];
        }
    }
    __syncthreads();
#pragma unroll
    for (int l = 0; l < 10; l++) {
        int idx = tid + l * 256;
        int n = idx >> 6, m = idx & 63;
        dblt[(size_t)n * NN + m0 + m] = Ct[m][n];
    }
}

// ---------------------------------------------------------------- fused W_out GEMM + add + LayerNorm
__global__ __launch_bounds__(256) void gemm_at_ln(const float* __restrict__ AT,
                                                  const float* __restrict__ B,
                                                  const float* __restrict__ hg,
                                                  const float* __restrict__ gamma,
                                                  const float* __restrict__ beta,
                                                  float* __restrict__ out) {
    __shared__ float As[16][36];
    __shared__ float Bs[16][132];
    int tid = threadIdx.x;
    int m0 = blockIdx.x * 32;
    int ty = tid >> 4, tx = tid & 15;
    float acc[2][8] = {{0.f}};
    for (int k0 = 0; k0 < 256; k0 += 16) {
        {
            int idx = tid * 2;
            int kk = idx >> 5, i = idx & 31;
            As[kk][i] = AT[(size_t)(k0 + kk) * NN + m0 + i];
            As[kk][i + 1] = AT[(size_t)(k0 + kk) * NN + m0 + i + 1];
        }
        {
            int krow = tid >> 4;
            int c8 = (tid & 15) * 8;
            const float* bp = &B[(size_t)(k0 + krow) * HH + c8];
            *(float4*)&Bs[krow][c8] = *(const float4*)bp;
            *(float4*)&Bs[krow][c8 + 4] = *(const float4*)(bp + 4);
        }
        __syncthreads();
#pragma unroll
        for (int kk = 0; kk < 16; kk++) {
            float a0 = As[kk][ty * 2];
            float a1 = As[kk][ty * 2 + 1];
            float4 b0 = *(const float4*)&Bs[kk][tx * 4];
            float4 b1 = *(const float4*)&Bs[kk][64 + tx * 4];
            float bv[8] = {b0.x, b0.y, b0.z, b0.w, b1.x, b1.y, b1.z, b1.w};
#pragma unroll
            for (int c = 0; c < 8; c++) {
                acc[0][c] = fmaf(a0, bv[c], acc[0][c]);
                acc[1][c] = fmaf(a1, bv[c], acc[1][c]);
            }
        }
        __syncthreads();
    }
    float4 g0 = *(const float4*)&gamma[tx * 4];
    float4 g1 = *(const float4*)&gamma[64 + tx * 4];
    float4 be0 = *(const float4*)&beta[tx * 4];
    float4 be1 = *(const float4*)&beta[64 + tx * 4];
    float gv[8] = {g0.x, g0.y, g0.z, g0.w, g1.x, g1.y, g1.z, g1.w};
    float bv[8] = {be0.x, be0.y, be0.z, be0.w, be1.x, be1.y, be1.z, be1.w};
#pragma unroll
    for (int r = 0; r < 2; r++) {
        int m = m0 + ty * 2 + r;
        float4 h0 = *(const float4*)&hg[(size_t)m * HH + tx * 4];
        float4 h1 = *(const float4*)&hg[(size_t)m * HH + 64 + tx * 4];
        float v[8] = {acc[r][0] + h0.x, acc[r][1] + h0.y, acc[r][2] + h0.z, acc[r][3] + h0.w,
                      acc[r][4] + h1.x, acc[r][5] + h1.y, acc[r][6] + h1.z, acc[r][7] + h1.w};
        float sum = 0.f;
#pragma unroll
        for (int c = 0; c < 8; c++) sum += v[c];
        sum += __shfl_xor(sum, 1); sum += __shfl_xor(sum, 2);
        sum += __shfl_xor(sum, 4); sum += __shfl_xor(sum, 8);
        float mu = sum * (1.f / 128.f);
        float vs = 0.f;
#pragma unroll
        for (int c = 0; c < 8; c++) { float dd = v[c] - mu; vs += dd * dd; }
        vs += __shfl_xor(vs, 1); vs += __shfl_xor(vs, 2);
        vs += __shfl_xor(vs, 4); vs += __shfl_xor(vs, 8);
        float inv = rsqrtf(vs * (1.f / 128.f) + 1e-5f);
        float4 o0, o1;
        o0.x = (v[0] - mu) * inv * gv[0] + bv[0];
        o0.y = (v[1] - mu) * inv * gv[1] + bv[1];
        o0.z = (v[2] - mu) * inv * gv[2] + bv[2];
        o0.w = (v[3] - mu) * inv * gv[3] + bv[3];
        o1.x = (v[4] - mu) * inv * gv[4] + bv[4];
        o1.y = (v[5] - mu) * inv * gv[5] + bv[5];
        o1.z = (v[6] - mu) * inv * gv[6] + bv[6];
        o1.w = (v[7] - mu) * inv * gv[7] + bv[7];
        *(float4*)&out[(size_t)m * HH + tx * 4] = o0;
        *(float4*)&out[(size_t)m * HH + 64 + tx * 4] = o1;
    }
}

// ---------------------------------------------------------------- GCN gather, float4, 4-edge unroll
__global__ __launch_bounds__(256) void gcn_gather4(const float* __restrict__ xw,
                                                   const int* __restrict__ rowptr,
                                                   const int* __restrict__ col,
                                                   const float* __restrict__ dinv,
                                                   const float* __restrict__ b,
                                                   float* __restrict__ out) {
    int tid = threadIdx.x;
    int sub = tid & 31;
    int n = blockIdx.x * 8 + (tid >> 5);
    float dn = dinv[n];
    const float4* xw4 = (const float4*)xw;
    float4 a = xw4[(size_t)n * 32 + sub];
    float ws = dn * dn;
    float4 acc;
    acc.x = a.x * ws; acc.y = a.y * ws; acc.z = a.z * ws; acc.w = a.w * ws;
    int beg = rowptr[n], end = rowptr[n + 1];
    int e = beg;
    for (; e + 4 <= end; e += 4) {
        int s0 = col[e], s1 = col[e + 1], s2 = col[e + 2], s3 = col[e + 3];
        float w0 = dinv[s0] * dn, w1 = dinv[s1] * dn;
        float w2 = dinv[s2] * dn, w3 = dinv[s3] * dn;
        float4 v0 = xw4[(size_t)s0 * 32 + sub];
        float4 v1 = xw4[(size_t)s1 * 32 + sub];
        float4 v2 = xw4[(size_t)s2 * 32 + sub];
        float4 v3 = xw4[(size_t)s3 * 32 + sub];
        acc.x = fmaf(v0.x, w0, acc.x); acc.y = fmaf(v0.y, w0, acc.y);
        acc.z = fmaf(v0.z, w0, acc.z); acc.w = fmaf(v0.w, w0, acc.w);
        acc.x = fmaf(v1.x, w1, acc.x); acc.y = fmaf(v1.y, w1, acc.y);
        acc.z = fmaf(v1.z, w1, acc.z); acc.w = fmaf(v1.w, w1, acc.w);
        acc.x = fmaf(v2.x, w2, acc.x); acc.y = fmaf(v2.y, w2, acc.y);
        acc.z = fmaf(v2.z, w2, acc.z); acc.w = fmaf(v2.w, w2, acc.w);
        acc.x = fmaf(v3.x, w3, acc.x); acc.y = fmaf(v3.y, w3, acc.y);
        acc.z = fmaf(v3.z, w3, acc.z); acc.w = fmaf(v3.w, w3, acc.w);
    }
    for (; e < end; e++) {
        int s0 = col[e];
        float w0 = dinv[s0] * dn;
        float4 v0 = xw4[(size_t)s0 * 32 + sub];
        acc.x = fmaf(v0.x, w0, acc.x); acc.y = fmaf(v0.y, w0, acc.y);
        acc.z = fmaf(v0.z, w0, acc.z); acc.w = fmaf(v0.w, w0, acc.w);
    }
    float4 b4 = ((const float4*)b)[sub];
    acc.x = fmaxf(acc.x + b4.x, 0.f);
    acc.y = fmaxf(acc.y + b4.y, 0.f);
    acc.z = fmaxf(acc.z + b4.z, 0.f);
    acc.w = fmaxf(acc.w + b4.w, 0.f);
    ((float4*)out)[(size_t)n * 32 + sub] = acc;
}

// ---------------------------------------------------------------- conv + silu, transposed outputs
__global__ __launch_bounds__(256) void conv_silu_t(const float* __restrict__ xz,
                                                   const float* __restrict__ cw,
                                                   const float* __restrict__ cb,
                                                   float* __restrict__ xst,
                                                   float* __restrict__ szt) {
    __shared__ float tile[67][65];
    int tid = threadIdx.x;
    int t0 = blockIdx.x * 64;
    int c0 = blockIdx.y * 64;
#pragma unroll
    for (int l = 0; l < 17; l++) {
        int idx = tid + l * 256;
        if (idx < 67 * 64) {
            int r = idx >> 6, c = idx & 63;
            int gt = t0 - 3 + r;
            tile[r][c] = (gt >= 0) ? xz[(size_t)gt * 512 + c0 + c] : 0.f;
        }
    }
    __syncthreads();
    int tl = tid & 63;
    int d0 = tid >> 6;
    if (c0 < 256) {
#pragma unroll
        for (int l = 0; l < 16; l++) {
            int dl = d0 + l * 4;
            int dg = c0 + dl;
            float acc = cb[dg];
#pragma unroll
            for (int k = 0; k < DC; k++)
                acc = fmaf(tile[tl + k][dl], cw[dg * DC + k], acc);
            xst[dg * NN + t0 + tl] = siluf(acc);
        }
    } else {
#pragma unroll
        for (int l = 0; l < 16; l++) {
            int dl = d0 + l * 4;
            int dg = c0 - 256 + dl;
            szt[dg * NN + t0 + tl] = siluf(tile[tl + 3][dl]);
        }
    }
}

// ---------------------------------------------------------------- Mamba scan (LDS-staged)
__global__ __launch_bounds__(256, 6) void scan_phase1(const float* __restrict__ xst,
                                                      const float* __restrict__ dblt,
                                                      const float* __restrict__ A_log,
                                                      const float* __restrict__ W_dt,
                                                      const float* __restrict__ b_dt,
                                                      float* __restrict__ chkP,
                                                      float* __restrict__ chkH) {
    __shared__ float Td[32][68];
    __shared__ float Tx[32][68];
    __shared__ float Bs[16][68];
    __shared__ float D8[8][68];
    int tid = threadIdx.x;
    int wave = tid >> 6, lane = tid & 63;
    int sg = lane & 7, dl = lane >> 3;
    int dblk = blockIdx.x, chunk = blockIdx.y;
    int t0 = chunk * CHLEN;
    int dloc = wave * 8 + dl;
    int d = dblk * 32 + dloc;
    int s0 = 2 * sg;
#pragma unroll
    for (int p = 0; p < 2; p++) {
        int linear = tid + p * 256;
        int row = linear >> 4, c4 = (linear & 15) * 4;
        *(float4*)&Tx[row][c4] = *(const float4*)&xst[(size_t)(dblk * 32 + row) * NN + t0 + c4];
    }
    if (tid < 128) {
        int r = tid >> 4, c4 = (tid & 15) * 4;
        *(float4*)&D8[r][c4] = *(const float4*)&dblt[(size_t)r * NN + t0 + c4];
    }
    {
        int s = tid >> 4, c4 = (tid & 15) * 4;
        *(float4*)&Bs[s][c4] = *(const float4*)&dblt[(size_t)(8 + s) * NN + t0 + c4];
    }
    float A0 = -expf(A_log[d * DS + s0]);
    float A1 = -expf(A_log[d * DS + s0 + 1]);
    __syncthreads();
    {   // dt tile: 32 d x 64 t
        int row = tid >> 3;
        int tb = (tid & 7) * 8;
        int dd = dblk * 32 + row;
        float bd = b_dt[dd];
        float wv[8];
#pragma unroll
        for (int j = 0; j < 8; j++) wv[j] = W_dt[j * DI + dd];
#pragma unroll
        for (int j = 0; j < 8; j++) {
            int t = tb + j;
            float acc = bd;
#pragma unroll
            for (int k = 0; k < 8; k++) acc = fmaf(D8[k][t], wv[k], acc);
            Td[row][t] = softplusf(acc);
        }
    }
    __syncthreads();
    float h0 = 0.f, h1 = 0.f, P0 = 1.f, P1 = 1.f;
    for (int i = 0; i < CHLEN; i += 4) {
        float4 d4 = *(const float4*)&Td[dloc][i];
        float4 x4 = *(const float4*)&Tx[dloc][i];
        float4 b04 = *(const float4*)&Bs[s0][i];
        float4 b14 = *(const float4*)&Bs[s0 + 1][i];
#define P1S(U) { float dtv = d4.U; float a0 = __expf(dtv * A0); float a1 = __expf(dtv * A1); \
        float dx = dtv * x4.U; h0 = fmaf(a0, h0, dx * b04.U); h1 = fmaf(a1, h1, dx * b14.U); \
        P0 *= a0; P1 *= a1; }
        P1S(x) P1S(y) P1S(z) P1S(w)
#undef P1S
    }
    int idx = chunk * 4096 + d * DS + s0;
    float2 vP; vP.x = P0; vP.y = P1;
    float2 vH; vH.x = h0; vH.y = h1;
    *(float2*)(chkP + idx) = vP;
    *(float2*)(chkH + idx) = vH;
}

// single phase2: serial over all chunks with 8-deep batched prefetch (R2 structure)
__global__ void scan_phase2(const float* __restrict__ chkP, const float* __restrict__ chkH,
                            float* __restrict__ init) {
    int idx = blockIdx.x * blockDim.x + threadIdx.x;  // 4096 total
    float h = 0.f;
    for (int c0 = 0; c0 < NCH; c0 += 8) {
        float p[8], q[8];
#pragma unroll
        for (int j = 0; j < 8; j++) {
            p[j] = chkP[(c0 + j) * 4096 + idx];
            q[j] = chkH[(c0 + j) * 4096 + idx];
        }
#pragma unroll
        for (int j = 0; j < 8; j++) {
            init[(c0 + j) * 4096 + idx] = h;
            h = fmaf(p[j], h, q[j]);
        }
    }
}

// phase3: D8 overlaid into Cs buffer (D8 dead after dt compute) -> LDS 26.1 KB, 6 blocks/CU
__global__ __launch_bounds__(256, 6) void scan_phase3(const float* __restrict__ xst,
                                                      const float* __restrict__ dblt,
                                                      const float* __restrict__ A_log,
                                                      const float* __restrict__ W_dt,
                                                      const float* __restrict__ b_dt,
                                                      const float* __restrict__ init,
                                                      const float* __restrict__ D_p,
                                                      const float* __restrict__ szt,
                                                      float* __restrict__ yt) {
    __shared__ float Td[32][68];
    __shared__ float Tx[32][68];
    __shared__ float Bs[16][68];
    __shared__ float CsD8[16][68];   // rows 0..7 = D8 during dt compute; then C rows 0..15
    int tid = threadIdx.x;
    int wave = tid >> 6, lane = tid & 63;
    int sg = lane & 7, dl = lane >> 3;
    int dblk = blockIdx.x, chunk = blockIdx.y;
    int t0 = chunk * CHLEN;
    int dloc = wave * 8 + dl;
    int d = dblk * 32 + dloc;
    int s0 = 2 * sg;
#pragma unroll
    for (int p = 0; p < 2; p++) {
        int linear = tid + p * 256;
        int row = linear >> 4, c4 = (linear & 15) * 4;
        *(float4*)&Tx[row][c4] = *(const float4*)&xst[(size_t)(dblk * 32 + row) * NN + t0 + c4];
    }
    if (tid < 128) {
        int r = tid >> 4, c4 = (tid & 15) * 4;
        *(float4*)&CsD8[r][c4] = *(const float4*)&dblt[(size_t)r * NN + t0 + c4];  // D8
    }
    {
        int s = tid >> 4, c4 = (tid & 15) * 4;
        *(float4*)&Bs[s][c4] = *(const float4*)&dblt[(size_t)(8 + s) * NN + t0 + c4];
    }
    float A0 = -expf(A_log[d * DS + s0]);
    float A1 = -expf(A_log[d * DS + s0 + 1]);
    float Dd = D_p[d];
    float2 ini = *(const float2*)(init + chunk * 4096 + d * DS + s0);
    float h0 = ini.x, h1 = ini.y;
    __syncthreads();
    {   // dt tile from D8 (CsD8 rows 0..7)
        int row = tid >> 3;
        int tb = (tid & 7) * 8;
        int dd = dblk * 32 + row;
        float bd = b_dt[dd];
        float wv[8];
#pragma unroll
        for (int j = 0; j < 8; j++) wv[j] = W_dt[j * DI + dd];
#pragma unroll
        for (int j = 0; j < 8; j++) {
            int t = tb + j;
            float acc = bd;
#pragma unroll
            for (int k = 0; k < 8; k++) acc = fmaf(CsD8[k][t], wv[k], acc);
            Td[row][t] = softplusf(acc);
        }
    }
    __syncthreads();
    {   // now load C rows over the dead D8
        int s = tid >> 4, c4 = (tid & 15) * 4;
        *(float4*)&CsD8[s][c4] = *(const float4*)&dblt[(size_t)(24 + s) * NN + t0 + c4];
    }
    __syncthreads();
    for (int i = 0; i < CHLEN; i += 4) {
        float4 d4 = *(const float4*)&Td[dloc][i];
        float4 x4 = *(const float4*)&Tx[dloc][i];
        float4 b04 = *(const float4*)&Bs[s0][i];
        float4 b14 = *(const float4*)&Bs[s0 + 1][i];
        float4 c04 = *(const float4*)&CsD8[s0][i];
        float4 c14 = *(const float4*)&CsD8[s0 + 1][i];
        float4 yv;
#define P3S(U) { float dtv = d4.U; float a0 = __expf(dtv * A0); float a1 = __expf(dtv * A1); \
        float dx = dtv * x4.U; h0 = fmaf(a0, h0, dx * b04.U); h1 = fmaf(a1, h1, dx * b14.U); \
        float c = fmaf(h1, c14.U, h0 * c04.U); \
        c += __shfl_xor(c, 1); c += __shfl_xor(c, 2); c += __shfl_xor(c, 4); \
        yv.U = c + Dd * x4.U; }
        P3S(x) P3S(y) P3S(z) P3S(w)
#undef P3S
        if (sg == 0) *(float4*)&Td[dloc][i] = yv;  // in-place: this wave's row only
    }
#pragma unroll
    for (int r = 0; r < 8; r++) {
        int row = wave * 8 + r;
        float sz = szt[(size_t)(dblk * 32 + row) * NN + t0 + lane];
        yt[(size_t)(dblk * 32 + row) * NN + t0 + lane] = Td[row][lane] * sz;
    }
}

// ---------------------------------------------------------------- pooling (batch sorted), 64 rows/block
__global__ void pool_kernel(const float* __restrict__ hf, const int* __restrict__ batch,
                            float* __restrict__ ge, int* __restrict__ counts) {
    int f = threadIdx.x;  // 128
    int r0 = blockIdx.x * 64;
    int gcur = batch[r0];
    float acc = 0.f;
    int cnt = 0;
    for (int i = 0; i < 64; i += 4) {
        int r = r0 + i;
        int g0 = batch[r], g3 = batch[r + 3];
        float v0 = hf[(size_t)r * HH + f];
        float v1 = hf[(size_t)(r + 1) * HH + f];
        float v2 = hf[(size_t)(r + 2) * HH + f];
        float v3 = hf[(size_t)(r + 3) * HH + f];
        if (g0 == gcur && g3 == gcur) {
            acc += (v0 + v1) + (v2 + v3);
            cnt += 4;
        } else {
            int gs[4] = {g0, batch[r + 1], batch[r + 2], g3};
            float vs[4] = {v0, v1, v2, v3};
#pragma unroll
            for (int k = 0; k < 4; k++) {
                if (gs[k] != gcur) {
                    atomicAdd(&ge[gcur * HH + f], acc);
                    if (f == 0) atomicAdd(&counts[gcur], cnt);
                    acc = 0.f; cnt = 0; gcur = gs[k];
                }
                acc += vs[k];
                cnt++;
            }
        }
    }
    atomicAdd(&ge[gcur * HH + f], acc);
    if (f == 0) atomicAdd(&counts[gcur], cnt);
}

// ---------------------------------------------------------------- output heads (ge_norm folded in)
__global__ void heads_kernel(const float* __restrict__ ge, const int* __restrict__ counts,
                             const float* Wc, const float* bc, const float* Wh, const float* bh,
                             const float* Wt, const float* bt, const float* Wp1, const float* bp1,
                             const float* Wp2, const float* bp2, const float* Wd, const float* bd,
                             const float* Ws, const float* bs, float* __restrict__ out) {
    int col = blockIdx.x * blockDim.x + threadIdx.x;
    int b = blockIdx.y;
    if (col >= OUTW) return;
    const float* W; const float* bi; int lc, w;
    if (col < 1)         { W = Wc;  bi = bc;  lc = col;        w = 1; }
    else if (col < 5)    { W = Wh;  bi = bh;  lc = col - 1;    w = 4; }
    else if (col < 8)    { W = Wt;  bi = bt;  lc = col - 5;    w = 3; }
    else if (col < 520)  { W = Wp1; bi = bp1; lc = col - 8;    w = 512; }
    else if (col < 1032) { W = Wp2; bi = bp2; lc = col - 520;  w = 512; }
    else if (col < 1544) { W = Wd;  bi = bd;  lc = col - 1032; w = 512; }
    else                 { W = Ws;  bi = bs;  lc = col - 1544; w = 8; }
    float scale = 1.f / fmaxf((float)counts[b], 1.f);
    float dot = 0.f;
#pragma unroll 8
    for (int f = 0; f < HH; f++) dot = fmaf(ge[b * HH + f], W[f * w + lc], dot);
    out[(size_t)b * OUTW + col] = bi[lc] + scale * dot;
}

// ---------------------------------------------------------------- launch
extern "C" void kernel_launch(void* const* d_in, const int* in_sizes, int n_in,
                              void* d_out, int out_size, void* d_ws, size_t ws_size,
                              hipStream_t stream) {
    const float* nf      = (const float*)d_in[0];
    const int*   ei      = (const int*)d_in[1];
    const int*   batch   = (const int*)d_in[2];
    const float* W_in    = (const float*)d_in[3];
    const float* b_in    = (const float*)d_in[4];
    const float* W_g1    = (const float*)d_in[5];
    const float* b_g1    = (const float*)d_in[6];
    const float* W_g2    = (const float*)d_in[7];
    const float* b_g2    = (const float*)d_in[8];
    const float* W_inproj= (const float*)d_in[9];
    const float* conv_w  = (const float*)d_in[10];
    const float* conv_b  = (const float*)d_in[11];
    const float* W_xproj = (const float*)d_in[12];
    const float* W_dt    = (const float*)d_in[13];
    const float* b_dt    = (const float*)d_in[14];
    const float* A_log   = (const float*)d_in[15];
    const float* D_p     = (const float*)d_in[16];
    const float* W_out   = (const float*)d_in[17];
    const float* gamma   = (const float*)d_in[18];
    const float* beta    = (const float*)d_in[19];
    const float* Wc = (const float*)d_in[20]; const float* bc = (const float*)d_in[21];
    const float* Wh = (const float*)d_in[22]; const float* bh = (const float*)d_in[23];
    const float* Wt = (const float*)d_in[24]; const float* bt = (const float*)d_in[25];
    const float* Wp1= (const float*)d_in[26]; const float* bp1= (const float*)d_in[27];
    const float* Wp2= (const float*)d_in[28]; const float* bp2= (const float*)d_in[29];
    const float* Wd = (const float*)d_in[30]; const float* bd = (const float*)d_in[31];
    const float* Ws = (const float*)d_in[32]; const float* bs = (const float*)d_in[33];

    const int* e_src = ei;
    const int* e_dst = ei + EE;

    // workspace layout (floats, then ints)
    float* w = (float*)d_ws;
    size_t o = 0;
    float* F0   = w + o; o += (size_t)NN * HH;   // dead during scan -> CHP/CHH
    float* F1   = w + o; o += (size_t)NN * HH;   // dead during scan -> INI
    float* F2   = w + o; o += (size_t)NN * HH;
    float* XZ   = w + o; o += (size_t)NN * 512;  // dead after conv_silu_t; reused:
    float* YT   = XZ;                             //   y^T [DI][NN]
    float* XST  = w + o; o += (size_t)NN * DI;   // x (conv+silu), transposed [DI][NN]
    float* SZT  = w + o; o += (size_t)NN * DI;   // silu(z), transposed [DI][NN]
    float* DBLT = w + o; o += (size_t)NN * 40;   // [40][NN]; 0..7 = dt-proj^T, 8..23 = B^T, 24..39 = C^T
    float* GE   = w + o; o += BB * HH;
    float* DINV = w + o; o += NN;
    int* ip = (int*)(w + o);
    int* CNT    = ip; ip += NN;
    int* ROWPTR = ip; ip += NN + 1;
    int* CURSOR = ip; ip += NN;
    int* COL    = ip; ip += EE;
    int* COUNTS = ip; ip += BB;

    // overlays (regions dead during the scan)
    float* CHP  = F0;                         // NCH*4096 = 1M floats
    float* CHH  = F0 + (size_t)NCH * 4096;    // 1M floats (F0 holds 2M)
    float* INI  = F1;                         // NCH*4096 = 1M floats (F1 holds 2M)

    // zero scratch (single kernel instead of 3 memsets)
    zero_kernel<<<(NN + 255) / 256, 256, 0, stream>>>(CNT, GE, COUNTS);

    // CSR build
    deg_kernel<<<EE / 256, 256, 0, stream>>>(e_dst, CNT);
    prefix_kernel<<<1, 1024, 0, stream>>>(CNT, ROWPTR, CURSOR, DINV);
    scatter_kernel<<<EE / 256, 256, 0, stream>>>(e_src, e_dst, CURSOR, COL);

    // h0 = relu(nf @ W_in + b_in)
    gemm_k<<<dim3(2, NN / 64), 256, 0, stream>>>(nf, W_in, b_in, F0, NN, HH, FF, 1);
    // GCN layer 1
    gemm_k<<<dim3(2, NN / 64), 256, 0, stream>>>(F0, W_g1, nullptr, F1, NN, HH, HH, 0);
    gcn_gather4<<<NN / 8, 256, 0, stream>>>(F1, ROWPTR, COL, DINV, b_g1, F0);
    // GCN layer 2
    gemm_k<<<dim3(2, NN / 64), 256, 0, stream>>>(F0, W_g2, nullptr, F1, NN, HH, HH, 0);
    gcn_gather4<<<NN / 8, 256, 0, stream>>>(F1, ROWPTR, COL, DINV, b_g2, F2);  // F2 = h_gnn

    // xz = h_gnn @ W_inproj (big-tile GEMM)
    gemm_big<<<dim3(4, NN / 128), 256, 0, stream>>>(F2, W_inproj, XZ, NN, 512, HH);
    // conv + silu -> XST; silu(z) -> SZT (both transposed)
    conv_silu_t<<<dim3(NN / 64, 8), 256, 0, stream>>>(XZ, conv_w, conv_b, XST, SZT);
    // dbl = xs @ W_xproj, written directly transposed -> DBLT (fused)
    gemm_at_dblt<<<NN / 64, 256, 0, stream>>>(XST, W_xproj, DBLT);

    // Mamba scan (dt fused into phase1/phase3; single phase2)
    scan_phase1<<<dim3(8, NCH), 256, 0, stream>>>(XST, DBLT, A_log, W_dt, b_dt, CHP, CHH);
    scan_phase2<<<16, 256, 0, stream>>>(CHP, CHH, INI);
    scan_phase3<<<dim3(8, NCH), 256, 0, stream>>>(XST, DBLT, A_log, W_dt, b_dt, INI, D_p, SZT, YT);

    // h_mamba = y @ W_out; + h_gnn; LayerNorm -> F0 (fused, 32-row tiles)
    gemm_at_ln<<<NN / 32, 256, 0, stream>>>(YT, W_out, F2, gamma, beta, F0);

    // pooling
    pool_kernel<<<NN / 64, HH, 0, stream>>>(F0, batch, GE, COUNTS);

    // heads (ge_norm folded in)
    heads_kernel<<<dim3((OUTW + 127) / 128, BB), 128, 0, stream>>>(
        GE, COUNTS, Wc, bc, Wh, bh, Wt, bt, Wp1, bp1, Wp2, bp2, Wd, bd, Ws, bs, (float*)d_out);
}

// Round 12
// 404.383 us; speedup vs baseline: 2.4313x; 1.0087x over previous
//
#include <hip/hip_runtime.h>
#include <math.h>

#define NN 16384
#define EE 262144
#define FF 32
#define HH 128
#define BB 16
#define DI 256
#define DS 16
#define DC 4
#define DTR 8
#define OUTW 1552
#define NCH 256
#define CHLEN 64    // NCH*CHLEN == NN

// ---------------------------------------------------------------- utilities
__device__ __forceinline__ float siluf(float v) { return v / (1.f + __expf(-v)); }
__device__ __forceinline__ float softplusf(float v) {
    return fmaxf(v, 0.f) + __logf(1.f + __expf(-fabsf(v)));
}

// ---------------------------------------------------------------- zero scratch (replaces 3 memsets)
__global__ void zero_kernel(int* __restrict__ cnt, float* __restrict__ ge,
                            int* __restrict__ counts) {
    int idx = blockIdx.x * blockDim.x + threadIdx.x;
    if (idx < NN) cnt[idx] = 0;
    if (idx < BB * HH) ge[idx] = 0.f;
    if (idx < BB) counts[idx] = 0;
}

// ---------------------------------------------------------------- CSR build
__global__ void deg_kernel(const int* __restrict__ dst, int* __restrict__ cnt) {
    int e = blockIdx.x * blockDim.x + threadIdx.x;
    if (e < EE) atomicAdd(&cnt[dst[e]], 1);
}

__global__ __launch_bounds__(1024) void prefix_kernel(const int* __restrict__ cnt,
                                                      int* __restrict__ rowptr,
                                                      int* __restrict__ cursor,
                                                      float* __restrict__ dinv) {
    __shared__ int part[1024];
    int tid = threadIdx.x;
    int4 c4[4];
#pragma unroll
    for (int j = 0; j < 4; j++) c4[j] = ((const int4*)cnt)[tid * 4 + j];
    int v[16] = {c4[0].x, c4[0].y, c4[0].z, c4[0].w, c4[1].x, c4[1].y, c4[1].z, c4[1].w,
                 c4[2].x, c4[2].y, c4[2].z, c4[2].w, c4[3].x, c4[3].y, c4[3].z, c4[3].w};
    int s = 0;
#pragma unroll
    for (int j = 0; j < 16; j++) s += v[j];
    part[tid] = s;
    __syncthreads();
    for (int off = 1; off < 1024; off <<= 1) {
        int t = (tid >= off) ? part[tid - off] : 0;
        __syncthreads();
        part[tid] += t;
        __syncthreads();
    }
    int running = part[tid] - s;
    int rp[16];
    float dv[16];
#pragma unroll
    for (int j = 0; j < 16; j++) {
        rp[j] = running;
        running += v[j];
        dv[j] = rsqrtf((float)(v[j] + 1));  // +1 self loop
    }
#pragma unroll
    for (int j = 0; j < 4; j++) {
        int4 r4; r4.x = rp[j*4]; r4.y = rp[j*4+1]; r4.z = rp[j*4+2]; r4.w = rp[j*4+3];
        ((int4*)rowptr)[tid * 4 + j] = r4;
        ((int4*)cursor)[tid * 4 + j] = r4;
        float4 d4; d4.x = dv[j*4]; d4.y = dv[j*4+1]; d4.z = dv[j*4+2]; d4.w = dv[j*4+3];
        ((float4*)dinv)[tid * 4 + j] = d4;
    }
    if (tid == 1023) rowptr[NN] = part[1023];
}

__global__ void scatter_kernel(const int* __restrict__ src, const int* __restrict__ dst,
                               int* __restrict__ cursor, int* __restrict__ col) {
    int e = blockIdx.x * blockDim.x + threadIdx.x;
    if (e < EE) {
        int d = dst[e];
        int pos = atomicAdd(&cursor[d], 1);
        col[pos] = src[e];
    }
}

// ---------------------------------------------------------------- GEMM (fp32, 64x64 tile)
__global__ __launch_bounds__(256) void gemm_k(const float* __restrict__ A,
                                              const float* __restrict__ B,
                                              const float* __restrict__ bias,
                                              float* __restrict__ C,
                                              int M, int Nn, int K, int act) {
    __shared__ float As[16][68];
    __shared__ float Bs[16][68];
    int tid = threadIdx.x;
    int m0 = blockIdx.y * 64;
    int n0 = blockIdx.x * 64;
    int ty = tid >> 4, tx = tid & 15;
    float acc[4][4] = {{0.f}};
    for (int k0 = 0; k0 < K; k0 += 16) {
#pragma unroll
        for (int l = 0; l < 4; l++) {
            int idx = tid + l * 256;
            int i = idx >> 4, j = idx & 15;
            As[j][i] = A[(size_t)(m0 + i) * K + k0 + j];
        }
#pragma unroll
        for (int l = 0; l < 4; l++) {
            int idx = tid + l * 256;
            int i = idx >> 6, j = idx & 63;
            int n = n0 + j;
            Bs[i][j] = (n < Nn) ? B[(size_t)(k0 + i) * Nn + n] : 0.f;
        }
        __syncthreads();
#pragma unroll
        for (int kk = 0; kk < 16; kk++) {
            float4 a4 = *(const float4*)&As[kk][ty * 4];
            float4 b4 = *(const float4*)&Bs[kk][tx * 4];
            float av[4] = {a4.x, a4.y, a4.z, a4.w};
            float bv[4] = {b4.x, b4.y, b4.z, b4.w};
#pragma unroll
            for (int r = 0; r < 4; r++)
#pragma unroll
                for (int c = 0; c < 4; c++) acc[r][c] = fmaf(av[r], bv[c], acc[r][c]);
        }
        __syncthreads();
    }
    int nb = n0 + tx * 4;
    if (nb < Nn) {
        float4 bi4 = {0.f, 0.f, 0.f, 0.f};
        if (bias) bi4 = *(const float4*)&bias[nb];
#pragma unroll
        for (int r = 0; r < 4; r++) {
            int m = m0 + ty * 4 + r;
            float4 v;
            v.x = acc[r][0] + bi4.x; v.y = acc[r][1] + bi4.y;
            v.z = acc[r][2] + bi4.z; v.w = acc[r][3] + bi4.w;
            if (act == 1) {
                v.x = fmaxf(v.x, 0.f); v.y = fmaxf(v.y, 0.f);
                v.z = fmaxf(v.z, 0.f); v.w = fmaxf(v.w, 0.f);
            }
            *(float4*)&C[(size_t)m * Nn + nb] = v;
        }
    }
}

// ---------------------------------------------------------------- big-tile GEMM, 512 threads
// 128x128 tile, micro-tile 4m x 8n (3 LDS float4 reads : 32 FMA). 2 blocks/CU.
__global__ __launch_bounds__(512, 4) void gemm_big512(const float* __restrict__ A,
                                                      const float* __restrict__ B,
                                                      float* __restrict__ C,
                                                      int M, int Nn, int K) {
    __shared__ float As[16][132];
    __shared__ float Bs[16][132];
    int tid = threadIdx.x;
    int m0 = blockIdx.y * 128;
    int n0 = blockIdx.x * 128;
    int ty = tid >> 4;          // 0..31 -> m rows ty*4..ty*4+3
    int tx = tid & 15;          // n cols tx*4 and 64+tx*4
    float acc[4][8] = {{0.f}};
    for (int k0 = 0; k0 < K; k0 += 16) {
        {   // A: 128 m x 16 k, one float4 per thread -> As[k][m]
            int m = tid >> 2;
            int kc = (tid & 3) * 4;
            float4 a = *(const float4*)&A[(size_t)(m0 + m) * K + k0 + kc];
            As[kc + 0][m] = a.x; As[kc + 1][m] = a.y;
            As[kc + 2][m] = a.z; As[kc + 3][m] = a.w;
        }
        {   // B: 16 k x 128 n, one float4 per thread
            int krow = tid >> 5;
            int c4 = (tid & 31) * 4;
            *(float4*)&Bs[krow][c4] = *(const float4*)&B[(size_t)(k0 + krow) * Nn + n0 + c4];
        }
        __syncthreads();
#pragma unroll
        for (int kk = 0; kk < 16; kk++) {
            float4 a4 = *(const float4*)&As[kk][ty * 4];
            float4 b0 = *(const float4*)&Bs[kk][tx * 4];
            float4 b1 = *(const float4*)&Bs[kk][64 + tx * 4];
            float av[4] = {a4.x, a4.y, a4.z, a4.w};
            float bv[8] = {b0.x, b0.y, b0.z, b0.w, b1.x, b1.y, b1.z, b1.w};
#pragma unroll
            for (int r = 0; r < 4; r++)
#pragma unroll
                for (int c = 0; c < 8; c++) acc[r][c] = fmaf(av[r], bv[c], acc[r][c]);
        }
        __syncthreads();
    }
#pragma unroll
    for (int r = 0; r < 4; r++) {
        int m = m0 + ty * 4 + r;
        float4 v0, v1;
        v0.x = acc[r][0]; v0.y = acc[r][1]; v0.z = acc[r][2]; v0.w = acc[r][3];
        v1.x = acc[r][4]; v1.y = acc[r][5]; v1.z = acc[r][6]; v1.w = acc[r][7];
        *(float4*)&C[(size_t)m * Nn + n0 + tx * 4] = v0;
        *(float4*)&C[(size_t)m * Nn + n0 + 64 + tx * 4] = v1;
    }
}

// ---------------------------------------------------------------- xproj GEMM (A^T) + transposed output
__global__ __launch_bounds__(256) void gemm_at_dblt(const float* __restrict__ AT,
                                                    const float* __restrict__ B,
                                                    float* __restrict__ dblt) {
    __shared__ float As[16][68];
    __shared__ float Bs[16][68];
    __shared__ float Ct[64][41];
    int tid = threadIdx.x;
    int m0 = blockIdx.x * 64;
    int ty = tid >> 4, tx = tid & 15;
    float acc[4][4] = {{0.f}};
    for (int k0 = 0; k0 < DI; k0 += 16) {
#pragma unroll
        for (int l = 0; l < 4; l++) {
            int idx = tid + l * 256;
            int kk = idx >> 6, i = idx & 63;
            As[kk][i] = AT[(size_t)(k0 + kk) * NN + m0 + i];
        }
#pragma unroll
        for (int l = 0; l < 4; l++) {
            int idx = tid + l * 256;
            int i = idx >> 6, j = idx & 63;
            Bs[i][j] = (j < 40) ? B[(size_t)(k0 + i) * 40 + j] : 0.f;
        }
        __syncthreads();
#pragma unroll
        for (int kk = 0; kk < 16; kk++) {
            float4 a4 = *(const float4*)&As[kk][ty * 4];
            float4 b4 = *(const float4*)&Bs[kk][tx * 4];
            float av[4] = {a4.x, a4.y, a4.z, a4.w};
            float bv[4] = {b4.x, b4.y, b4.z, b4.w};
#pragma unroll
            for (int r = 0; r < 4; r++)
#pragma unroll
                for (int c = 0; c < 4; c++) acc[r][c] = fmaf(av[r], bv[c], acc[r][c]);
        }
        __syncthreads();
    }
    if (tx * 4 < 40) {
#pragma unroll
        for (int r = 0; r < 4; r++) {
            int m = ty * 4 + r;
            Ct[m][tx * 4 + 0] = acc[r][0];
            Ct[m][tx * 4 + 1] = acc[r][1];
            Ct[m][tx * 4 + 2] = acc[r][2];
            Ct[m][tx * 4 + 3] = acc[r][3];
        }
    }
    __syncthreads();
#pragma unroll
    for (int l = 0; l < 10; l++) {
        int idx = tid + l * 256;
        int n = idx >> 6, m = idx & 63;
        dblt[(size_t)n * NN + m0 + m] = Ct[m][n];
    }
}

// ---------------------------------------------------------------- fused W_out GEMM + add + LayerNorm
__global__ __launch_bounds__(256) void gemm_at_ln(const float* __restrict__ AT,
                                                  const float* __restrict__ B,
                                                  const float* __restrict__ hg,
                                                  const float* __restrict__ gamma,
                                                  const float* __restrict__ beta,
                                                  float* __restrict__ out) {
    __shared__ float As[16][36];
    __shared__ float Bs[16][132];
    int tid = threadIdx.x;
    int m0 = blockIdx.x * 32;
    int ty = tid >> 4, tx = tid & 15;
    float acc[2][8] = {{0.f}};
    for (int k0 = 0; k0 < 256; k0 += 16) {
        {
            int idx = tid * 2;
            int kk = idx >> 5, i = idx & 31;
            As[kk][i] = AT[(size_t)(k0 + kk) * NN + m0 + i];
            As[kk][i + 1] = AT[(size_t)(k0 + kk) * NN + m0 + i + 1];
        }
        {
            int krow = tid >> 4;
            int c8 = (tid & 15) * 8;
            const float* bp = &B[(size_t)(k0 + krow) * HH + c8];
            *(float4*)&Bs[krow][c8] = *(const float4*)bp;
            *(float4*)&Bs[krow][c8 + 4] = *(const float4*)(bp + 4);
        }
        __syncthreads();
#pragma unroll
        for (int kk = 0; kk < 16; kk++) {
            float a0 = As[kk][ty * 2];
            float a1 = As[kk][ty * 2 + 1];
            float4 b0 = *(const float4*)&Bs[kk][tx * 4];
            float4 b1 = *(const float4*)&Bs[kk][64 + tx * 4];
            float bv[8] = {b0.x, b0.y, b0.z, b0.w, b1.x, b1.y, b1.z, b1.w};
#pragma unroll
            for (int c = 0; c < 8; c++) {
                acc[0][c] = fmaf(a0, bv[c], acc[0][c]);
                acc[1][c] = fmaf(a1, bv[c], acc[1][c]);
            }
        }
        __syncthreads();
    }
    float4 g0 = *(const float4*)&gamma[tx * 4];
    float4 g1 = *(const float4*)&gamma[64 + tx * 4];
    float4 be0 = *(const float4*)&beta[tx * 4];
    float4 be1 = *(const float4*)&beta[64 + tx * 4];
    float gv[8] = {g0.x, g0.y, g0.z, g0.w, g1.x, g1.y, g1.z, g1.w};
    float bv[8] = {be0.x, be0.y, be0.z, be0.w, be1.x, be1.y, be1.z, be1.w};
#pragma unroll
    for (int r = 0; r < 2; r++) {
        int m = m0 + ty * 2 + r;
        float4 h0 = *(const float4*)&hg[(size_t)m * HH + tx * 4];
        float4 h1 = *(const float4*)&hg[(size_t)m * HH + 64 + tx * 4];
        float v[8] = {acc[r][0] + h0.x, acc[r][1] + h0.y, acc[r][2] + h0.z, acc[r][3] + h0.w,
                      acc[r][4] + h1.x, acc[r][5] + h1.y, acc[r][6] + h1.z, acc[r][7] + h1.w};
        float sum = 0.f;
#pragma unroll
        for (int c = 0; c < 8; c++) sum += v[c];
        sum += __shfl_xor(sum, 1); sum += __shfl_xor(sum, 2);
        sum += __shfl_xor(sum, 4); sum += __shfl_xor(sum, 8);
        float mu = sum * (1.f / 128.f);
        float vs = 0.f;
#pragma unroll
        for (int c = 0; c < 8; c++) { float dd = v[c] - mu; vs += dd * dd; }
        vs += __shfl_xor(vs, 1); vs += __shfl_xor(vs, 2);
        vs += __shfl_xor(vs, 4); vs += __shfl_xor(vs, 8);
        float inv = rsqrtf(vs * (1.f / 128.f) + 1e-5f);
        float4 o0, o1;
        o0.x = (v[0] - mu) * inv * gv[0] + bv[0];
        o0.y = (v[1] - mu) * inv * gv[1] + bv[1];
        o0.z = (v[2] - mu) * inv * gv[2] + bv[2];
        o0.w = (v[3] - mu) * inv * gv[3] + bv[3];
        o1.x = (v[4] - mu) * inv * gv[4] + bv[4];
        o1.y = (v[5] - mu) * inv * gv[5] + bv[5];
        o1.z = (v[6] - mu) * inv * gv[6] + bv[6];
        o1.w = (v[7] - mu) * inv * gv[7] + bv[7];
        *(float4*)&out[(size_t)m * HH + tx * 4] = o0;
        *(float4*)&out[(size_t)m * HH + 64 + tx * 4] = o1;
    }
}

// ---------------------------------------------------------------- GCN gather, float4, 4-edge unroll
__global__ __launch_bounds__(256) void gcn_gather4(const float* __restrict__ xw,
                                                   const int* __restrict__ rowptr,
                                                   const int* __restrict__ col,
                                                   const float* __restrict__ dinv,
                                                   const float* __restrict__ b,
                                                   float* __restrict__ out) {
    int tid = threadIdx.x;
    int sub = tid & 31;
    int n = blockIdx.x * 8 + (tid >> 5);
    float dn = dinv[n];
    const float4* xw4 = (const float4*)xw;
    float4 a = xw4[(size_t)n * 32 + sub];
    float ws = dn * dn;
    float4 acc;
    acc.x = a.x * ws; acc.y = a.y * ws; acc.z = a.z * ws; acc.w = a.w * ws;
    int beg = rowptr[n], end = rowptr[n + 1];
    int e = beg;
    for (; e + 4 <= end; e += 4) {
        int s0 = col[e], s1 = col[e + 1], s2 = col[e + 2], s3 = col[e + 3];
        float w0 = dinv[s0] * dn, w1 = dinv[s1] * dn;
        float w2 = dinv[s2] * dn, w3 = dinv[s3] * dn;
        float4 v0 = xw4[(size_t)s0 * 32 + sub];
        float4 v1 = xw4[(size_t)s1 * 32 + sub];
        float4 v2 = xw4[(size_t)s2 * 32 + sub];
        float4 v3 = xw4[(size_t)s3 * 32 + sub];
        acc.x = fmaf(v0.x, w0, acc.x); acc.y = fmaf(v0.y, w0, acc.y);
        acc.z = fmaf(v0.z, w0, acc.z); acc.w = fmaf(v0.w, w0, acc.w);
        acc.x = fmaf(v1.x, w1, acc.x); acc.y = fmaf(v1.y, w1, acc.y);
        acc.z = fmaf(v1.z, w1, acc.z); acc.w = fmaf(v1.w, w1, acc.w);
        acc.x = fmaf(v2.x, w2, acc.x); acc.y = fmaf(v2.y, w2, acc.y);
        acc.z = fmaf(v2.z, w2, acc.z); acc.w = fmaf(v2.w, w2, acc.w);
        acc.x = fmaf(v3.x, w3, acc.x); acc.y = fmaf(v3.y, w3, acc.y);
        acc.z = fmaf(v3.z, w3, acc.z); acc.w = fmaf(v3.w, w3, acc.w);
    }
    for (; e < end; e++) {
        int s0 = col[e];
        float w0 = dinv[s0] * dn;
        float4 v0 = xw4[(size_t)s0 * 32 + sub];
        acc.x = fmaf(v0.x, w0, acc.x); acc.y = fmaf(v0.y, w0, acc.y);
        acc.z = fmaf(v0.z, w0, acc.z); acc.w = fmaf(v0.w, w0, acc.w);
    }
    float4 b4 = ((const float4*)b)[sub];
    acc.x = fmaxf(acc.x + b4.x, 0.f);
    acc.y = fmaxf(acc.y + b4.y, 0.f);
    acc.z = fmaxf(acc.z + b4.z, 0.f);
    acc.w = fmaxf(acc.w + b4.w, 0.f);
    ((float4*)out)[(size_t)n * 32 + sub] = acc;
}

// ---------------------------------------------------------------- conv + silu, transposed outputs
__global__ __launch_bounds__(256) void conv_silu_t(const float* __restrict__ xz,
                                                   const float* __restrict__ cw,
                                                   const float* __restrict__ cb,
                                                   float* __restrict__ xst,
                                                   float* __restrict__ szt) {
    __shared__ float tile[67][65];
    int tid = threadIdx.x;
    int t0 = blockIdx.x * 64;
    int c0 = blockIdx.y * 64;
#pragma unroll
    for (int l = 0; l < 17; l++) {
        int idx = tid + l * 256;
        if (idx < 67 * 64) {
            int r = idx >> 6, c = idx & 63;
            int gt = t0 - 3 + r;
            tile[r][c] = (gt >= 0) ? xz[(size_t)gt * 512 + c0 + c] : 0.f;
        }
    }
    __syncthreads();
    int tl = tid & 63;
    int d0 = tid >> 6;
    if (c0 < 256) {
#pragma unroll
        for (int l = 0; l < 16; l++) {
            int dl = d0 + l * 4;
            int dg = c0 + dl;
            float acc = cb[dg];
#pragma unroll
            for (int k = 0; k < DC; k++)
                acc = fmaf(tile[tl + k][dl], cw[dg * DC + k], acc);
            xst[dg * NN + t0 + tl] = siluf(acc);
        }
    } else {
#pragma unroll
        for (int l = 0; l < 16; l++) {
            int dl = d0 + l * 4;
            int dg = c0 - 256 + dl;
            szt[dg * NN + t0 + tl] = siluf(tile[tl + 3][dl]);
        }
    }
}

// ---------------------------------------------------------------- Mamba scan (LDS-staged)
__global__ __launch_bounds__(256, 6) void scan_phase1(const float* __restrict__ xst,
                                                      const float* __restrict__ dblt,
                                                      const float* __restrict__ A_log,
                                                      const float* __restrict__ W_dt,
                                                      const float* __restrict__ b_dt,
                                                      float* __restrict__ chkP,
                                                      float* __restrict__ chkH) {
    __shared__ float Td[32][68];
    __shared__ float Tx[32][68];
    __shared__ float Bs[16][68];
    __shared__ float D8[8][68];
    int tid = threadIdx.x;
    int wave = tid >> 6, lane = tid & 63;
    int sg = lane & 7, dl = lane >> 3;
    int dblk = blockIdx.x, chunk = blockIdx.y;
    int t0 = chunk * CHLEN;
    int dloc = wave * 8 + dl;
    int d = dblk * 32 + dloc;
    int s0 = 2 * sg;
#pragma unroll
    for (int p = 0; p < 2; p++) {
        int linear = tid + p * 256;
        int row = linear >> 4, c4 = (linear & 15) * 4;
        *(float4*)&Tx[row][c4] = *(const float4*)&xst[(size_t)(dblk * 32 + row) * NN + t0 + c4];
    }
    if (tid < 128) {
        int r = tid >> 4, c4 = (tid & 15) * 4;
        *(float4*)&D8[r][c4] = *(const float4*)&dblt[(size_t)r * NN + t0 + c4];
    }
    {
        int s = tid >> 4, c4 = (tid & 15) * 4;
        *(float4*)&Bs[s][c4] = *(const float4*)&dblt[(size_t)(8 + s) * NN + t0 + c4];
    }
    float A0 = -expf(A_log[d * DS + s0]);
    float A1 = -expf(A_log[d * DS + s0 + 1]);
    __syncthreads();
    {   // dt tile: 32 d x 64 t
        int row = tid >> 3;
        int tb = (tid & 7) * 8;
        int dd = dblk * 32 + row;
        float bd = b_dt[dd];
        float wv[8];
#pragma unroll
        for (int j = 0; j < 8; j++) wv[j] = W_dt[j * DI + dd];
#pragma unroll
        for (int j = 0; j < 8; j++) {
            int t = tb + j;
            float acc = bd;
#pragma unroll
            for (int k = 0; k < 8; k++) acc = fmaf(D8[k][t], wv[k], acc);
            Td[row][t] = softplusf(acc);
        }
    }
    __syncthreads();
    float h0 = 0.f, h1 = 0.f, P0 = 1.f, P1 = 1.f;
    for (int i = 0; i < CHLEN; i += 4) {
        float4 d4 = *(const float4*)&Td[dloc][i];
        float4 x4 = *(const float4*)&Tx[dloc][i];
        float4 b04 = *(const float4*)&Bs[s0][i];
        float4 b14 = *(const float4*)&Bs[s0 + 1][i];
#define P1S(U) { float dtv = d4.U; float a0 = __expf(dtv * A0); float a1 = __expf(dtv * A1); \
        float dx = dtv * x4.U; h0 = fmaf(a0, h0, dx * b04.U); h1 = fmaf(a1, h1, dx * b14.U); \
        P0 *= a0; P1 *= a1; }
        P1S(x) P1S(y) P1S(z) P1S(w)
#undef P1S
    }
    int idx = chunk * 4096 + d * DS + s0;
    float2 vP; vP.x = P0; vP.y = P1;
    float2 vH; vH.x = h0; vH.y = h1;
    *(float2*)(chkP + idx) = vP;
    *(float2*)(chkH + idx) = vH;
}

// single phase2: serial over all chunks with 8-deep batched prefetch
__global__ void scan_phase2(const float* __restrict__ chkP, const float* __restrict__ chkH,
                            float* __restrict__ init) {
    int idx = blockIdx.x * blockDim.x + threadIdx.x;  // 4096 total
    float h = 0.f;
    for (int c0 = 0; c0 < NCH; c0 += 8) {
        float p[8], q[8];
#pragma unroll
        for (int j = 0; j < 8; j++) {
            p[j] = chkP[(c0 + j) * 4096 + idx];
            q[j] = chkH[(c0 + j) * 4096 + idx];
        }
#pragma unroll
        for (int j = 0; j < 8; j++) {
            init[(c0 + j) * 4096 + idx] = h;
            h = fmaf(p[j], h, q[j]);
        }
    }
}

// phase3: D8 overlaid into Cs buffer; sz prefetched into registers before the scan loop
__global__ __launch_bounds__(256, 6) void scan_phase3(const float* __restrict__ xst,
                                                      const float* __restrict__ dblt,
                                                      const float* __restrict__ A_log,
                                                      const float* __restrict__ W_dt,
                                                      const float* __restrict__ b_dt,
                                                      const float* __restrict__ init,
                                                      const float* __restrict__ D_p,
                                                      const float* __restrict__ szt,
                                                      float* __restrict__ yt) {
    __shared__ float Td[32][68];
    __shared__ float Tx[32][68];
    __shared__ float Bs[16][68];
    __shared__ float CsD8[16][68];   // rows 0..7 = D8 during dt compute; then C rows 0..15
    int tid = threadIdx.x;
    int wave = tid >> 6, lane = tid & 63;
    int sg = lane & 7, dl = lane >> 3;
    int dblk = blockIdx.x, chunk = blockIdx.y;
    int t0 = chunk * CHLEN;
    int dloc = wave * 8 + dl;
    int d = dblk * 32 + dloc;
    int s0 = 2 * sg;
#pragma unroll
    for (int p = 0; p < 2; p++) {
        int linear = tid + p * 256;
        int row = linear >> 4, c4 = (linear & 15) * 4;
        *(float4*)&Tx[row][c4] = *(const float4*)&xst[(size_t)(dblk * 32 + row) * NN + t0 + c4];
    }
    if (tid < 128) {
        int r = tid >> 4, c4 = (tid & 15) * 4;
        *(float4*)&CsD8[r][c4] = *(const float4*)&dblt[(size_t)r * NN + t0 + c4];  // D8
    }
    {
        int s = tid >> 4, c4 = (tid & 15) * 4;
        *(float4*)&Bs[s][c4] = *(const float4*)&dblt[(size_t)(8 + s) * NN + t0 + c4];
    }
    float A0 = -expf(A_log[d * DS + s0]);
    float A1 = -expf(A_log[d * DS + s0 + 1]);
    float Dd = D_p[d];
    float2 ini = *(const float2*)(init + chunk * 4096 + d * DS + s0);
    float h0 = ini.x, h1 = ini.y;
    __syncthreads();
    {   // dt tile from D8 (CsD8 rows 0..7)
        int row = tid >> 3;
        int tb = (tid & 7) * 8;
        int dd = dblk * 32 + row;
        float bd = b_dt[dd];
        float wv[8];
#pragma unroll
        for (int j = 0; j < 8; j++) wv[j] = W_dt[j * DI + dd];
#pragma unroll
        for (int j = 0; j < 8; j++) {
            int t = tb + j;
            float acc = bd;
#pragma unroll
            for (int k = 0; k < 8; k++) acc = fmaf(CsD8[k][t], wv[k], acc);
            Td[row][t] = softplusf(acc);
        }
    }
    __syncthreads();
    {   // now load C rows over the dead D8
        int s = tid >> 4, c4 = (tid & 15) * 4;
        *(float4*)&CsD8[s][c4] = *(const float4*)&dblt[(size_t)(24 + s) * NN + t0 + c4];
    }
    // prefetch sz for the store epilogue (8 independent loads, hidden under the scan)
    float szv[8];
#pragma unroll
    for (int r = 0; r < 8; r++)
        szv[r] = szt[(size_t)(dblk * 32 + wave * 8 + r) * NN + t0 + lane];
    __syncthreads();
    for (int i = 0; i < CHLEN; i += 4) {
        float4 d4 = *(const float4*)&Td[dloc][i];
        float4 x4 = *(const float4*)&Tx[dloc][i];
        float4 b04 = *(const float4*)&Bs[s0][i];
        float4 b14 = *(const float4*)&Bs[s0 + 1][i];
        float4 c04 = *(const float4*)&CsD8[s0][i];
        float4 c14 = *(const float4*)&CsD8[s0 + 1][i];
        float4 yv;
#define P3S(U) { float dtv = d4.U; float a0 = __expf(dtv * A0); float a1 = __expf(dtv * A1); \
        float dx = dtv * x4.U; h0 = fmaf(a0, h0, dx * b04.U); h1 = fmaf(a1, h1, dx * b14.U); \
        float c = fmaf(h1, c14.U, h0 * c04.U); \
        c += __shfl_xor(c, 1); c += __shfl_xor(c, 2); c += __shfl_xor(c, 4); \
        yv.U = c + Dd * x4.U; }
        P3S(x) P3S(y) P3S(z) P3S(w)
#undef P3S
        if (sg == 0) *(float4*)&Td[dloc][i] = yv;  // in-place: this wave's row only
    }
#pragma unroll
    for (int r = 0; r < 8; r++) {
        int row = wave * 8 + r;
        yt[(size_t)(dblk * 32 + row) * NN + t0 + lane] = Td[row][lane] * szv[r];
    }
}

// ---------------------------------------------------------------- pooling (batch sorted), 64 rows/block
__global__ void pool_kernel(const float* __restrict__ hf, const int* __restrict__ batch,
                            float* __restrict__ ge, int* __restrict__ counts) {
    int f = threadIdx.x;  // 128
    int r0 = blockIdx.x * 64;
    int gcur = batch[r0];
    float acc = 0.f;
    int cnt = 0;
    for (int i = 0; i < 64; i += 4) {
        int r = r0 + i;
        int g0 = batch[r], g3 = batch[r + 3];
        float v0 = hf[(size_t)r * HH + f];
        float v1 = hf[(size_t)(r + 1) * HH + f];
        float v2 = hf[(size_t)(r + 2) * HH + f];
        float v3 = hf[(size_t)(r + 3) * HH + f];
        if (g0 == gcur && g3 == gcur) {
            acc += (v0 + v1) + (v2 + v3);
            cnt += 4;
        } else {
            int gs[4] = {g0, batch[r + 1], batch[r + 2], g3};
            float vs[4] = {v0, v1, v2, v3};
#pragma unroll
            for (int k = 0; k < 4; k++) {
                if (gs[k] != gcur) {
                    atomicAdd(&ge[gcur * HH + f], acc);
                    if (f == 0) atomicAdd(&counts[gcur], cnt);
                    acc = 0.f; cnt = 0; gcur = gs[k];
                }
                acc += vs[k];
                cnt++;
            }
        }
    }
    atomicAdd(&ge[gcur * HH + f], acc);
    if (f == 0) atomicAdd(&counts[gcur], cnt);
}

// ---------------------------------------------------------------- output heads (ge_norm folded in)
__global__ void heads_kernel(const float* __restrict__ ge, const int* __restrict__ counts,
                             const float* Wc, const float* bc, const float* Wh, const float* bh,
                             const float* Wt, const float* bt, const float* Wp1, const float* bp1,
                             const float* Wp2, const float* bp2, const float* Wd, const float* bd,
                             const float* Ws, const float* bs, float* __restrict__ out) {
    int col = blockIdx.x * blockDim.x + threadIdx.x;
    int b = blockIdx.y;
    if (col >= OUTW) return;
    const float* W; const float* bi; int lc, w;
    if (col < 1)         { W = Wc;  bi = bc;  lc = col;        w = 1; }
    else if (col < 5)    { W = Wh;  bi = bh;  lc = col - 1;    w = 4; }
    else if (col < 8)    { W = Wt;  bi = bt;  lc = col - 5;    w = 3; }
    else if (col < 520)  { W = Wp1; bi = bp1; lc = col - 8;    w = 512; }
    else if (col < 1032) { W = Wp2; bi = bp2; lc = col - 520;  w = 512; }
    else if (col < 1544) { W = Wd;  bi = bd;  lc = col - 1032; w = 512; }
    else                 { W = Ws;  bi = bs;  lc = col - 1544; w = 8; }
    float scale = 1.f / fmaxf((float)counts[b], 1.f);
    float dot = 0.f;
#pragma unroll 8
    for (int f = 0; f < HH; f++) dot = fmaf(ge[b * HH + f], W[f * w + lc], dot);
    out[(size_t)b * OUTW + col] = bi[lc] + scale * dot;
}

// ---------------------------------------------------------------- launch
extern "C" void kernel_launch(void* const* d_in, const int* in_sizes, int n_in,
                              void* d_out, int out_size, void* d_ws, size_t ws_size,
                              hipStream_t stream) {
    const float* nf      = (const float*)d_in[0];
    const int*   ei      = (const int*)d_in[1];
    const int*   batch   = (const int*)d_in[2];
    const float* W_in    = (const float*)d_in[3];
    const float* b_in    = (const float*)d_in[4];
    const float* W_g1    = (const float*)d_in[5];
    const float* b_g1    = (const float*)d_in[6];
    const float* W_g2    = (const float*)d_in[7];
    const float* b_g2    = (const float*)d_in[8];
    const float* W_inproj= (const float*)d_in[9];
    const float* conv_w  = (const float*)d_in[10];
    const float* conv_b  = (const float*)d_in[11];
    const float* W_xproj = (const float*)d_in[12];
    const float* W_dt    = (const float*)d_in[13];
    const float* b_dt    = (const float*)d_in[14];
    const float* A_log   = (const float*)d_in[15];
    const float* D_p     = (const float*)d_in[16];
    const float* W_out   = (const float*)d_in[17];
    const float* gamma   = (const float*)d_in[18];
    const float* beta    = (const float*)d_in[19];
    const float* Wc = (const float*)d_in[20]; const float* bc = (const float*)d_in[21];
    const float* Wh = (const float*)d_in[22]; const float* bh = (const float*)d_in[23];
    const float* Wt = (const float*)d_in[24]; const float* bt = (const float*)d_in[25];
    const float* Wp1= (const float*)d_in[26]; const float* bp1= (const float*)d_in[27];
    const float* Wp2= (const float*)d_in[28]; const float* bp2= (const float*)d_in[29];
    const float* Wd = (const float*)d_in[30]; const float* bd = (const float*)d_in[31];
    const float* Ws = (const float*)d_in[32]; const float* bs = (const float*)d_in[33];

    const int* e_src = ei;
    const int* e_dst = ei + EE;

    // workspace layout (floats, then ints)
    float* w = (float*)d_ws;
    size_t o = 0;
    float* F0   = w + o; o += (size_t)NN * HH;   // dead during scan -> CHP/CHH
    float* F1   = w + o; o += (size_t)NN * HH;   // dead during scan -> INI
    float* F2   = w + o; o += (size_t)NN * HH;
    float* XZ   = w + o; o += (size_t)NN * 512;  // dead after conv_silu_t; reused:
    float* YT   = XZ;                             //   y^T [DI][NN]
    float* XST  = w + o; o += (size_t)NN * DI;   // x (conv+silu), transposed [DI][NN]
    float* SZT  = w + o; o += (size_t)NN * DI;   // silu(z), transposed [DI][NN]
    float* DBLT = w + o; o += (size_t)NN * 40;   // [40][NN]; 0..7 = dt-proj^T, 8..23 = B^T, 24..39 = C^T
    float* GE   = w + o; o += BB * HH;
    float* DINV = w + o; o += NN;
    int* ip = (int*)(w + o);
    int* CNT    = ip; ip += NN;
    int* ROWPTR = ip; ip += NN + 1;
    int* CURSOR = ip; ip += NN;
    int* COL    = ip; ip += EE;
    int* COUNTS = ip; ip += BB;

    // overlays (regions dead during the scan)
    float* CHP  = F0;                         // NCH*4096 = 1M floats
    float* CHH  = F0 + (size_t)NCH * 4096;    // 1M floats (F0 holds 2M)
    float* INI  = F1;                         // NCH*4096 = 1M floats (F1 holds 2M)

    // zero scratch (single kernel instead of 3 memsets)
    zero_kernel<<<(NN + 255) / 256, 256, 0, stream>>>(CNT, GE, COUNTS);

    // CSR build
    deg_kernel<<<EE / 256, 256, 0, stream>>>(e_dst, CNT);
    prefix_kernel<<<1, 1024, 0, stream>>>(CNT, ROWPTR, CURSOR, DINV);
    scatter_kernel<<<EE / 256, 256, 0, stream>>>(e_src, e_dst, CURSOR, COL);

    // h0 = relu(nf @ W_in + b_in)
    gemm_k<<<dim3(2, NN / 64), 256, 0, stream>>>(nf, W_in, b_in, F0, NN, HH, FF, 1);
    // GCN layer 1
    gemm_k<<<dim3(2, NN / 64), 256, 0, stream>>>(F0, W_g1, nullptr, F1, NN, HH, HH, 0);
    gcn_gather4<<<NN / 8, 256, 0, stream>>>(F1, ROWPTR, COL, DINV, b_g1, F0);
    // GCN layer 2
    gemm_k<<<dim3(2, NN / 64), 256, 0, stream>>>(F0, W_g2, nullptr, F1, NN, HH, HH, 0);
    gcn_gather4<<<NN / 8, 256, 0, stream>>>(F1, ROWPTR, COL, DINV, b_g2, F2);  // F2 = h_gnn

    // xz = h_gnn @ W_inproj (512-thread big-tile GEMM)
    gemm_big512<<<dim3(4, NN / 128), 512, 0, stream>>>(F2, W_inproj, XZ, NN, 512, HH);
    // conv + silu -> XST; silu(z) -> SZT (both transposed)
    conv_silu_t<<<dim3(NN / 64, 8), 256, 0, stream>>>(XZ, conv_w, conv_b, XST, SZT);
    // dbl = xs @ W_xproj, written directly transposed -> DBLT (fused)
    gemm_at_dblt<<<NN / 64, 256, 0, stream>>>(XST, W_xproj, DBLT);

    // Mamba scan (dt fused into phase1/phase3; single phase2)
    scan_phase1<<<dim3(8, NCH), 256, 0, stream>>>(XST, DBLT, A_log, W_dt, b_dt, CHP, CHH);
    scan_phase2<<<16, 256, 0, stream>>>(CHP, CHH, INI);
    scan_phase3<<<dim3(8, NCH), 256, 0, stream>>>(XST, DBLT, A_log, W_dt, b_dt, INI, D_p, SZT, YT);

    // h_mamba = y @ W_out; + h_gnn; LayerNorm -> F0 (fused, 32-row tiles)
    gemm_at_ln<<<NN / 32, 256, 0, stream>>>(YT, W_out, F2, gamma, beta, F0);

    // pooling
    pool_kernel<<<NN / 64, HH, 0, stream>>>(F0, batch, GE, COUNTS);

    // heads (ge_norm folded in)
    heads_kernel<<<dim3((OUTW + 127) / 128, BB), 128, 0, stream>>>(
        GE, COUNTS, Wc, bc, Wh, bh, Wt, bt, Wp1, bp1, Wp2, bp2, Wd, bd, Ws, bs, (float*)d_out);
}